// Round 5
// baseline (184.293 us; speedup 1.0000x reference)
//
#include <hip/hip_runtime.h>
#include <hip/hip_bf16.h>

typedef __hip_bfloat16 bf16;
typedef float f32x4 __attribute__((ext_vector_type(4)));
typedef short s16x8 __attribute__((ext_vector_type(8)));

#define B_    2048
#define S_    40
#define NTOK  (B_*S_)
#define TPB   256
#define TOKB  64

// LDS layout (dwords). A1 aliases FF (FF dead after phase 1).
#define FF_OFF    0       // 64 tokens x 67 u32 (ff bf16 pairs)
#define A1_OFFD   0       // A1: 64 rows x 128B bf16 (aliases FF)
#define A0_OFFD   4288    // A0: 64 rows x 256B bf16 (K=128, k=5i+d); also KV staging
#define PE_OFFD   8384    // 64 f32
#define LDS_DW    8448    // 33792 B -> 4 blocks/CU

#define A0B (A0_OFFD*4)
#define A1B (A1_OFFD*4)

// packW fragment offsets (uint4 units)
#define PK_GL0 0          // [w][S=4][lane]  -> 1024
#define PK_GL1 1024       // [w][S=2][lane]  -> 512
#define PK_GL2 1536       // [S=2][lane]     -> 128
#define PK_KV  1664       // [w][cf=2][S=2][lane] -> 1024
#define PK_TOT 2688

__device__ inline unsigned pk2(float a, float b){
    __hip_bfloat16 ha = __float2bfloat16(a), hb = __float2bfloat16(b);
    unsigned short ua = *reinterpret_cast<unsigned short*>(&ha);
    unsigned short ub = *reinterpret_cast<unsigned short*>(&hb);
    return (unsigned)ua | ((unsigned)ub << 16);
}
__device__ inline float blo(unsigned u){ return __uint_as_float(u << 16); }
__device__ inline float bhi(unsigned u){ return __uint_as_float(u & 0xffff0000u); }

__device__ inline f32x4 MFMA(uint4 a, uint4 b, f32x4 c){
    union { uint4 q; s16x8 s; } A, Bv;
    A.q = a; Bv.q = b;
    return __builtin_amdgcn_mfma_f32_16x16x32_bf16(A.s, Bv.s, c, 0, 0, 0);
}

// ---------------- Kernel 0: pre-pack weight fragments ----------------
__global__ __launch_bounds__(256) void k_pack(
    const float* __restrict__ gl0_W, const float* __restrict__ gl1_W,
    const float* __restrict__ gl2_W, const float* __restrict__ Wqkv,
    uint4* __restrict__ packW)
{
    int f = blockIdx.x * 256 + threadIdx.x;
    if (f >= PK_TOT) return;
    unsigned pr[4];
    if (f < PK_GL1){
        int w = f >> 8, r = f & 255, S = r >> 6, lane = r & 63;
        int half = lane >> 4, c15 = lane & 15, col = w * 16 + c15;
        #pragma unroll
        for (int jj = 0; jj < 4; ++jj){
            int k0 = S*32 + half*8 + 2*jj;
            float v0 = (k0   < 110) ? gl0_W[k0*64 + col]     : 0.f;
            float v1 = (k0+1 < 110) ? gl0_W[(k0+1)*64 + col] : 0.f;
            pr[jj] = pk2(v0, v1);
        }
    } else if (f < PK_GL2){
        int g = f - PK_GL1, w = g >> 7, r = g & 127, S = r >> 6, lane = r & 63;
        int half = lane >> 4, c15 = lane & 15, col = w * 16 + c15;
        #pragma unroll
        for (int jj = 0; jj < 4; ++jj){
            int k0 = S*32 + half*8 + 2*jj;
            pr[jj] = pk2(gl1_W[k0*64 + col], gl1_W[(k0+1)*64 + col]);
        }
    } else if (f < PK_KV){
        int g = f - PK_GL2, S = g >> 6, lane = g & 63;
        int half = lane >> 4, c15 = lane & 15;
        #pragma unroll
        for (int jj = 0; jj < 4; ++jj){
            int k0 = S*32 + half*8 + 2*jj;
            pr[jj] = pk2(gl2_W[k0*16 + c15], gl2_W[(k0+1)*16 + c15]);
        }
    } else {
        int g = f - PK_KV, w = g >> 8, r = g & 255, cf = r >> 7, r2 = r & 127;
        int S = r2 >> 6, lane = r2 & 63;
        int half = lane >> 4, c15 = lane & 15, col = 64 + w*32 + cf*16 + c15;
        #pragma unroll
        for (int jj = 0; jj < 4; ++jj){
            int k0 = S*32 + half*8 + 2*jj;
            pr[jj] = pk2(Wqkv[k0*192 + col], Wqkv[(k0+1)*192 + col]);
        }
    }
    packW[f] = (uint4){pr[0], pr[1], pr[2], pr[3]};
}

// ---------------- Kernel 1: MFMA featurizer ----------------
__global__ __launch_bounds__(TPB, 4) void k_token(
    const float* __restrict__ X,
    const float* __restrict__ emb_act,
    const float* __restrict__ emb_zone,
    const float* __restrict__ lin0_W, const float* __restrict__ lin0_b,
    const float* __restrict__ gat_W,  const float* __restrict__ gat_b,
    const float* __restrict__ gat_a,
    const float* __restrict__ gl0_b,  const float* __restrict__ gl1_b,
    const float* __restrict__ gl2_b,  const float* __restrict__ bqkv,
    const uint4* __restrict__ packW,
    bf16* __restrict__ kv, float* __restrict__ src_last)
{
    __shared__ unsigned L[LDS_DW];
    char* Lb = (char*)L;

    const int t    = threadIdx.x;
    const int w    = t >> 6;      // wave id 0..3
    const int lane = t & 63;
    const int half = (lane >> 4); // 0..3
    const int c15  = lane & 15;
    const int blk0 = blockIdx.x * TOKB;
    const int swzc = (c15 & 7) << 4;

    // ---------- phase 0: ff -> LDS, head -> regs, pe -> LDS, A0 pad zero ----------
    for (int task = t; task < TOKB * 22; task += TPB){
        int tt = task / 22;
        int r  = task - tt * 22;
        const float* xp = X + (size_t)(blk0 + tt) * 118 + 8 + r * 5;
        float f0 = xp[0], f1 = xp[1], f2 = xp[2], f3 = xp[3], f4 = xp[4];
        unsigned* dst = &L[FF_OFF + tt * 67 + 3 * r];
        dst[0] = pk2(f0, f1); dst[1] = pk2(f2, f3); dst[2] = pk2(f4, 0.f);
    }
    // zero-pad A0 k in [110,128): bytes [220,256)
    for (int idx = t; idx < 64 * 9; idx += TPB){
        int row = idx / 9, p = idx - row * 9;
        *(unsigned*)(Lb + A0B + row * 256 + ((220 + 4*p) ^ ((row & 7) << 4))) = 0u;
    }
    // own-token head -> registers
    float hd[8];
    {
        const float2* xp = (const float2*)(X + (size_t)(blk0 + lane) * 118);
        #pragma unroll
        for (int p = 0; p < 4; ++p){ float2 v = xp[p]; hd[2*p] = v.x; hd[2*p+1] = v.y; }
    }
    if (t < TOKB){
        int tok = blk0 + t;
        int b = tok / 40, s = tok - b * 40;
        float denom = powf(100.0f, (2.0f * (float)s) / 40.0f);
        float ang   = (float)b / denom;
        float pe    = ((s & 1) == 0) ? sinf(ang) : cosf(ang);
        ((float*)&L[PE_OFFD])[t] = pe;
    }
    __syncthreads();

    // ---------- phase 1: GAT -> hp (bf16) into A0 (k = 5i+d, K=128) ----------
    {
        const unsigned tb = FF_OFF + lane * 67;
        float va1[5], va2[5];
        float cc1 = 0.f, cc2 = 0.f;
        #pragma unroll
        for (int e = 0; e < 5; ++e){
            float u1 = 0.f, u2 = 0.f;
            #pragma unroll
            for (int d = 0; d < 5; ++d){
                u1 += gat_W[e*5+d] * gat_a[d];
                u2 += gat_W[e*5+d] * gat_a[5+d];
            }
            va1[e] = u1; va2[e] = u2;
        }
        #pragma unroll
        for (int d = 0; d < 5; ++d){ cc1 += gat_b[d]*gat_a[d]; cc2 += gat_b[d]*gat_a[5+d]; }

        float s2v[22];
        float m2 = -1e30f;
        #pragma unroll
        for (int j = 0; j < 22; ++j){
            unsigned u0 = L[tb + 3*j], u1 = L[tb + 3*j + 1], u2 = L[tb + 3*j + 2];
            float f0 = blo(u0), f1 = bhi(u0), f2 = blo(u1), f3 = bhi(u1), f4 = blo(u2);
            s2v[j] = cc2 + f0*va2[0] + f1*va2[1] + f2*va2[2] + f3*va2[3] + f4*va2[4];
            m2 = fmaxf(m2, s2v[j]);
        }

        const int wbase = w * 6;
        const int nI = (w == 3) ? 4 : 6;

        float s1own[6], mi[6], Z[6], ffp[6][5];
        #pragma unroll
        for (int ii = 0; ii < 6; ++ii){
            int i = wbase + ii; if (i > 21) i = 21;   // clamp (w=3, ii>=4 unused)
            unsigned u0 = L[tb + 3*i], u1 = L[tb + 3*i + 1], u2 = L[tb + 3*i + 2];
            float f0 = blo(u0), f1 = bhi(u0), f2 = blo(u1), f3 = bhi(u1), f4 = blo(u2);
            float s1 = cc1 + f0*va1[0] + f1*va1[1] + f2*va1[2] + f3*va1[3] + f4*va1[4];
            s1own[ii] = s1;
            float em = s1 + m2;
            mi[ii] = fmaxf(em, 0.2f * em);
            Z[ii] = 0.f;
            #pragma unroll
            for (int e = 0; e < 5; ++e) ffp[ii][e] = 0.f;
        }

        #pragma unroll
        for (int j = 0; j < 22; ++j){
            unsigned u0 = L[tb + 3*j], u1 = L[tb + 3*j + 1], u2 = L[tb + 3*j + 2];
            float f0 = blo(u0), f1 = bhi(u0), f2 = blo(u1), f3 = bhi(u1), f4 = blo(u2);
            #pragma unroll
            for (int ii = 0; ii < 6; ++ii){
                float e2 = s1own[ii] + s2v[j];
                float lr = fmaxf(e2, 0.2f * e2);
                float wg = __expf(lr - mi[ii]);
                Z[ii] += wg;
                ffp[ii][0] = fmaf(wg, f0, ffp[ii][0]);
                ffp[ii][1] = fmaf(wg, f1, ffp[ii][1]);
                ffp[ii][2] = fmaf(wg, f2, ffp[ii][2]);
                ffp[ii][3] = fmaf(wg, f3, ffp[ii][3]);
                ffp[ii][4] = fmaf(wg, f4, ffp[ii][4]);
            }
        }

        float hflat[30];
        #pragma unroll
        for (int ii = 0; ii < 6; ++ii){
            float rz = 1.f / Z[ii];
            #pragma unroll
            for (int d = 0; d < 5; ++d){
                float u = 0.f;
                #pragma unroll
                for (int e = 0; e < 5; ++e) u += ffp[ii][e] * gat_W[e*5+d];
                hflat[5*ii + d] = u * rz + gat_b[d];
            }
        }
        const int rswz = (lane & 7) << 4;
        if (w < 3){
            #pragma unroll
            for (int p = 0; p < 15; ++p)
                *(unsigned*)(Lb + A0B + lane*256 + ((60*w + 4*p) ^ rswz)) = pk2(hflat[2*p], hflat[2*p+1]);
        } else {
            #pragma unroll
            for (int p = 0; p < 10; ++p)
                *(unsigned*)(Lb + A0B + lane*256 + ((180 + 4*p) ^ rswz)) = pk2(hflat[2*p], hflat[2*p+1]);
        }
    }
    __syncthreads();

    // ---------- phase 2: gl0 MFMA (K=128), wave w -> cols 16w.. ; out -> A1 ----------
    {
        uint4 bfr[4];
        #pragma unroll
        for (int S = 0; S < 4; ++S) bfr[S] = packW[PK_GL0 + (w*4 + S)*64 + lane];
        const int col = w * 16 + c15;
        float bias = gl0_b[col];
        f32x4 ac0 = {bias,bias,bias,bias}, ac1 = ac0, ac2 = ac0, ac3 = ac0;
        #pragma unroll
        for (int S = 0; S < 4; ++S){
            int koff = S*64 + half*16;
            uint4 a0 = *(const uint4*)(Lb + A0B + (0*16 + c15)*256 + (koff ^ swzc));
            uint4 a1 = *(const uint4*)(Lb + A0B + (1*16 + c15)*256 + (koff ^ swzc));
            uint4 a2 = *(const uint4*)(Lb + A0B + (2*16 + c15)*256 + (koff ^ swzc));
            uint4 a3 = *(const uint4*)(Lb + A0B + (3*16 + c15)*256 + (koff ^ swzc));
            ac0 = MFMA(a0, bfr[S], ac0);
            ac1 = MFMA(a1, bfr[S], ac1);
            ac2 = MFMA(a2, bfr[S], ac2);
            ac3 = MFMA(a3, bfr[S], ac3);
        }
        const int off = col * 2;
        #pragma unroll
        for (int r = 0; r < 4; ++r){
            int row0 = 0*16 + half*4 + r;
            int row1 = 1*16 + half*4 + r;
            int row2 = 2*16 + half*4 + r;
            int row3 = 3*16 + half*4 + r;
            *(bf16*)(Lb + A1B + row0*128 + (off ^ ((row0 & 7) << 4))) = __float2bfloat16(fmaxf(ac0[r], 0.f));
            *(bf16*)(Lb + A1B + row1*128 + (off ^ ((row1 & 7) << 4))) = __float2bfloat16(fmaxf(ac1[r], 0.f));
            *(bf16*)(Lb + A1B + row2*128 + (off ^ ((row2 & 7) << 4))) = __float2bfloat16(fmaxf(ac2[r], 0.f));
            *(bf16*)(Lb + A1B + row3*128 + (off ^ ((row3 & 7) << 4))) = __float2bfloat16(fmaxf(ac3[r], 0.f));
        }
    }
    __syncthreads();

    // ---------- phase 3: gl1 MFMA (A1 -> A0 region, stride 128B) ----------
    {
        uint4 bfr[2];
        #pragma unroll
        for (int S = 0; S < 2; ++S) bfr[S] = packW[PK_GL1 + (w*2 + S)*64 + lane];
        const int col = w * 16 + c15;
        float bias = gl1_b[col];
        f32x4 ac0 = {bias,bias,bias,bias}, ac1 = ac0, ac2 = ac0, ac3 = ac0;
        #pragma unroll
        for (int S = 0; S < 2; ++S){
            int koff = S*64 + half*16;
            uint4 a0 = *(const uint4*)(Lb + A1B + (0*16 + c15)*128 + (koff ^ swzc));
            uint4 a1 = *(const uint4*)(Lb + A1B + (1*16 + c15)*128 + (koff ^ swzc));
            uint4 a2 = *(const uint4*)(Lb + A1B + (2*16 + c15)*128 + (koff ^ swzc));
            uint4 a3 = *(const uint4*)(Lb + A1B + (3*16 + c15)*128 + (koff ^ swzc));
            ac0 = MFMA(a0, bfr[S], ac0);
            ac1 = MFMA(a1, bfr[S], ac1);
            ac2 = MFMA(a2, bfr[S], ac2);
            ac3 = MFMA(a3, bfr[S], ac3);
        }
        const int off = col * 2;
        #pragma unroll
        for (int r = 0; r < 4; ++r){
            int row0 = 0*16 + half*4 + r;
            int row1 = 1*16 + half*4 + r;
            int row2 = 2*16 + half*4 + r;
            int row3 = 3*16 + half*4 + r;
            *(bf16*)(Lb + A0B + row0*128 + (off ^ ((row0 & 7) << 4))) = __float2bfloat16(fmaxf(ac0[r], 0.f));
            *(bf16*)(Lb + A0B + row1*128 + (off ^ ((row1 & 7) << 4))) = __float2bfloat16(fmaxf(ac1[r], 0.f));
            *(bf16*)(Lb + A0B + row2*128 + (off ^ ((row2 & 7) << 4))) = __float2bfloat16(fmaxf(ac2[r], 0.f));
            *(bf16*)(Lb + A0B + row3*128 + (off ^ ((row3 & 7) << 4))) = __float2bfloat16(fmaxf(ac3[r], 0.f));
        }
    }
    __syncthreads();

    // ---------- phase 4: gl2 MFMA (wave w -> rowblk w) + src build into A1 ----------
    {
        uint4 bfr[2];
        #pragma unroll
        for (int S = 0; S < 2; ++S) bfr[S] = packW[PK_GL2 + S*64 + lane];
        float bias = gl2_b[c15];
        f32x4 ac = {bias,bias,bias,bias};
        #pragma unroll
        for (int S = 0; S < 2; ++S){
            int koff = S*64 + half*16;
            uint4 a = *(const uint4*)(Lb + A0B + (w*16 + c15)*128 + (koff ^ swzc));
            ac = MFMA(a, bfr[S], ac);
        }
        const float* pef = (const float*)&L[PE_OFFD];
        const int off = (48 + c15) * 2;
        #pragma unroll
        for (int r = 0; r < 4; ++r){
            int row = w*16 + half*4 + r;
            float v = fmaxf(ac[r], 0.f) + pef[row];
            *(bf16*)(Lb + A1B + row*128 + (off ^ ((row & 7) << 4))) = __float2bfloat16(v);
        }

        // emb_act / emb_zone / od -> src cols 0..47 (own token, head in regs)
        float pe = pef[lane];
        int ia = (int)hd[0], iz = (int)hd[1];
        const int tswz = (lane & 7) << 4;
        #pragma unroll
        for (int pp = 0; pp < 6; ++pp){
            int p = w * 6 + pp;
            int c0 = 2 * p;
            float v0, v1;
            if (p < 8)        { v0 = emb_act[ia*16 + c0];        v1 = emb_act[ia*16 + c0 + 1]; }
            else if (p < 16)  { v0 = emb_zone[iz*16 + c0 - 16];  v1 = emb_zone[iz*16 + c0 - 15]; }
            else {
                int cc = c0 - 32;
                float o0 = lin0_b[cc], o1 = lin0_b[cc+1];
                #pragma unroll
                for (int e = 0; e < 6; ++e){
                    float f = hd[2 + e];
                    o0 = fmaf(f, lin0_W[e*16 + cc], o0);
                    o1 = fmaf(f, lin0_W[e*16 + cc + 1], o1);
                }
                v0 = o0; v1 = o1;
            }
            *(unsigned*)(Lb + A1B + lane*128 + ((4*p) ^ tswz)) = pk2(v0 + pe, v1 + pe);
        }
    }
    __syncthreads();

    // ---------- phase 5: src_last + KV MFMA ----------
    {
        int r0 = 39 - (blk0 % 40);
        if (t < 128){
            int tok = r0 + 40 * (t >> 6);
            if (tok < 64){
                int col = t & 63;
                bf16 hv = *(const bf16*)(Lb + A1B + tok*128 + ((col*2) ^ ((tok & 7) << 4)));
                src_last[(size_t)((blk0 + tok) / 40) * 64 + col] = __bfloat162float(hv);
            }
        }

        uint4 bfk[2][2];
        #pragma unroll
        for (int cf = 0; cf < 2; ++cf)
            #pragma unroll
            for (int S = 0; S < 2; ++S)
                bfk[cf][S] = packW[PK_KV + ((w*2 + cf)*2 + S)*64 + lane];

        float b0v = bqkv[64 + w*32 + c15];
        float b1v = bqkv[64 + w*32 + 16 + c15];
        f32x4 acc[4][2];
        #pragma unroll
        for (int R = 0; R < 4; ++R){
            acc[R][0] = (f32x4){b0v, b0v, b0v, b0v};
            acc[R][1] = (f32x4){b1v, b1v, b1v, b1v};
        }
        #pragma unroll
        for (int S = 0; S < 2; ++S){
            int koff = S*64 + half*16;
            #pragma unroll
            for (int R = 0; R < 4; ++R){
                uint4 a = *(const uint4*)(Lb + A1B + (R*16 + c15)*128 + (koff ^ swzc));
                acc[R][0] = MFMA(a, bfk[0][S], acc[R][0]);
                acc[R][1] = MFMA(a, bfk[1][S], acc[R][1]);
            }
        }
        #pragma unroll
        for (int R = 0; R < 4; ++R){
            #pragma unroll
            for (int cf = 0; cf < 2; ++cf){
                int lcol = w*32 + cf*16 + c15;
                int off = lcol * 2;
                #pragma unroll
                for (int r = 0; r < 4; ++r){
                    int row = R*16 + half*4 + r;
                    *(bf16*)(Lb + A0B + row*256 + (off ^ ((row & 7) << 4))) = __float2bfloat16(acc[R][cf][r]);
                }
            }
        }
    }
    __syncthreads();

    // coalesced KV store
    {
        int row = t >> 2;
        int q = t & 3;
        #pragma unroll
        for (int c = 0; c < 4; ++c){
            int chunk = q*4 + c;
            uint4 d = *(const uint4*)(Lb + A0B + row*256 + ((chunk*16) ^ ((row & 7) << 4)));
            *((uint4*)(kv + (size_t)(blk0 + row) * 128 + chunk * 8)) = d;
        }
    }
}

// ---------------- Kernel 2: per-batch attention@last + FFN + heads (2 batches/block) ----------------
__global__ __launch_bounds__(256, 4) void k_head(
    const bf16* __restrict__ kv, const float* __restrict__ src_last,
    const float* __restrict__ Wqkv, const float* __restrict__ bqkv,
    const float* __restrict__ Wo,   const float* __restrict__ bo,
    const float* __restrict__ ln1_g, const float* __restrict__ ln1_b,
    const float* __restrict__ W1,   const float* __restrict__ b1,
    const float* __restrict__ W2,   const float* __restrict__ b2,
    const float* __restrict__ ln2_g, const float* __restrict__ ln2_b,
    const float* __restrict__ relu_W, const float* __restrict__ relu_b,
    const float* __restrict__ nd_W, const float* __restrict__ nd_b,
    const float* __restrict__ ldt_W, const float* __restrict__ ldt_b,
    const float* __restrict__ nz_W, const float* __restrict__ nz_b,
    const float* __restrict__ lz_W, const float* __restrict__ lz_b,
    const float* __restrict__ na0_W, const float* __restrict__ na0_b,
    const float* __restrict__ na1_W, const float* __restrict__ na1_b,
    const float* __restrict__ la_W, const float* __restrict__ la_b,
    float* __restrict__ out)
{
    const int hf = threadIdx.x >> 7;     // which batch half
    const int t  = threadIdx.x & 127;
    const int b  = blockIdx.x * 2 + hf;

    __shared__ unsigned kb32[2][40][32];   // K rows, packed bf16 pairs
    __shared__ unsigned vb32[2][40][32];   // V rows
    __shared__ float qs[2][64], xb[2][64], yb[2][64], f1[2][256];
    __shared__ float xrs[2][64], m65[2][65], mzs[2][20], fa1[2][85], fa2[2][85], redv[2];

    {
        const unsigned* kv32 = (const unsigned*)(kv + (size_t)b * 40 * 128);
        for (int idx = t; idx < 2560; idx += 128){
            unsigned u = kv32[idx];
            int j   = idx >> 6;
            int c32 = idx & 63;
            if (c32 < 32) kb32[hf][j][c32] = u;
            else          vb32[hf][j][c32-32] = u;
        }
    }
    if (t < 64) xb[hf][t] = src_last[b*64 + t];
    __syncthreads();

    if (t < 64){
        float a0=0.f,a1=0.f,a2=0.f,a3=0.f;
        #pragma unroll
        for (int d = 0; d < 64; d += 4){
            a0 = fmaf(xb[hf][d+0], Wqkv[(d+0)*192 + t], a0);
            a1 = fmaf(xb[hf][d+1], Wqkv[(d+1)*192 + t], a1);
            a2 = fmaf(xb[hf][d+2], Wqkv[(d+2)*192 + t], a2);
            a3 = fmaf(xb[hf][d+3], Wqkv[(d+3)*192 + t], a3);
        }
        qs[hf][t] = (bqkv[t] + ((a0+a1)+(a2+a3))) * 0.35355339059327373f;
    }
    __syncthreads();

    float o_c = 0.f;
    if (t < 64){
        const int h = t >> 3;
        float qh[8];
        #pragma unroll
        for (int d = 0; d < 8; ++d) qh[d] = qs[hf][h*8 + d];
        float sc[40];
        float m0 = -1e30f, m1 = -1e30f;
        #pragma unroll
        for (int j = 0; j < 40; ++j){
            float a = 0.f, bb = 0.f;
            #pragma unroll
            for (int d2 = 0; d2 < 4; ++d2){
                unsigned u = kb32[hf][j][h*4 + d2];
                a  = fmaf(qh[2*d2],   blo(u), a);
                bb = fmaf(qh[2*d2+1], bhi(u), bb);
            }
            sc[j] = a + bb;
            if (j & 1) m1 = fmaxf(m1, sc[j]); else m0 = fmaxf(m0, sc[j]);
        }
        float m = fmaxf(m0, m1);
        float Z0=0.f, Z1=0.f, ac0=0.f, ac1=0.f;
        #pragma unroll
        for (int j = 0; j < 40; j += 2){
            float w0 = __expf(sc[j]   - m);
            float w1 = __expf(sc[j+1] - m);
            unsigned u0 = vb32[hf][j][t>>1], u1 = vb32[hf][j+1][t>>1];
            float v0 = (t & 1) ? bhi(u0) : blo(u0);
            float v1 = (t & 1) ? bhi(u1) : blo(u1);
            Z0 += w0; Z1 += w1;
            ac0 = fmaf(w0, v0, ac0); ac1 = fmaf(w1, v1, ac1);
        }
        o_c = (ac0 + ac1) / (Z0 + Z1);
    }
    if (t < 64) yb[hf][t] = o_c;
    __syncthreads();

    float x1 = 0.f;
    if (t < 64){
        float a0=0.f,a1=0.f,a2=0.f,a3=0.f;
        #pragma unroll
        for (int d = 0; d < 64; d += 4){
            a0 = fmaf(yb[hf][d+0], Wo[(d+0)*64+t], a0);
            a1 = fmaf(yb[hf][d+1], Wo[(d+1)*64+t], a1);
            a2 = fmaf(yb[hf][d+2], Wo[(d+2)*64+t], a2);
            a3 = fmaf(yb[hf][d+3], Wo[(d+3)*64+t], a3);
        }
        float v = xb[hf][t] + bo[t] + ((a0+a1)+(a2+a3));
        float sum = v;
        #pragma unroll
        for (int off = 1; off < 64; off <<= 1) sum += __shfl_xor(sum, off, 64);
        float mean = sum * (1.f/64.f);
        float dd = v - mean;
        float s2 = dd*dd;
        #pragma unroll
        for (int off = 1; off < 64; off <<= 1) s2 += __shfl_xor(s2, off, 64);
        float var = s2 * (1.f/64.f);
        x1 = dd * rsqrtf(var + 1e-5f) * ln1_g[t] + ln1_b[t];
    }
    __syncthreads();
    if (t < 64) xb[hf][t] = x1;
    __syncthreads();

    for (int c = t; c < 256; c += 128){
        float a0=0.f,a1=0.f,a2=0.f,a3=0.f;
        #pragma unroll
        for (int d = 0; d < 64; d += 4){
            a0 = fmaf(xb[hf][d+0], W1[(d+0)*256+c], a0);
            a1 = fmaf(xb[hf][d+1], W1[(d+1)*256+c], a1);
            a2 = fmaf(xb[hf][d+2], W1[(d+2)*256+c], a2);
            a3 = fmaf(xb[hf][d+3], W1[(d+3)*256+c], a3);
        }
        f1[hf][c] = fmaxf(b1[c] + ((a0+a1)+(a2+a3)), 0.f);
    }
    __syncthreads();

    if (t < 64){
        float a0=0.f,a1=0.f,a2=0.f,a3=0.f;
        #pragma unroll
        for (int j = 0; j < 256; j += 4){
            a0 = fmaf(f1[hf][j+0], W2[(j+0)*64+t], a0);
            a1 = fmaf(f1[hf][j+1], W2[(j+1)*64+t], a1);
            a2 = fmaf(f1[hf][j+2], W2[(j+2)*64+t], a2);
            a3 = fmaf(f1[hf][j+3], W2[(j+3)*64+t], a3);
        }
        float v = xb[hf][t] + b2[t] + ((a0+a1)+(a2+a3));
        float sum = v;
        #pragma unroll
        for (int off = 1; off < 64; off <<= 1) sum += __shfl_xor(sum, off, 64);
        float mean = sum * (1.f/64.f);
        float dd = v - mean;
        float s2 = dd*dd;
        #pragma unroll
        for (int off = 1; off < 64; off <<= 1) s2 += __shfl_xor(s2, off, 64);
        float var = s2 * (1.f/64.f);
        yb[hf][t] = dd * rsqrtf(var + 1e-5f) * ln2_g[t] + ln2_b[t];
    }
    __syncthreads();

    if (t < 64){
        float a0=0.f,a1=0.f,a2=0.f,a3=0.f;
        #pragma unroll
        for (int d = 0; d < 64; d += 4){
            a0 = fmaf(yb[hf][d+0], relu_W[(d+0)*64+t], a0);
            a1 = fmaf(yb[hf][d+1], relu_W[(d+1)*64+t], a1);
            a2 = fmaf(yb[hf][d+2], relu_W[(d+2)*64+t], a2);
            a3 = fmaf(yb[hf][d+3], relu_W[(d+3)*64+t], a3);
        }
        xrs[hf][t] = relu_b[t] + ((a0+a1)+(a2+a3));
    }
    __syncthreads();

    if (t < 64){
        float a0=0.f,a1=0.f,a2=0.f,a3=0.f;
        #pragma unroll
        for (int d = 0; d < 64; d += 4){
            a0 = fmaf(xrs[hf][d+0], nd_W[(d+0)*64+t], a0);
            a1 = fmaf(xrs[hf][d+1], nd_W[(d+1)*64+t], a1);
            a2 = fmaf(xrs[hf][d+2], nd_W[(d+2)*64+t], a2);
            a3 = fmaf(xrs[hf][d+3], nd_W[(d+3)*64+t], a3);
        }
        float a = nd_b[t] + ((a0+a1)+(a2+a3));
        float contrib = a * ldt_W[t];
        #pragma unroll
        for (int off = 1; off < 64; off <<= 1) contrib += __shfl_xor(contrib, off, 64);
        if (t == 0) redv[hf] = contrib + ldt_b[0];
    }
    __syncthreads();
    float dT = redv[hf];

    if (t < 65){
        float a0 = nz_b[t] + dT*nz_W[t], a1=0.f, a2=0.f, a3=0.f;
        #pragma unroll
        for (int d = 0; d < 64; d += 4){
            a0 = fmaf(xrs[hf][d+0], nz_W[(1+d)*65+t],   a0);
            a1 = fmaf(xrs[hf][d+1], nz_W[(2+d)*65+t],   a1);
            a2 = fmaf(xrs[hf][d+2], nz_W[(3+d)*65+t],   a2);
            a3 = fmaf(xrs[hf][d+3], nz_W[(4+d)*65+t],   a3);
        }
        m65[hf][t] = ((a0+a1)+(a2+a3));
    }
    __syncthreads();

    if (t < 20){
        float a0=0.f,a1=0.f,a2=0.f,a3=0.f;
        #pragma unroll
        for (int d = 0; d < 64; d += 4){
            a0 = fmaf(m65[hf][d+0], lz_W[(d+0)*20+t], a0);
            a1 = fmaf(m65[hf][d+1], lz_W[(d+1)*20+t], a1);
            a2 = fmaf(m65[hf][d+2], lz_W[(d+2)*20+t], a2);
            a3 = fmaf(m65[hf][d+3], lz_W[(d+3)*20+t], a3);
        }
        a0 = fmaf(m65[hf][64], lz_W[64*20+t], a0);
        mzs[hf][t] = lz_b[t] + ((a0+a1)+(a2+a3));
    }
    __syncthreads();

    if (t < 85){
        float a0=0.f,a1=0.f,a2=0.f,a3=0.f;
        #pragma unroll
        for (int d = 0; d < 20; d += 4){
            a0 = fmaf(mzs[hf][d+0], na0_W[(d+0)*85+t], a0);
            a1 = fmaf(mzs[hf][d+1], na0_W[(d+1)*85+t], a1);
            a2 = fmaf(mzs[hf][d+2], na0_W[(d+2)*85+t], a2);
            a3 = fmaf(mzs[hf][d+3], na0_W[(d+3)*85+t], a3);
        }
        a0 = fmaf(dT, na0_W[20*85+t], a0);
        #pragma unroll
        for (int d = 0; d < 64; d += 4){
            a0 = fmaf(xrs[hf][d+0], na0_W[(21+d)*85+t], a0);
            a1 = fmaf(xrs[hf][d+1], na0_W[(22+d)*85+t], a1);
            a2 = fmaf(xrs[hf][d+2], na0_W[(23+d)*85+t], a2);
            a3 = fmaf(xrs[hf][d+3], na0_W[(24+d)*85+t], a3);
        }
        fa1[hf][t] = na0_b[t] + ((a0+a1)+(a2+a3));
    }
    __syncthreads();
    if (t < 85){
        float a0=0.f,a1=0.f,a2=0.f,a3=0.f;
        #pragma unroll
        for (int d = 0; d < 84; d += 4){
            a0 = fmaf(fa1[hf][d+0], na1_W[(d+0)*85+t], a0);
            a1 = fmaf(fa1[hf][d+1], na1_W[(d+1)*85+t], a1);
            a2 = fmaf(fa1[hf][d+2], na1_W[(d+2)*85+t], a2);
            a3 = fmaf(fa1[hf][d+3], na1_W[(d+3)*85+t], a3);
        }
        a0 = fmaf(fa1[hf][84], na1_W[84*85+t], a0);
        fa2[hf][t] = na1_b[t] + ((a0+a1)+(a2+a3));
    }
    __syncthreads();

    if (t == 0) out[b*26] = dT;
    if (t < 20) out[b*26 + 1 + t] = mzs[hf][t];
    if (t < 5){
        float a0=0.f,a1=0.f,a2=0.f,a3=0.f;
        #pragma unroll
        for (int d = 0; d < 84; d += 4){
            a0 = fmaf(fa2[hf][d+0], la_W[(d+0)*5+t], a0);
            a1 = fmaf(fa2[hf][d+1], la_W[(d+1)*5+t], a1);
            a2 = fmaf(fa2[hf][d+2], la_W[(d+2)*5+t], a2);
            a3 = fmaf(fa2[hf][d+3], la_W[(d+3)*5+t], a3);
        }
        a0 = fmaf(fa2[hf][84], la_W[84*5+t], a0);
        out[b*26 + 21 + t] = la_b[t] + ((a0+a1)+(a2+a3));
    }
}

extern "C" void kernel_launch(void* const* d_in, const int* in_sizes, int n_in,
                              void* d_out, int out_size, void* d_ws, size_t ws_size,
                              hipStream_t stream)
{
    const float* X        = (const float*)d_in[0];
    const float* emb_act  = (const float*)d_in[1];
    const float* emb_zone = (const float*)d_in[2];
    const float* lin0_W   = (const float*)d_in[3];
    const float* lin0_b   = (const float*)d_in[4];
    const float* gat_W    = (const float*)d_in[5];
    const float* gat_b    = (const float*)d_in[6];
    const float* gat_a    = (const float*)d_in[7];
    const float* gl0_W    = (const float*)d_in[8];
    const float* gl0_b    = (const float*)d_in[9];
    const float* gl1_W    = (const float*)d_in[10];
    const float* gl1_b    = (const float*)d_in[11];
    const float* gl2_W    = (const float*)d_in[12];
    const float* gl2_b    = (const float*)d_in[13];
    const float* Wqkv     = (const float*)d_in[14];
    const float* bqkv     = (const float*)d_in[15];
    const float* Wo       = (const float*)d_in[16];
    const float* bo       = (const float*)d_in[17];
    const float* ln1_g    = (const float*)d_in[18];
    const float* ln1_b    = (const float*)d_in[19];
    const float* W1       = (const float*)d_in[20];
    const float* b1       = (const float*)d_in[21];
    const float* W2       = (const float*)d_in[22];
    const float* b2       = (const float*)d_in[23];
    const float* ln2_g    = (const float*)d_in[24];
    const float* ln2_b    = (const float*)d_in[25];
    const float* relu_W   = (const float*)d_in[26];
    const float* relu_b   = (const float*)d_in[27];
    const float* nd_W     = (const float*)d_in[28];
    const float* nd_b     = (const float*)d_in[29];
    const float* ldt_W    = (const float*)d_in[30];
    const float* ldt_b    = (const float*)d_in[31];
    const float* nz_W     = (const float*)d_in[32];
    const float* nz_b     = (const float*)d_in[33];
    const float* lz_W     = (const float*)d_in[34];
    const float* lz_b     = (const float*)d_in[35];
    const float* na0_W    = (const float*)d_in[36];
    const float* na0_b    = (const float*)d_in[37];
    const float* na1_W    = (const float*)d_in[38];
    const float* na1_b    = (const float*)d_in[39];
    const float* la_W     = (const float*)d_in[40];
    const float* la_b     = (const float*)d_in[41];

    bf16*  kv       = (bf16*)d_ws;
    float* src_last = (float*)((char*)d_ws + (size_t)NTOK * 128 * sizeof(bf16));
    uint4* packW    = (uint4*)((char*)d_ws + (size_t)NTOK * 128 * sizeof(bf16) + (size_t)B_ * 64 * sizeof(float));

    k_pack<<<(PK_TOT + 255)/256, 256, 0, stream>>>(gl0_W, gl1_W, gl2_W, Wqkv, packW);

    k_token<<<NTOK/TOKB, TPB, 0, stream>>>(X, emb_act, emb_zone, lin0_W, lin0_b,
        gat_W, gat_b, gat_a, gl0_b, gl1_b, gl2_b, bqkv, packW, kv, src_last);

    k_head<<<B_/2, 256, 0, stream>>>(kv, src_last, Wqkv, bqkv, Wo, bo,
        ln1_g, ln1_b, W1, b1, W2, b2, ln2_g, ln2_b, relu_W, relu_b,
        nd_W, nd_b, ldt_W, ldt_b, nz_W, nz_b, lz_W, lz_b,
        na0_W, na0_b, na1_W, na1_b, la_W, la_b, (float*)d_out);
}

// Round 6
// 141.396 us; speedup vs baseline: 1.3034x; 1.3034x over previous
//
#include <hip/hip_runtime.h>
#include <hip/hip_bf16.h>

typedef __hip_bfloat16 bf16;
typedef float f32x4 __attribute__((ext_vector_type(4)));
typedef short s16x8 __attribute__((ext_vector_type(8)));

#define B_    2048
#define S_    40
#define NTOK  (B_*S_)
#define TPB   256
#define TOKB  64

// LDS layout (dwords). A1 aliases FF (FF dead after phase 1).
#define FF_OFF    0       // 64 tokens x 67 u32 (ff bf16 pairs)
#define A1_OFFD   0       // A1: 64 rows x 128B bf16 (aliases FF)
#define A0_OFFD   4288    // A0: 64 rows x 256B bf16 (K=128, k=5i+d); also KV staging
#define PE_OFFD   8384    // 64 f32
#define LDS_DW    8448    // 33792 B

#define A0B (A0_OFFD*4)
#define A1B (A1_OFFD*4)

// packW fragment offsets (uint4 units)
#define PK_GL0 0          // [w][S=4][lane]  -> 1024
#define PK_GL1 1024       // [w][S=2][lane]  -> 512
#define PK_GL2 1536       // [S=2][lane]     -> 128
#define PK_KV  1664       // [w][cf=2][S=2][lane] -> 1024
#define PK_TOT 2688

__device__ inline unsigned pk2(float a, float b){
    __hip_bfloat16 ha = __float2bfloat16(a), hb = __float2bfloat16(b);
    unsigned short ua = *reinterpret_cast<unsigned short*>(&ha);
    unsigned short ub = *reinterpret_cast<unsigned short*>(&hb);
    return (unsigned)ua | ((unsigned)ub << 16);
}
__device__ inline float blo(unsigned u){ return __uint_as_float(u << 16); }
__device__ inline float bhi(unsigned u){ return __uint_as_float(u & 0xffff0000u); }

__device__ inline f32x4 MFMA(uint4 a, uint4 b, f32x4 c){
    union { uint4 q; s16x8 s; } A, Bv;
    A.q = a; Bv.q = b;
    return __builtin_amdgcn_mfma_f32_16x16x32_bf16(A.s, Bv.s, c, 0, 0, 0);
}

// ---------------- Kernel 0: pre-pack weight fragments ----------------
__global__ __launch_bounds__(256) void k_pack(
    const float* __restrict__ gl0_W, const float* __restrict__ gl1_W,
    const float* __restrict__ gl2_W, const float* __restrict__ Wqkv,
    uint4* __restrict__ packW)
{
    int f = blockIdx.x * 256 + threadIdx.x;
    if (f >= PK_TOT) return;
    unsigned pr[4];
    if (f < PK_GL1){
        int w = f >> 8, r = f & 255, S = r >> 6, lane = r & 63;
        int half = lane >> 4, c15 = lane & 15, col = w * 16 + c15;
        #pragma unroll
        for (int jj = 0; jj < 4; ++jj){
            int k0 = S*32 + half*8 + 2*jj;
            float v0 = (k0   < 110) ? gl0_W[k0*64 + col]     : 0.f;
            float v1 = (k0+1 < 110) ? gl0_W[(k0+1)*64 + col] : 0.f;
            pr[jj] = pk2(v0, v1);
        }
    } else if (f < PK_GL2){
        int g = f - PK_GL1, w = g >> 7, r = g & 127, S = r >> 6, lane = r & 63;
        int half = lane >> 4, c15 = lane & 15, col = w * 16 + c15;
        #pragma unroll
        for (int jj = 0; jj < 4; ++jj){
            int k0 = S*32 + half*8 + 2*jj;
            pr[jj] = pk2(gl1_W[k0*64 + col], gl1_W[(k0+1)*64 + col]);
        }
    } else if (f < PK_KV){
        int g = f - PK_GL2, S = g >> 6, lane = g & 63;
        int half = lane >> 4, c15 = lane & 15;
        #pragma unroll
        for (int jj = 0; jj < 4; ++jj){
            int k0 = S*32 + half*8 + 2*jj;
            pr[jj] = pk2(gl2_W[k0*16 + c15], gl2_W[(k0+1)*16 + c15]);
        }
    } else {
        int g = f - PK_KV, w = g >> 8, r = g & 255, cf = r >> 7, r2 = r & 127;
        int S = r2 >> 6, lane = r2 & 63;
        int half = lane >> 4, c15 = lane & 15, col = 64 + w*32 + cf*16 + c15;
        #pragma unroll
        for (int jj = 0; jj < 4; ++jj){
            int k0 = S*32 + half*8 + 2*jj;
            pr[jj] = pk2(Wqkv[k0*192 + col], Wqkv[(k0+1)*192 + col]);
        }
    }
    packW[f] = (uint4){pr[0], pr[1], pr[2], pr[3]};
}

// ---------------- Kernel 1: MFMA featurizer ----------------
__global__ __launch_bounds__(TPB) void k_token(
    const float* __restrict__ X,
    const float* __restrict__ emb_act,
    const float* __restrict__ emb_zone,
    const float* __restrict__ lin0_W, const float* __restrict__ lin0_b,
    const float* __restrict__ gat_W,  const float* __restrict__ gat_b,
    const float* __restrict__ gat_a,
    const float* __restrict__ gl0_b,  const float* __restrict__ gl1_b,
    const float* __restrict__ gl2_b,  const float* __restrict__ bqkv,
    const uint4* __restrict__ packW,
    bf16* __restrict__ kv, float* __restrict__ src_last)
{
    __shared__ unsigned L[LDS_DW];
    char* Lb = (char*)L;

    const int t    = threadIdx.x;
    const int w    = t >> 6;      // wave id 0..3
    const int lane = t & 63;
    const int half = (lane >> 4); // 0..3
    const int c15  = lane & 15;
    const int blk0 = blockIdx.x * TOKB;
    const int swzc = (c15 & 7) << 4;

    // ---------- phase 0: ff -> LDS, head -> regs, pe -> LDS, A0 pad zero ----------
    for (int task = t; task < TOKB * 22; task += TPB){
        int tt = task / 22;
        int r  = task - tt * 22;
        const float* xp = X + (size_t)(blk0 + tt) * 118 + 8 + r * 5;
        float f0 = xp[0], f1 = xp[1], f2 = xp[2], f3 = xp[3], f4 = xp[4];
        unsigned* dst = &L[FF_OFF + tt * 67 + 3 * r];
        dst[0] = pk2(f0, f1); dst[1] = pk2(f2, f3); dst[2] = pk2(f4, 0.f);
    }
    // zero-pad A0 k in [110,128): bytes [220,256)
    for (int idx = t; idx < 64 * 9; idx += TPB){
        int row = idx / 9, p = idx - row * 9;
        *(unsigned*)(Lb + A0B + row * 256 + ((220 + 4*p) ^ ((row & 7) << 4))) = 0u;
    }
    // own-token head -> registers
    float hd[8];
    {
        const float2* xp = (const float2*)(X + (size_t)(blk0 + lane) * 118);
        #pragma unroll
        for (int p = 0; p < 4; ++p){ float2 v = xp[p]; hd[2*p] = v.x; hd[2*p+1] = v.y; }
    }
    if (t < TOKB){
        int tok = blk0 + t;
        int b = tok / 40, s = tok - b * 40;
        float denom = powf(100.0f, (2.0f * (float)s) / 40.0f);
        float ang   = (float)b / denom;
        float pe    = ((s & 1) == 0) ? sinf(ang) : cosf(ang);
        ((float*)&L[PE_OFFD])[t] = pe;
    }
    __syncthreads();

    // ---------- phase 1: GAT -> hp (bf16) into A0 (k = 5i+d, K=128) ----------
    {
        const unsigned tb = FF_OFF + lane * 67;
        float va1[5], va2[5];
        float cc1 = 0.f, cc2 = 0.f;
        #pragma unroll
        for (int e = 0; e < 5; ++e){
            float u1 = 0.f, u2 = 0.f;
            #pragma unroll
            for (int d = 0; d < 5; ++d){
                u1 += gat_W[e*5+d] * gat_a[d];
                u2 += gat_W[e*5+d] * gat_a[5+d];
            }
            va1[e] = u1; va2[e] = u2;
        }
        #pragma unroll
        for (int d = 0; d < 5; ++d){ cc1 += gat_b[d]*gat_a[d]; cc2 += gat_b[d]*gat_a[5+d]; }

        float s2v[22];
        float m2 = -1e30f;
        #pragma unroll
        for (int j = 0; j < 22; ++j){
            unsigned u0 = L[tb + 3*j], u1 = L[tb + 3*j + 1], u2 = L[tb + 3*j + 2];
            float f0 = blo(u0), f1 = bhi(u0), f2 = blo(u1), f3 = bhi(u1), f4 = blo(u2);
            s2v[j] = cc2 + f0*va2[0] + f1*va2[1] + f2*va2[2] + f3*va2[3] + f4*va2[4];
            m2 = fmaxf(m2, s2v[j]);
        }

        const int wbase = w * 6;

        float s1own[6], mi[6], Z[6], ffp[6][5];
        #pragma unroll
        for (int ii = 0; ii < 6; ++ii){
            int i = wbase + ii; if (i > 21) i = 21;   // clamp (w=3, ii>=4 unused)
            unsigned u0 = L[tb + 3*i], u1 = L[tb + 3*i + 1], u2 = L[tb + 3*i + 2];
            float f0 = blo(u0), f1 = bhi(u0), f2 = blo(u1), f3 = bhi(u1), f4 = blo(u2);
            float s1 = cc1 + f0*va1[0] + f1*va1[1] + f2*va1[2] + f3*va1[3] + f4*va1[4];
            s1own[ii] = s1;
            float em = s1 + m2;
            mi[ii] = fmaxf(em, 0.2f * em);
            Z[ii] = 0.f;
            #pragma unroll
            for (int e = 0; e < 5; ++e) ffp[ii][e] = 0.f;
        }

        #pragma unroll
        for (int j = 0; j < 22; ++j){
            unsigned u0 = L[tb + 3*j], u1 = L[tb + 3*j + 1], u2 = L[tb + 3*j + 2];
            float f0 = blo(u0), f1 = bhi(u0), f2 = blo(u1), f3 = bhi(u1), f4 = blo(u2);
            #pragma unroll
            for (int ii = 0; ii < 6; ++ii){
                float e2 = s1own[ii] + s2v[j];
                float lr = fmaxf(e2, 0.2f * e2);
                float wg = __expf(lr - mi[ii]);
                Z[ii] += wg;
                ffp[ii][0] = fmaf(wg, f0, ffp[ii][0]);
                ffp[ii][1] = fmaf(wg, f1, ffp[ii][1]);
                ffp[ii][2] = fmaf(wg, f2, ffp[ii][2]);
                ffp[ii][3] = fmaf(wg, f3, ffp[ii][3]);
                ffp[ii][4] = fmaf(wg, f4, ffp[ii][4]);
            }
        }

        // direct b16 writes (k = 5i+d -> byte 10i+2d, XOR-swizzled)
        const int rswz = (lane & 7) << 4;
        #pragma unroll
        for (int ii = 0; ii < 6; ++ii){
            int i = wbase + ii;
            if (i < 22){
                float rz = 1.f / Z[ii];
                #pragma unroll
                for (int d = 0; d < 5; ++d){
                    float u = 0.f;
                    #pragma unroll
                    for (int e = 0; e < 5; ++e) u += ffp[ii][e] * gat_W[e*5+d];
                    float h = u * rz + gat_b[d];
                    *(bf16*)(Lb + A0B + lane*256 + ((10*i + 2*d) ^ rswz)) = __float2bfloat16(h);
                }
            }
        }
    }
    __syncthreads();

    // ---------- phase 2: gl0 MFMA (K=128), wave w -> cols 16w.. ; out -> A1 ----------
    {
        uint4 bfr[4];
        #pragma unroll
        for (int S = 0; S < 4; ++S) bfr[S] = packW[PK_GL0 + (w*4 + S)*64 + lane];
        const int col = w * 16 + c15;
        float bias = gl0_b[col];
        f32x4 ac0 = {bias,bias,bias,bias}, ac1 = ac0, ac2 = ac0, ac3 = ac0;
        #pragma unroll
        for (int S = 0; S < 4; ++S){
            int koff = S*64 + half*16;
            uint4 a0 = *(const uint4*)(Lb + A0B + (0*16 + c15)*256 + (koff ^ swzc));
            uint4 a1 = *(const uint4*)(Lb + A0B + (1*16 + c15)*256 + (koff ^ swzc));
            uint4 a2 = *(const uint4*)(Lb + A0B + (2*16 + c15)*256 + (koff ^ swzc));
            uint4 a3 = *(const uint4*)(Lb + A0B + (3*16 + c15)*256 + (koff ^ swzc));
            ac0 = MFMA(a0, bfr[S], ac0);
            ac1 = MFMA(a1, bfr[S], ac1);
            ac2 = MFMA(a2, bfr[S], ac2);
            ac3 = MFMA(a3, bfr[S], ac3);
        }
        const int off = col * 2;
        #pragma unroll
        for (int r = 0; r < 4; ++r){
            int row0 = 0*16 + half*4 + r;
            int row1 = 1*16 + half*4 + r;
            int row2 = 2*16 + half*4 + r;
            int row3 = 3*16 + half*4 + r;
            *(bf16*)(Lb + A1B + row0*128 + (off ^ ((row0 & 7) << 4))) = __float2bfloat16(fmaxf(ac0[r], 0.f));
            *(bf16*)(Lb + A1B + row1*128 + (off ^ ((row1 & 7) << 4))) = __float2bfloat16(fmaxf(ac1[r], 0.f));
            *(bf16*)(Lb + A1B + row2*128 + (off ^ ((row2 & 7) << 4))) = __float2bfloat16(fmaxf(ac2[r], 0.f));
            *(bf16*)(Lb + A1B + row3*128 + (off ^ ((row3 & 7) << 4))) = __float2bfloat16(fmaxf(ac3[r], 0.f));
        }
    }
    __syncthreads();

    // ---------- phase 3: gl1 MFMA (A1 -> A0 region, stride 128B) ----------
    {
        uint4 bfr[2];
        #pragma unroll
        for (int S = 0; S < 2; ++S) bfr[S] = packW[PK_GL1 + (w*2 + S)*64 + lane];
        const int col = w * 16 + c15;
        float bias = gl1_b[col];
        f32x4 ac0 = {bias,bias,bias,bias}, ac1 = ac0, ac2 = ac0, ac3 = ac0;
        #pragma unroll
        for (int S = 0; S < 2; ++S){
            int koff = S*64 + half*16;
            uint4 a0 = *(const uint4*)(Lb + A1B + (0*16 + c15)*128 + (koff ^ swzc));
            uint4 a1 = *(const uint4*)(Lb + A1B + (1*16 + c15)*128 + (koff ^ swzc));
            uint4 a2 = *(const uint4*)(Lb + A1B + (2*16 + c15)*128 + (koff ^ swzc));
            uint4 a3 = *(const uint4*)(Lb + A1B + (3*16 + c15)*128 + (koff ^ swzc));
            ac0 = MFMA(a0, bfr[S], ac0);
            ac1 = MFMA(a1, bfr[S], ac1);
            ac2 = MFMA(a2, bfr[S], ac2);
            ac3 = MFMA(a3, bfr[S], ac3);
        }
        const int off = col * 2;
        #pragma unroll
        for (int r = 0; r < 4; ++r){
            int row0 = 0*16 + half*4 + r;
            int row1 = 1*16 + half*4 + r;
            int row2 = 2*16 + half*4 + r;
            int row3 = 3*16 + half*4 + r;
            *(bf16*)(Lb + A0B + row0*128 + (off ^ ((row0 & 7) << 4))) = __float2bfloat16(fmaxf(ac0[r], 0.f));
            *(bf16*)(Lb + A0B + row1*128 + (off ^ ((row1 & 7) << 4))) = __float2bfloat16(fmaxf(ac1[r], 0.f));
            *(bf16*)(Lb + A0B + row2*128 + (off ^ ((row2 & 7) << 4))) = __float2bfloat16(fmaxf(ac2[r], 0.f));
            *(bf16*)(Lb + A0B + row3*128 + (off ^ ((row3 & 7) << 4))) = __float2bfloat16(fmaxf(ac3[r], 0.f));
        }
    }
    __syncthreads();

    // ---------- phase 4: gl2 MFMA (wave w -> rowblk w) + src build into A1 ----------
    {
        uint4 bfr[2];
        #pragma unroll
        for (int S = 0; S < 2; ++S) bfr[S] = packW[PK_GL2 + S*64 + lane];
        float bias = gl2_b[c15];
        f32x4 ac = {bias,bias,bias,bias};
        #pragma unroll
        for (int S = 0; S < 2; ++S){
            int koff = S*64 + half*16;
            uint4 a = *(const uint4*)(Lb + A0B + (w*16 + c15)*128 + (koff ^ swzc));
            ac = MFMA(a, bfr[S], ac);
        }
        const float* pef = (const float*)&L[PE_OFFD];
        const int off = (48 + c15) * 2;
        #pragma unroll
        for (int r = 0; r < 4; ++r){
            int row = w*16 + half*4 + r;
            float v = fmaxf(ac[r], 0.f) + pef[row];
            *(bf16*)(Lb + A1B + row*128 + (off ^ ((row & 7) << 4))) = __float2bfloat16(v);
        }

        // emb_act / emb_zone / od -> src cols 0..47 (own token, head in regs)
        float pe = pef[lane];
        int ia = (int)hd[0], iz = (int)hd[1];
        const int tswz = (lane & 7) << 4;
        #pragma unroll
        for (int pp = 0; pp < 6; ++pp){
            int p = w * 6 + pp;
            int c0 = 2 * p;
            float v0, v1;
            if (p < 8)        { v0 = emb_act[ia*16 + c0];        v1 = emb_act[ia*16 + c0 + 1]; }
            else if (p < 16)  { v0 = emb_zone[iz*16 + c0 - 16];  v1 = emb_zone[iz*16 + c0 - 15]; }
            else {
                int cc = c0 - 32;
                float o0 = lin0_b[cc], o1 = lin0_b[cc+1];
                #pragma unroll
                for (int e = 0; e < 6; ++e){
                    float f = hd[2 + e];
                    o0 = fmaf(f, lin0_W[e*16 + cc], o0);
                    o1 = fmaf(f, lin0_W[e*16 + cc + 1], o1);
                }
                v0 = o0; v1 = o1;
            }
            *(unsigned*)(Lb + A1B + lane*128 + ((4*p) ^ tswz)) = pk2(v0 + pe, v1 + pe);
        }
    }
    __syncthreads();

    // ---------- phase 5: src_last + KV MFMA ----------
    {
        int r0 = 39 - (blk0 % 40);
        if (t < 128){
            int tok = r0 + 40 * (t >> 6);
            if (tok < 64){
                int col = t & 63;
                bf16 hv = *(const bf16*)(Lb + A1B + tok*128 + ((col*2) ^ ((tok & 7) << 4)));
                src_last[(size_t)((blk0 + tok) / 40) * 64 + col] = __bfloat162float(hv);
            }
        }

        uint4 bfk[2][2];
        #pragma unroll
        for (int cf = 0; cf < 2; ++cf)
            #pragma unroll
            for (int S = 0; S < 2; ++S)
                bfk[cf][S] = packW[PK_KV + ((w*2 + cf)*2 + S)*64 + lane];

        float b0v = bqkv[64 + w*32 + c15];
        float b1v = bqkv[64 + w*32 + 16 + c15];
        f32x4 acc[4][2];
        #pragma unroll
        for (int R = 0; R < 4; ++R){
            acc[R][0] = (f32x4){b0v, b0v, b0v, b0v};
            acc[R][1] = (f32x4){b1v, b1v, b1v, b1v};
        }
        #pragma unroll
        for (int S = 0; S < 2; ++S){
            int koff = S*64 + half*16;
            #pragma unroll
            for (int R = 0; R < 4; ++R){
                uint4 a = *(const uint4*)(Lb + A1B + (R*16 + c15)*128 + (koff ^ swzc));
                acc[R][0] = MFMA(a, bfk[0][S], acc[R][0]);
                acc[R][1] = MFMA(a, bfk[1][S], acc[R][1]);
            }
        }
        #pragma unroll
        for (int R = 0; R < 4; ++R){
            #pragma unroll
            for (int cf = 0; cf < 2; ++cf){
                int lcol = w*32 + cf*16 + c15;
                int off = lcol * 2;
                #pragma unroll
                for (int r = 0; r < 4; ++r){
                    int row = R*16 + half*4 + r;
                    *(bf16*)(Lb + A0B + row*256 + (off ^ ((row & 7) << 4))) = __float2bfloat16(acc[R][cf][r]);
                }
            }
        }
    }
    __syncthreads();

    // coalesced KV store
    {
        int row = t >> 2;
        int q = t & 3;
        #pragma unroll
        for (int c = 0; c < 4; ++c){
            int chunk = q*4 + c;
            uint4 d = *(const uint4*)(Lb + A0B + row*256 + ((chunk*16) ^ ((row & 7) << 4)));
            *((uint4*)(kv + (size_t)(blk0 + row) * 128 + chunk * 8)) = d;
        }
    }
}

// ---------------- Kernel 2: per-batch attention@last + FFN + heads (2 batches/block) ----------------
__global__ __launch_bounds__(256) void k_head(
    const bf16* __restrict__ kv, const float* __restrict__ src_last,
    const float* __restrict__ Wqkv, const float* __restrict__ bqkv,
    const float* __restrict__ Wo,   const float* __restrict__ bo,
    const float* __restrict__ ln1_g, const float* __restrict__ ln1_b,
    const float* __restrict__ W1,   const float* __restrict__ b1,
    const float* __restrict__ W2,   const float* __restrict__ b2,
    const float* __restrict__ ln2_g, const float* __restrict__ ln2_b,
    const float* __restrict__ relu_W, const float* __restrict__ relu_b,
    const float* __restrict__ nd_W, const float* __restrict__ nd_b,
    const float* __restrict__ ldt_W, const float* __restrict__ ldt_b,
    const float* __restrict__ nz_W, const float* __restrict__ nz_b,
    const float* __restrict__ lz_W, const float* __restrict__ lz_b,
    const float* __restrict__ na0_W, const float* __restrict__ na0_b,
    const float* __restrict__ na1_W, const float* __restrict__ na1_b,
    const float* __restrict__ la_W, const float* __restrict__ la_b,
    float* __restrict__ out)
{
    const int hf = threadIdx.x >> 7;     // which batch half
    const int t  = threadIdx.x & 127;
    const int b  = blockIdx.x * 2 + hf;

    __shared__ unsigned kb32[2][40][32];   // K rows, packed bf16 pairs
    __shared__ unsigned vb32[2][40][32];   // V rows
    __shared__ float qs[2][64], xb[2][64], yb[2][64], f1[2][256];
    __shared__ float xrs[2][64], m65[2][65], mzs[2][20], fa1[2][85], fa2[2][85], redv[2];

    {
        const unsigned* kv32 = (const unsigned*)(kv + (size_t)b * 40 * 128);
        for (int idx = t; idx < 2560; idx += 128){
            unsigned u = kv32[idx];
            int j   = idx >> 6;
            int c32 = idx & 63;
            if (c32 < 32) kb32[hf][j][c32] = u;
            else          vb32[hf][j][c32-32] = u;
        }
    }
    if (t < 64) xb[hf][t] = src_last[b*64 + t];
    __syncthreads();

    if (t < 64){
        float a0=0.f,a1=0.f,a2=0.f,a3=0.f;
        #pragma unroll
        for (int d = 0; d < 64; d += 4){
            a0 = fmaf(xb[hf][d+0], Wqkv[(d+0)*192 + t], a0);
            a1 = fmaf(xb[hf][d+1], Wqkv[(d+1)*192 + t], a1);
            a2 = fmaf(xb[hf][d+2], Wqkv[(d+2)*192 + t], a2);
            a3 = fmaf(xb[hf][d+3], Wqkv[(d+3)*192 + t], a3);
        }
        qs[hf][t] = (bqkv[t] + ((a0+a1)+(a2+a3))) * 0.35355339059327373f;
    }
    __syncthreads();

    float o_c = 0.f;
    if (t < 64){
        const int h = t >> 3;
        float qh[8];
        #pragma unroll
        for (int d = 0; d < 8; ++d) qh[d] = qs[hf][h*8 + d];
        float sc[40];
        float m0 = -1e30f, m1 = -1e30f;
        #pragma unroll
        for (int j = 0; j < 40; ++j){
            float a = 0.f, bb = 0.f;
            #pragma unroll
            for (int d2 = 0; d2 < 4; ++d2){
                unsigned u = kb32[hf][j][h*4 + d2];
                a  = fmaf(qh[2*d2],   blo(u), a);
                bb = fmaf(qh[2*d2+1], bhi(u), bb);
            }
            sc[j] = a + bb;
            if (j & 1) m1 = fmaxf(m1, sc[j]); else m0 = fmaxf(m0, sc[j]);
        }
        float m = fmaxf(m0, m1);
        float Z0=0.f, Z1=0.f, ac0=0.f, ac1=0.f;
        #pragma unroll
        for (int j = 0; j < 40; j += 2){
            float w0 = __expf(sc[j]   - m);
            float w1 = __expf(sc[j+1] - m);
            unsigned u0 = vb32[hf][j][t>>1], u1 = vb32[hf][j+1][t>>1];
            float v0 = (t & 1) ? bhi(u0) : blo(u0);
            float v1 = (t & 1) ? bhi(u1) : blo(u1);
            Z0 += w0; Z1 += w1;
            ac0 = fmaf(w0, v0, ac0); ac1 = fmaf(w1, v1, ac1);
        }
        o_c = (ac0 + ac1) / (Z0 + Z1);
    }
    if (t < 64) yb[hf][t] = o_c;
    __syncthreads();

    float x1 = 0.f;
    if (t < 64){
        float a0=0.f,a1=0.f,a2=0.f,a3=0.f;
        #pragma unroll
        for (int d = 0; d < 64; d += 4){
            a0 = fmaf(yb[hf][d+0], Wo[(d+0)*64+t], a0);
            a1 = fmaf(yb[hf][d+1], Wo[(d+1)*64+t], a1);
            a2 = fmaf(yb[hf][d+2], Wo[(d+2)*64+t], a2);
            a3 = fmaf(yb[hf][d+3], Wo[(d+3)*64+t], a3);
        }
        float v = xb[hf][t] + bo[t] + ((a0+a1)+(a2+a3));
        float sum = v;
        #pragma unroll
        for (int off = 1; off < 64; off <<= 1) sum += __shfl_xor(sum, off, 64);
        float mean = sum * (1.f/64.f);
        float dd = v - mean;
        float s2 = dd*dd;
        #pragma unroll
        for (int off = 1; off < 64; off <<= 1) s2 += __shfl_xor(s2, off, 64);
        float var = s2 * (1.f/64.f);
        x1 = dd * rsqrtf(var + 1e-5f) * ln1_g[t] + ln1_b[t];
    }
    __syncthreads();
    if (t < 64) xb[hf][t] = x1;
    __syncthreads();

    for (int c = t; c < 256; c += 128){
        float a0=0.f,a1=0.f,a2=0.f,a3=0.f;
        #pragma unroll
        for (int d = 0; d < 64; d += 4){
            a0 = fmaf(xb[hf][d+0], W1[(d+0)*256+c], a0);
            a1 = fmaf(xb[hf][d+1], W1[(d+1)*256+c], a1);
            a2 = fmaf(xb[hf][d+2], W1[(d+2)*256+c], a2);
            a3 = fmaf(xb[hf][d+3], W1[(d+3)*256+c], a3);
        }
        f1[hf][c] = fmaxf(b1[c] + ((a0+a1)+(a2+a3)), 0.f);
    }
    __syncthreads();

    if (t < 64){
        float a0=0.f,a1=0.f,a2=0.f,a3=0.f;
        #pragma unroll
        for (int j = 0; j < 256; j += 4){
            a0 = fmaf(f1[hf][j+0], W2[(j+0)*64+t], a0);
            a1 = fmaf(f1[hf][j+1], W2[(j+1)*64+t], a1);
            a2 = fmaf(f1[hf][j+2], W2[(j+2)*64+t], a2);
            a3 = fmaf(f1[hf][j+3], W2[(j+3)*64+t], a3);
        }
        float v = xb[hf][t] + b2[t] + ((a0+a1)+(a2+a3));
        float sum = v;
        #pragma unroll
        for (int off = 1; off < 64; off <<= 1) sum += __shfl_xor(sum, off, 64);
        float mean = sum * (1.f/64.f);
        float dd = v - mean;
        float s2 = dd*dd;
        #pragma unroll
        for (int off = 1; off < 64; off <<= 1) s2 += __shfl_xor(s2, off, 64);
        float var = s2 * (1.f/64.f);
        yb[hf][t] = dd * rsqrtf(var + 1e-5f) * ln2_g[t] + ln2_b[t];
    }
    __syncthreads();

    if (t < 64){
        float a0=0.f,a1=0.f,a2=0.f,a3=0.f;
        #pragma unroll
        for (int d = 0; d < 64; d += 4){
            a0 = fmaf(yb[hf][d+0], relu_W[(d+0)*64+t], a0);
            a1 = fmaf(yb[hf][d+1], relu_W[(d+1)*64+t], a1);
            a2 = fmaf(yb[hf][d+2], relu_W[(d+2)*64+t], a2);
            a3 = fmaf(yb[hf][d+3], relu_W[(d+3)*64+t], a3);
        }
        xrs[hf][t] = relu_b[t] + ((a0+a1)+(a2+a3));
    }
    __syncthreads();

    if (t < 64){
        float a0=0.f,a1=0.f,a2=0.f,a3=0.f;
        #pragma unroll
        for (int d = 0; d < 64; d += 4){
            a0 = fmaf(xrs[hf][d+0], nd_W[(d+0)*64+t], a0);
            a1 = fmaf(xrs[hf][d+1], nd_W[(d+1)*64+t], a1);
            a2 = fmaf(xrs[hf][d+2], nd_W[(d+2)*64+t], a2);
            a3 = fmaf(xrs[hf][d+3], nd_W[(d+3)*64+t], a3);
        }
        float a = nd_b[t] + ((a0+a1)+(a2+a3));
        float contrib = a * ldt_W[t];
        #pragma unroll
        for (int off = 1; off < 64; off <<= 1) contrib += __shfl_xor(contrib, off, 64);
        if (t == 0) redv[hf] = contrib + ldt_b[0];
    }
    __syncthreads();
    float dT = redv[hf];

    if (t < 65){
        float a0 = nz_b[t] + dT*nz_W[t], a1=0.f, a2=0.f, a3=0.f;
        #pragma unroll
        for (int d = 0; d < 64; d += 4){
            a0 = fmaf(xrs[hf][d+0], nz_W[(1+d)*65+t],   a0);
            a1 = fmaf(xrs[hf][d+1], nz_W[(2+d)*65+t],   a1);
            a2 = fmaf(xrs[hf][d+2], nz_W[(3+d)*65+t],   a2);
            a3 = fmaf(xrs[hf][d+3], nz_W[(4+d)*65+t],   a3);
        }
        m65[hf][t] = ((a0+a1)+(a2+a3));
    }
    __syncthreads();

    if (t < 20){
        float a0=0.f,a1=0.f,a2=0.f,a3=0.f;
        #pragma unroll
        for (int d = 0; d < 64; d += 4){
            a0 = fmaf(m65[hf][d+0], lz_W[(d+0)*20+t], a0);
            a1 = fmaf(m65[hf][d+1], lz_W[(d+1)*20+t], a1);
            a2 = fmaf(m65[hf][d+2], lz_W[(d+2)*20+t], a2);
            a3 = fmaf(m65[hf][d+3], lz_W[(d+3)*20+t], a3);
        }
        a0 = fmaf(m65[hf][64], lz_W[64*20+t], a0);
        mzs[hf][t] = lz_b[t] + ((a0+a1)+(a2+a3));
    }
    __syncthreads();

    if (t < 85){
        float a0=0.f,a1=0.f,a2=0.f,a3=0.f;
        #pragma unroll
        for (int d = 0; d < 20; d += 4){
            a0 = fmaf(mzs[hf][d+0], na0_W[(d+0)*85+t], a0);
            a1 = fmaf(mzs[hf][d+1], na0_W[(d+1)*85+t], a1);
            a2 = fmaf(mzs[hf][d+2], na0_W[(d+2)*85+t], a2);
            a3 = fmaf(mzs[hf][d+3], na0_W[(d+3)*85+t], a3);
        }
        a0 = fmaf(dT, na0_W[20*85+t], a0);
        #pragma unroll
        for (int d = 0; d < 64; d += 4){
            a0 = fmaf(xrs[hf][d+0], na0_W[(21+d)*85+t], a0);
            a1 = fmaf(xrs[hf][d+1], na0_W[(22+d)*85+t], a1);
            a2 = fmaf(xrs[hf][d+2], na0_W[(23+d)*85+t], a2);
            a3 = fmaf(xrs[hf][d+3], na0_W[(24+d)*85+t], a3);
        }
        fa1[hf][t] = na0_b[t] + ((a0+a1)+(a2+a3));
    }
    __syncthreads();
    if (t < 85){
        float a0=0.f,a1=0.f,a2=0.f,a3=0.f;
        #pragma unroll
        for (int d = 0; d < 84; d += 4){
            a0 = fmaf(fa1[hf][d+0], na1_W[(d+0)*85+t], a0);
            a1 = fmaf(fa1[hf][d+1], na1_W[(d+1)*85+t], a1);
            a2 = fmaf(fa1[hf][d+2], na1_W[(d+2)*85+t], a2);
            a3 = fmaf(fa1[hf][d+3], na1_W[(d+3)*85+t], a3);
        }
        a0 = fmaf(fa1[hf][84], na1_W[84*85+t], a0);
        fa2[hf][t] = na1_b[t] + ((a0+a1)+(a2+a3));
    }
    __syncthreads();

    if (t == 0) out[b*26] = dT;
    if (t < 20) out[b*26 + 1 + t] = mzs[hf][t];
    if (t < 5){
        float a0=0.f,a1=0.f,a2=0.f,a3=0.f;
        #pragma unroll
        for (int d = 0; d < 84; d += 4){
            a0 = fmaf(fa2[hf][d+0], la_W[(d+0)*5+t], a0);
            a1 = fmaf(fa2[hf][d+1], la_W[(d+1)*5+t], a1);
            a2 = fmaf(fa2[hf][d+2], la_W[(d+2)*5+t], a2);
            a3 = fmaf(fa2[hf][d+3], la_W[(d+3)*5+t], a3);
        }
        a0 = fmaf(fa2[hf][84], la_W[84*5+t], a0);
        out[b*26 + 21 + t] = la_b[t] + ((a0+a1)+(a2+a3));
    }
}

extern "C" void kernel_launch(void* const* d_in, const int* in_sizes, int n_in,
                              void* d_out, int out_size, void* d_ws, size_t ws_size,
                              hipStream_t stream)
{
    const float* X        = (const float*)d_in[0];
    const float* emb_act  = (const float*)d_in[1];
    const float* emb_zone = (const float*)d_in[2];
    const float* lin0_W   = (const float*)d_in[3];
    const float* lin0_b   = (const float*)d_in[4];
    const float* gat_W    = (const float*)d_in[5];
    const float* gat_b    = (const float*)d_in[6];
    const float* gat_a    = (const float*)d_in[7];
    const float* gl0_W    = (const float*)d_in[8];
    const float* gl0_b    = (const float*)d_in[9];
    const float* gl1_W    = (const float*)d_in[10];
    const float* gl1_b    = (const float*)d_in[11];
    const float* gl2_W    = (const float*)d_in[12];
    const float* gl2_b    = (const float*)d_in[13];
    const float* Wqkv     = (const float*)d_in[14];
    const float* bqkv     = (const float*)d_in[15];
    const float* Wo       = (const float*)d_in[16];
    const float* bo       = (const float*)d_in[17];
    const float* ln1_g    = (const float*)d_in[18];
    const float* ln1_b    = (const float*)d_in[19];
    const float* W1       = (const float*)d_in[20];
    const float* b1       = (const float*)d_in[21];
    const float* W2       = (const float*)d_in[22];
    const float* b2       = (const float*)d_in[23];
    const float* ln2_g    = (const float*)d_in[24];
    const float* ln2_b    = (const float*)d_in[25];
    const float* relu_W   = (const float*)d_in[26];
    const float* relu_b   = (const float*)d_in[27];
    const float* nd_W     = (const float*)d_in[28];
    const float* nd_b     = (const float*)d_in[29];
    const float* ldt_W    = (const float*)d_in[30];
    const float* ldt_b    = (const float*)d_in[31];
    const float* nz_W     = (const float*)d_in[32];
    const float* nz_b     = (const float*)d_in[33];
    const float* lz_W     = (const float*)d_in[34];
    const float* lz_b     = (const float*)d_in[35];
    const float* na0_W    = (const float*)d_in[36];
    const float* na0_b    = (const float*)d_in[37];
    const float* na1_W    = (const float*)d_in[38];
    const float* na1_b    = (const float*)d_in[39];
    const float* la_W     = (const float*)d_in[40];
    const float* la_b     = (const float*)d_in[41];

    bf16*  kv       = (bf16*)d_ws;
    float* src_last = (float*)((char*)d_ws + (size_t)NTOK * 128 * sizeof(bf16));
    uint4* packW    = (uint4*)((char*)d_ws + (size_t)NTOK * 128 * sizeof(bf16) + (size_t)B_ * 64 * sizeof(float));

    k_pack<<<(PK_TOT + 255)/256, 256, 0, stream>>>(gl0_W, gl1_W, gl2_W, Wqkv, packW);

    k_token<<<NTOK/TOKB, TPB, 0, stream>>>(X, emb_act, emb_zone, lin0_W, lin0_b,
        gat_W, gat_b, gat_a, gl0_b, gl1_b, gl2_b, bqkv, packW, kv, src_last);

    k_head<<<B_/2, 256, 0, stream>>>(kv, src_last, Wqkv, bqkv, Wo, bo,
        ln1_g, ln1_b, W1, b1, W2, b2, ln2_g, ln2_b, relu_W, relu_b,
        nd_W, nd_b, ldt_W, ldt_b, nz_W, nz_b, lz_W, lz_b,
        na0_W, na0_b, na1_W, na1_b, la_W, la_b, (float*)d_out);
}

// Round 7
// 78.287 us; speedup vs baseline: 2.3541x; 1.8061x over previous
//
#include <hip/hip_runtime.h>
#include <hip/hip_bf16.h>

typedef __hip_bfloat16 bf16;
typedef float f32x4 __attribute__((ext_vector_type(4)));
typedef short s16x8 __attribute__((ext_vector_type(8)));

#define B_    2048
#define S_    40
#define NTOK  (B_*S_)
#define TPB   256
#define TOKB  64

// ---- k_token LDS layout (dwords). A1 aliases FF (FF dead after phase 1).
#define FF_OFF    0
#define A1_OFFD   0
#define A0_OFFD   4288
#define PE_OFFD   8384
#define LDS_DW    8448

#define A0B (A0_OFFD*4)
#define A1B (A1_OFFD*4)

// ---- packW (token) fragment offsets (uint4 units)
#define PK_GL0 0
#define PK_GL1 1024
#define PK_GL2 1536
#define PK_KV  1664
#define PK_TOT 2688

// ---- packH (head) fragment offsets (uint4 units)
#define H_WQ   0       // Wqkv cols0..63 K64 S2 NB4  -> 512
#define H_WO   512     // Wo   K64 S2 NB4            -> 512
#define H_W1   1024    // W1   K64 S2 NB16           -> 2048
#define H_W2   3072    // W2   K256 S8 NB4           -> 2048
#define H_RELU 5120    // relu_W                      -> 512
#define H_ND   5632    // nd_W                        -> 512
#define H_NZ   6144    // nz_W K65 S3 NB5            -> 960
#define H_LZ   7104    // lz_W K65 S3 NB2            -> 384
#define H_NA0  7488    // na0_W K85 S3 NB6           -> 1152
#define H_NA1  8640    // na1_W                       -> 1152
#define H_LA   9792    // la_W K85 S3 NB1            -> 192
#define H_TOT  9984

__device__ inline unsigned pk2(float a, float b){
    __hip_bfloat16 ha = __float2bfloat16(a), hb = __float2bfloat16(b);
    unsigned short ua = *reinterpret_cast<unsigned short*>(&ha);
    unsigned short ub = *reinterpret_cast<unsigned short*>(&hb);
    return (unsigned)ua | ((unsigned)ub << 16);
}
__device__ inline float blo(unsigned u){ return __uint_as_float(u << 16); }
__device__ inline float bhi(unsigned u){ return __uint_as_float(u & 0xffff0000u); }

__device__ inline f32x4 MFMA(uint4 a, uint4 b, f32x4 c){
    union { uint4 q; s16x8 s; } A, Bv;
    A.q = a; Bv.q = b;
    return __builtin_amdgcn_mfma_f32_16x16x32_bf16(A.s, Bv.s, c, 0, 0, 0);
}

__device__ inline uint4 packB(const float* W, int ld, int K, int N, int nb, int S, int lane){
    int half = lane >> 4, c15 = lane & 15;
    int col = nb*16 + c15;
    unsigned pr[4];
    #pragma unroll
    for (int jj = 0; jj < 4; ++jj){
        int k0 = S*32 + half*8 + 2*jj;
        float v0 = (k0   < K && col < N) ? W[(size_t)k0*ld + col]     : 0.f;
        float v1 = (k0+1 < K && col < N) ? W[(size_t)(k0+1)*ld + col] : 0.f;
        pr[jj] = pk2(v0, v1);
    }
    return (uint4){pr[0], pr[1], pr[2], pr[3]};
}

// ---------------- Kernel 0: pre-pack ALL weight fragments ----------------
__global__ __launch_bounds__(256) void k_pack_all(
    const float* __restrict__ gl0_W, const float* __restrict__ gl1_W,
    const float* __restrict__ gl2_W, const float* __restrict__ Wqkv,
    const float* __restrict__ Wo,    const float* __restrict__ W1,
    const float* __restrict__ W2,    const float* __restrict__ relu_W,
    const float* __restrict__ nd_W,  const float* __restrict__ nz_W,
    const float* __restrict__ lz_W,  const float* __restrict__ na0_W,
    const float* __restrict__ na1_W, const float* __restrict__ la_W,
    uint4* __restrict__ packW, uint4* __restrict__ packH)
{
    int f = blockIdx.x * 256 + threadIdx.x;
    if (f < PK_TOT){
        unsigned pr[4];
        if (f < PK_GL1){
            int w = f >> 8, r = f & 255, S = r >> 6, lane = r & 63;
            int half = lane >> 4, c15 = lane & 15, col = w * 16 + c15;
            #pragma unroll
            for (int jj = 0; jj < 4; ++jj){
                int k0 = S*32 + half*8 + 2*jj;
                float v0 = (k0   < 110) ? gl0_W[k0*64 + col]     : 0.f;
                float v1 = (k0+1 < 110) ? gl0_W[(k0+1)*64 + col] : 0.f;
                pr[jj] = pk2(v0, v1);
            }
        } else if (f < PK_GL2){
            int g = f - PK_GL1, w = g >> 7, r = g & 127, S = r >> 6, lane = r & 63;
            int half = lane >> 4, c15 = lane & 15, col = w * 16 + c15;
            #pragma unroll
            for (int jj = 0; jj < 4; ++jj){
                int k0 = S*32 + half*8 + 2*jj;
                pr[jj] = pk2(gl1_W[k0*64 + col], gl1_W[(k0+1)*64 + col]);
            }
        } else if (f < PK_KV){
            int g = f - PK_GL2, S = g >> 6, lane = g & 63;
            int half = lane >> 4, c15 = lane & 15;
            #pragma unroll
            for (int jj = 0; jj < 4; ++jj){
                int k0 = S*32 + half*8 + 2*jj;
                pr[jj] = pk2(gl2_W[k0*16 + c15], gl2_W[(k0+1)*16 + c15]);
            }
        } else {
            int g = f - PK_KV, w = g >> 8, r = g & 255, cf = r >> 7, r2 = r & 127;
            int S = r2 >> 6, lane = r2 & 63;
            int half = lane >> 4, c15 = lane & 15, col = 64 + w*32 + cf*16 + c15;
            #pragma unroll
            for (int jj = 0; jj < 4; ++jj){
                int k0 = S*32 + half*8 + 2*jj;
                pr[jj] = pk2(Wqkv[k0*192 + col], Wqkv[(k0+1)*192 + col]);
            }
        }
        packW[f] = (uint4){pr[0], pr[1], pr[2], pr[3]};
        return;
    }
    int f2 = f - PK_TOT;
    if (f2 >= H_TOT) return;
    const float* W; int ld, K, N, St, base;
    if      (f2 < H_WO ){ W=Wqkv;   ld=192; K=64;  N=64;  St=2; base=H_WQ;  }
    else if (f2 < H_W1 ){ W=Wo;     ld=64;  K=64;  N=64;  St=2; base=H_WO;  }
    else if (f2 < H_W2 ){ W=W1;     ld=256; K=64;  N=256; St=2; base=H_W1;  }
    else if (f2 < H_RELU){W=W2;     ld=64;  K=256; N=64;  St=8; base=H_W2;  }
    else if (f2 < H_ND ){ W=relu_W; ld=64;  K=64;  N=64;  St=2; base=H_RELU;}
    else if (f2 < H_NZ ){ W=nd_W;   ld=64;  K=64;  N=64;  St=2; base=H_ND;  }
    else if (f2 < H_LZ ){ W=nz_W;   ld=65;  K=65;  N=65;  St=3; base=H_NZ;  }
    else if (f2 < H_NA0){ W=lz_W;   ld=20;  K=65;  N=20;  St=3; base=H_LZ;  }
    else if (f2 < H_NA1){ W=na0_W;  ld=85;  K=85;  N=85;  St=3; base=H_NA0; }
    else if (f2 < H_LA ){ W=na1_W;  ld=85;  K=85;  N=85;  St=3; base=H_NA1; }
    else               { W=la_W;   ld=5;   K=85;  N=5;   St=3; base=H_LA;  }
    int loc = f2 - base;
    int nb = loc / (St*64);
    int rem = loc - nb*St*64;
    packH[f2] = packB(W, ld, K, N, nb, rem >> 6, rem & 63);
}

// ---------------- Kernel 1: MFMA featurizer (unchanged from R6) ----------------
__global__ __launch_bounds__(TPB) void k_token(
    const float* __restrict__ X,
    const float* __restrict__ emb_act,
    const float* __restrict__ emb_zone,
    const float* __restrict__ lin0_W, const float* __restrict__ lin0_b,
    const float* __restrict__ gat_W,  const float* __restrict__ gat_b,
    const float* __restrict__ gat_a,
    const float* __restrict__ gl0_b,  const float* __restrict__ gl1_b,
    const float* __restrict__ gl2_b,  const float* __restrict__ bqkv,
    const uint4* __restrict__ packW,
    bf16* __restrict__ kv, float* __restrict__ src_last)
{
    __shared__ unsigned L[LDS_DW];
    char* Lb = (char*)L;

    const int t    = threadIdx.x;
    const int w    = t >> 6;
    const int lane = t & 63;
    const int half = (lane >> 4);
    const int c15  = lane & 15;
    const int blk0 = blockIdx.x * TOKB;
    const int swzc = (c15 & 7) << 4;

    for (int task = t; task < TOKB * 22; task += TPB){
        int tt = task / 22;
        int r  = task - tt * 22;
        const float* xp = X + (size_t)(blk0 + tt) * 118 + 8 + r * 5;
        float f0 = xp[0], f1 = xp[1], f2 = xp[2], f3 = xp[3], f4 = xp[4];
        unsigned* dst = &L[FF_OFF + tt * 67 + 3 * r];
        dst[0] = pk2(f0, f1); dst[1] = pk2(f2, f3); dst[2] = pk2(f4, 0.f);
    }
    for (int idx = t; idx < 64 * 9; idx += TPB){
        int row = idx / 9, p = idx - row * 9;
        *(unsigned*)(Lb + A0B + row * 256 + ((220 + 4*p) ^ ((row & 7) << 4))) = 0u;
    }
    float hd[8];
    {
        const float2* xp = (const float2*)(X + (size_t)(blk0 + lane) * 118);
        #pragma unroll
        for (int p = 0; p < 4; ++p){ float2 v = xp[p]; hd[2*p] = v.x; hd[2*p+1] = v.y; }
    }
    if (t < TOKB){
        int tok = blk0 + t;
        int b = tok / 40, s = tok - b * 40;
        float denom = powf(100.0f, (2.0f * (float)s) / 40.0f);
        float ang   = (float)b / denom;
        float pe    = ((s & 1) == 0) ? sinf(ang) : cosf(ang);
        ((float*)&L[PE_OFFD])[t] = pe;
    }
    __syncthreads();

    {
        const unsigned tb = FF_OFF + lane * 67;
        float va1[5], va2[5];
        float cc1 = 0.f, cc2 = 0.f;
        #pragma unroll
        for (int e = 0; e < 5; ++e){
            float u1 = 0.f, u2 = 0.f;
            #pragma unroll
            for (int d = 0; d < 5; ++d){
                u1 += gat_W[e*5+d] * gat_a[d];
                u2 += gat_W[e*5+d] * gat_a[5+d];
            }
            va1[e] = u1; va2[e] = u2;
        }
        #pragma unroll
        for (int d = 0; d < 5; ++d){ cc1 += gat_b[d]*gat_a[d]; cc2 += gat_b[d]*gat_a[5+d]; }

        float s2v[22];
        float m2 = -1e30f;
        #pragma unroll
        for (int j = 0; j < 22; ++j){
            unsigned u0 = L[tb + 3*j], u1 = L[tb + 3*j + 1], u2 = L[tb + 3*j + 2];
            float f0 = blo(u0), f1 = bhi(u0), f2 = blo(u1), f3 = bhi(u1), f4 = blo(u2);
            s2v[j] = cc2 + f0*va2[0] + f1*va2[1] + f2*va2[2] + f3*va2[3] + f4*va2[4];
            m2 = fmaxf(m2, s2v[j]);
        }

        const int wbase = w * 6;

        float s1own[6], mi[6], Z[6], ffp[6][5];
        #pragma unroll
        for (int ii = 0; ii < 6; ++ii){
            int i = wbase + ii; if (i > 21) i = 21;
            unsigned u0 = L[tb + 3*i], u1 = L[tb + 3*i + 1], u2 = L[tb + 3*i + 2];
            float f0 = blo(u0), f1 = bhi(u0), f2 = blo(u1), f3 = bhi(u1), f4 = blo(u2);
            float s1 = cc1 + f0*va1[0] + f1*va1[1] + f2*va1[2] + f3*va1[3] + f4*va1[4];
            s1own[ii] = s1;
            float em = s1 + m2;
            mi[ii] = fmaxf(em, 0.2f * em);
            Z[ii] = 0.f;
            #pragma unroll
            for (int e = 0; e < 5; ++e) ffp[ii][e] = 0.f;
        }

        #pragma unroll
        for (int j = 0; j < 22; ++j){
            unsigned u0 = L[tb + 3*j], u1 = L[tb + 3*j + 1], u2 = L[tb + 3*j + 2];
            float f0 = blo(u0), f1 = bhi(u0), f2 = blo(u1), f3 = bhi(u1), f4 = blo(u2);
            #pragma unroll
            for (int ii = 0; ii < 6; ++ii){
                float e2 = s1own[ii] + s2v[j];
                float lr = fmaxf(e2, 0.2f * e2);
                float wg = __expf(lr - mi[ii]);
                Z[ii] += wg;
                ffp[ii][0] = fmaf(wg, f0, ffp[ii][0]);
                ffp[ii][1] = fmaf(wg, f1, ffp[ii][1]);
                ffp[ii][2] = fmaf(wg, f2, ffp[ii][2]);
                ffp[ii][3] = fmaf(wg, f3, ffp[ii][3]);
                ffp[ii][4] = fmaf(wg, f4, ffp[ii][4]);
            }
        }

        const int rswz = (lane & 7) << 4;
        #pragma unroll
        for (int ii = 0; ii < 6; ++ii){
            int i = wbase + ii;
            if (i < 22){
                float rz = 1.f / Z[ii];
                #pragma unroll
                for (int d = 0; d < 5; ++d){
                    float u = 0.f;
                    #pragma unroll
                    for (int e = 0; e < 5; ++e) u += ffp[ii][e] * gat_W[e*5+d];
                    float h = u * rz + gat_b[d];
                    *(bf16*)(Lb + A0B + lane*256 + ((10*i + 2*d) ^ rswz)) = __float2bfloat16(h);
                }
            }
        }
    }
    __syncthreads();

    {
        uint4 bfr[4];
        #pragma unroll
        for (int S = 0; S < 4; ++S) bfr[S] = packW[PK_GL0 + (w*4 + S)*64 + lane];
        const int col = w * 16 + c15;
        float bias = gl0_b[col];
        f32x4 ac0 = {bias,bias,bias,bias}, ac1 = ac0, ac2 = ac0, ac3 = ac0;
        #pragma unroll
        for (int S = 0; S < 4; ++S){
            int koff = S*64 + half*16;
            uint4 a0 = *(const uint4*)(Lb + A0B + (0*16 + c15)*256 + (koff ^ swzc));
            uint4 a1 = *(const uint4*)(Lb + A0B + (1*16 + c15)*256 + (koff ^ swzc));
            uint4 a2 = *(const uint4*)(Lb + A0B + (2*16 + c15)*256 + (koff ^ swzc));
            uint4 a3 = *(const uint4*)(Lb + A0B + (3*16 + c15)*256 + (koff ^ swzc));
            ac0 = MFMA(a0, bfr[S], ac0);
            ac1 = MFMA(a1, bfr[S], ac1);
            ac2 = MFMA(a2, bfr[S], ac2);
            ac3 = MFMA(a3, bfr[S], ac3);
        }
        const int off = col * 2;
        #pragma unroll
        for (int r = 0; r < 4; ++r){
            int row0 = 0*16 + half*4 + r;
            int row1 = 1*16 + half*4 + r;
            int row2 = 2*16 + half*4 + r;
            int row3 = 3*16 + half*4 + r;
            *(bf16*)(Lb + A1B + row0*128 + (off ^ ((row0 & 7) << 4))) = __float2bfloat16(fmaxf(ac0[r], 0.f));
            *(bf16*)(Lb + A1B + row1*128 + (off ^ ((row1 & 7) << 4))) = __float2bfloat16(fmaxf(ac1[r], 0.f));
            *(bf16*)(Lb + A1B + row2*128 + (off ^ ((row2 & 7) << 4))) = __float2bfloat16(fmaxf(ac2[r], 0.f));
            *(bf16*)(Lb + A1B + row3*128 + (off ^ ((row3 & 7) << 4))) = __float2bfloat16(fmaxf(ac3[r], 0.f));
        }
    }
    __syncthreads();

    {
        uint4 bfr[2];
        #pragma unroll
        for (int S = 0; S < 2; ++S) bfr[S] = packW[PK_GL1 + (w*2 + S)*64 + lane];
        const int col = w * 16 + c15;
        float bias = gl1_b[col];
        f32x4 ac0 = {bias,bias,bias,bias}, ac1 = ac0, ac2 = ac0, ac3 = ac0;
        #pragma unroll
        for (int S = 0; S < 2; ++S){
            int koff = S*64 + half*16;
            uint4 a0 = *(const uint4*)(Lb + A1B + (0*16 + c15)*128 + (koff ^ swzc));
            uint4 a1 = *(const uint4*)(Lb + A1B + (1*16 + c15)*128 + (koff ^ swzc));
            uint4 a2 = *(const uint4*)(Lb + A1B + (2*16 + c15)*128 + (koff ^ swzc));
            uint4 a3 = *(const uint4*)(Lb + A1B + (3*16 + c15)*128 + (koff ^ swzc));
            ac0 = MFMA(a0, bfr[S], ac0);
            ac1 = MFMA(a1, bfr[S], ac1);
            ac2 = MFMA(a2, bfr[S], ac2);
            ac3 = MFMA(a3, bfr[S], ac3);
        }
        const int off = col * 2;
        #pragma unroll
        for (int r = 0; r < 4; ++r){
            int row0 = 0*16 + half*4 + r;
            int row1 = 1*16 + half*4 + r;
            int row2 = 2*16 + half*4 + r;
            int row3 = 3*16 + half*4 + r;
            *(bf16*)(Lb + A0B + row0*128 + (off ^ ((row0 & 7) << 4))) = __float2bfloat16(fmaxf(ac0[r], 0.f));
            *(bf16*)(Lb + A0B + row1*128 + (off ^ ((row1 & 7) << 4))) = __float2bfloat16(fmaxf(ac1[r], 0.f));
            *(bf16*)(Lb + A0B + row2*128 + (off ^ ((row2 & 7) << 4))) = __float2bfloat16(fmaxf(ac2[r], 0.f));
            *(bf16*)(Lb + A0B + row3*128 + (off ^ ((row3 & 7) << 4))) = __float2bfloat16(fmaxf(ac3[r], 0.f));
        }
    }
    __syncthreads();

    {
        uint4 bfr[2];
        #pragma unroll
        for (int S = 0; S < 2; ++S) bfr[S] = packW[PK_GL2 + S*64 + lane];
        float bias = gl2_b[c15];
        f32x4 ac = {bias,bias,bias,bias};
        #pragma unroll
        for (int S = 0; S < 2; ++S){
            int koff = S*64 + half*16;
            uint4 a = *(const uint4*)(Lb + A0B + (w*16 + c15)*128 + (koff ^ swzc));
            ac = MFMA(a, bfr[S], ac);
        }
        const float* pef = (const float*)&L[PE_OFFD];
        const int off = (48 + c15) * 2;
        #pragma unroll
        for (int r = 0; r < 4; ++r){
            int row = w*16 + half*4 + r;
            float v = fmaxf(ac[r], 0.f) + pef[row];
            *(bf16*)(Lb + A1B + row*128 + (off ^ ((row & 7) << 4))) = __float2bfloat16(v);
        }

        float pe = pef[lane];
        int ia = (int)hd[0], iz = (int)hd[1];
        const int tswz = (lane & 7) << 4;
        #pragma unroll
        for (int pp = 0; pp < 6; ++pp){
            int p = w * 6 + pp;
            int c0 = 2 * p;
            float v0, v1;
            if (p < 8)        { v0 = emb_act[ia*16 + c0];        v1 = emb_act[ia*16 + c0 + 1]; }
            else if (p < 16)  { v0 = emb_zone[iz*16 + c0 - 16];  v1 = emb_zone[iz*16 + c0 - 15]; }
            else {
                int cc = c0 - 32;
                float o0 = lin0_b[cc], o1 = lin0_b[cc+1];
                #pragma unroll
                for (int e = 0; e < 6; ++e){
                    float f = hd[2 + e];
                    o0 = fmaf(f, lin0_W[e*16 + cc], o0);
                    o1 = fmaf(f, lin0_W[e*16 + cc + 1], o1);
                }
                v0 = o0; v1 = o1;
            }
            *(unsigned*)(Lb + A1B + lane*128 + ((4*p) ^ tswz)) = pk2(v0 + pe, v1 + pe);
        }
    }
    __syncthreads();

    {
        int r0 = 39 - (blk0 % 40);
        if (t < 128){
            int tok = r0 + 40 * (t >> 6);
            if (tok < 64){
                int col = t & 63;
                bf16 hv = *(const bf16*)(Lb + A1B + tok*128 + ((col*2) ^ ((tok & 7) << 4)));
                src_last[(size_t)((blk0 + tok) / 40) * 64 + col] = __bfloat162float(hv);
            }
        }

        uint4 bfk[2][2];
        #pragma unroll
        for (int cf = 0; cf < 2; ++cf)
            #pragma unroll
            for (int S = 0; S < 2; ++S)
                bfk[cf][S] = packW[PK_KV + ((w*2 + cf)*2 + S)*64 + lane];

        float b0v = bqkv[64 + w*32 + c15];
        float b1v = bqkv[64 + w*32 + 16 + c15];
        f32x4 acc[4][2];
        #pragma unroll
        for (int R = 0; R < 4; ++R){
            acc[R][0] = (f32x4){b0v, b0v, b0v, b0v};
            acc[R][1] = (f32x4){b1v, b1v, b1v, b1v};
        }
        #pragma unroll
        for (int S = 0; S < 2; ++S){
            int koff = S*64 + half*16;
            #pragma unroll
            for (int R = 0; R < 4; ++R){
                uint4 a = *(const uint4*)(Lb + A1B + (R*16 + c15)*128 + (koff ^ swzc));
                acc[R][0] = MFMA(a, bfk[0][S], acc[R][0]);
                acc[R][1] = MFMA(a, bfk[1][S], acc[R][1]);
            }
        }
        #pragma unroll
        for (int R = 0; R < 4; ++R){
            #pragma unroll
            for (int cf = 0; cf < 2; ++cf){
                int lcol = w*32 + cf*16 + c15;
                int off = lcol * 2;
                #pragma unroll
                for (int r = 0; r < 4; ++r){
                    int row = R*16 + half*4 + r;
                    *(bf16*)(Lb + A0B + row*256 + (off ^ ((row & 7) << 4))) = __float2bfloat16(acc[R][cf][r]);
                }
            }
        }
    }
    __syncthreads();

    {
        int row = t >> 2;
        int q = t & 3;
        #pragma unroll
        for (int c = 0; c < 4; ++c){
            int chunk = q*4 + c;
            uint4 d = *(const uint4*)(Lb + A0B + row*256 + ((chunk*16) ^ ((row & 7) << 4)));
            *((uint4*)(kv + (size_t)(blk0 + row) * 128 + chunk * 8)) = d;
        }
    }
}

// ---------------- Kernel 2: MFMA head (32 batches/block) ----------------
#define T0B 0
#define T1B 8192
#define TQB 16384
#define XRB 24576
#define XFB 32768
#define TFB 40960
#define DTS 57344

#define TBA(base, row, col) (Lb + (base) + (row)*256 + ((((col)*2)) ^ (((row)&7)<<4)))
#define TFA(row, col)       (Lb + TFB   + (row)*512 + ((((col)*2)) ^ (((row)&7)<<4)))
#define XFA(row, col)       (Lb + XFB   + (row)*256 + ((((col)*4)) ^ (((row)&7)<<4)))

#define UNPK(u, arr) { arr[0]=blo(u.x); arr[1]=bhi(u.x); arr[2]=blo(u.y); arr[3]=bhi(u.y); \
                       arr[4]=blo(u.z); arr[5]=bhi(u.z); arr[6]=blo(u.w); arr[7]=bhi(u.w); }

__global__ __launch_bounds__(256) void k_head2(
    const bf16* __restrict__ kv, const float* __restrict__ src_last,
    const uint4* __restrict__ packH,
    const float* __restrict__ bqkv,  const float* __restrict__ bo,
    const float* __restrict__ ln1_g, const float* __restrict__ ln1_b,
    const float* __restrict__ b1,    const float* __restrict__ b2,
    const float* __restrict__ ln2_g, const float* __restrict__ ln2_b,
    const float* __restrict__ relu_b, const float* __restrict__ nd_b,
    const float* __restrict__ ldt_W, const float* __restrict__ ldt_b,
    const float* __restrict__ nz_b,  const float* __restrict__ lz_b,
    const float* __restrict__ na0_b, const float* __restrict__ na1_b,
    const float* __restrict__ la_b,
    float* __restrict__ out)
{
    __shared__ uint4 Lsh[3592];   // 57472 B
    char* Lb = (char*)Lsh;
    float* dTs = (float*)(Lb + DTS);

    const int t    = threadIdx.x;
    const int w    = t >> 6;
    const int lane = t & 63;
    const int half = lane >> 4;
    const int c15  = lane & 15;
    const int B0   = blockIdx.x * 32;
    const int bb   = t >> 3;        // 0..31 (row-parallel phases)
    const int g    = t & 7;
    const int gb   = B0 + bb;

    // ---- P0: load src rows -> XF (f32) + T0 (bf16)
    {
        const float4* sp = (const float4*)(src_last + (size_t)gb * 64 + g * 8);
        float4 v0 = sp[0], v1 = sp[1];
        *(float4*)XFA(bb, g*8)     = v0;
        *(float4*)XFA(bb, g*8 + 4) = v1;
        uint4 u;
        u.x = pk2(v0.x, v0.y); u.y = pk2(v0.z, v0.w);
        u.z = pk2(v1.x, v1.y); u.w = pk2(v1.z, v1.w);
        *(uint4*)TBA(T0B, bb, g*8) = u;
    }
    __syncthreads();

    // ---- P1: q = (src@Wq + bq) * 1/sqrt(8) -> TQ
    {
        int col = w*16 + c15;
        float bias = bqkv[col];
        f32x4 ac0 = {bias,bias,bias,bias}, ac1 = ac0;
        #pragma unroll
        for (int S = 0; S < 2; ++S){
            uint4 bfv = packH[H_WQ + (w*2 + S)*64 + lane];
            uint4 a0 = *(const uint4*)TBA(T0B, c15,      S*32 + half*8);
            uint4 a1 = *(const uint4*)TBA(T0B, 16 + c15, S*32 + half*8);
            ac0 = MFMA(a0, bfv, ac0); ac1 = MFMA(a1, bfv, ac1);
        }
        #pragma unroll
        for (int r = 0; r < 4; ++r){
            *(bf16*)TBA(TQB, half*4 + r,      col) = __float2bfloat16(ac0[r] * 0.35355339059327373f);
            *(bf16*)TBA(TQB, 16 + half*4 + r, col) = __float2bfloat16(ac1[r] * 0.35355339059327373f);
        }
    }
    __syncthreads();

    // ---- P2: attention, one (batch, head) pair per thread -> T1
    {
        int pb = t >> 3, h = t & 7;
        int gpb = B0 + pb;
        uint4 qu = *(const uint4*)TBA(TQB, pb, h*8);
        float qh[8]; UNPK(qu, qh);
        const uint4* kp = (const uint4*)(kv + (size_t)gpb * 40 * 128 + h*8);
        const uint4* vp = (const uint4*)(kv + (size_t)gpb * 40 * 128 + 64 + h*8);
        float sc[40];
        float m = -1e30f;
        #pragma unroll 4
        for (int j = 0; j < 40; ++j){
            uint4 ku = kp[j*16];
            float kf[8]; UNPK(ku, kf);
            float a = qh[0]*kf[0] + qh[1]*kf[1] + qh[2]*kf[2] + qh[3]*kf[3]
                    + qh[4]*kf[4] + qh[5]*kf[5] + qh[6]*kf[6] + qh[7]*kf[7];
            sc[j] = a; m = fmaxf(m, a);
        }
        float Z = 0.f;
        float o[8] = {0.f,0.f,0.f,0.f,0.f,0.f,0.f,0.f};
        #pragma unroll 4
        for (int j = 0; j < 40; ++j){
            float wj = __expf(sc[j] - m);
            Z += wj;
            uint4 vu = vp[j*16];
            float vf[8]; UNPK(vu, vf);
            #pragma unroll
            for (int d = 0; d < 8; ++d) o[d] = fmaf(wj, vf[d], o[d]);
        }
        float rz = 1.f / Z;
        uint4 u;
        u.x = pk2(o[0]*rz, o[1]*rz); u.y = pk2(o[2]*rz, o[3]*rz);
        u.z = pk2(o[4]*rz, o[5]*rz); u.w = pk2(o[6]*rz, o[7]*rz);
        *(uint4*)TBA(T1B, pb, h*8) = u;
    }
    __syncthreads();

    // ---- P3: Wo + residual: XF += T1@Wo + bo
    {
        int col = w*16 + c15;
        float bias = bo[col];
        f32x4 ac0 = {bias,bias,bias,bias}, ac1 = ac0;
        #pragma unroll
        for (int S = 0; S < 2; ++S){
            uint4 bfv = packH[H_WO + (w*2 + S)*64 + lane];
            uint4 a0 = *(const uint4*)TBA(T1B, c15,      S*32 + half*8);
            uint4 a1 = *(const uint4*)TBA(T1B, 16 + c15, S*32 + half*8);
            ac0 = MFMA(a0, bfv, ac0); ac1 = MFMA(a1, bfv, ac1);
        }
        #pragma unroll
        for (int r = 0; r < 4; ++r){
            *(float*)XFA(half*4 + r,      col) += ac0[r];
            *(float*)XFA(16 + half*4 + r, col) += ac1[r];
        }
    }
    __syncthreads();

    // ---- P4: LN1 -> T0 (bf16) + XF (f32, x1)
    {
        float4 v0 = *(const float4*)XFA(bb, g*8);
        float4 v1 = *(const float4*)XFA(bb, g*8 + 4);
        float vv[8] = {v0.x, v0.y, v0.z, v0.w, v1.x, v1.y, v1.z, v1.w};
        float s = 0.f, s2 = 0.f;
        #pragma unroll
        for (int j = 0; j < 8; ++j){ s += vv[j]; s2 += vv[j]*vv[j]; }
        #pragma unroll
        for (int msk = 1; msk < 8; msk <<= 1){ s += __shfl_xor(s, msk, 8); s2 += __shfl_xor(s2, msk, 8); }
        float mean = s * (1.f/64.f);
        float var  = s2 * (1.f/64.f) - mean*mean;
        float rstd = rsqrtf(var + 1e-5f);
        float xf[8];
        #pragma unroll
        for (int j = 0; j < 8; ++j){
            int c = g*8 + j;
            xf[j] = (vv[j] - mean) * rstd * ln1_g[c] + ln1_b[c];
        }
        uint4 u;
        u.x = pk2(xf[0], xf[1]); u.y = pk2(xf[2], xf[3]);
        u.z = pk2(xf[4], xf[5]); u.w = pk2(xf[6], xf[7]);
        *(uint4*)TBA(T0B, bb, g*8) = u;
        *(float4*)XFA(bb, g*8)     = (float4){xf[0], xf[1], xf[2], xf[3]};
        *(float4*)XFA(bb, g*8 + 4) = (float4){xf[4], xf[5], xf[6], xf[7]};
    }
    __syncthreads();

    // ---- P5: f1 = relu(x1@W1 + b1) -> TF [32][256]
    {
        uint4 aS[2][2];
        #pragma unroll
        for (int S = 0; S < 2; ++S){
            aS[S][0] = *(const uint4*)TBA(T0B, c15,      S*32 + half*8);
            aS[S][1] = *(const uint4*)TBA(T0B, 16 + c15, S*32 + half*8);
        }
        #pragma unroll
        for (int k = 0; k < 4; ++k){
            int nb = k*4 + w;
            int col = nb*16 + c15;
            float bias = b1[col];
            f32x4 ac0 = {bias,bias,bias,bias}, ac1 = ac0;
            #pragma unroll
            for (int S = 0; S < 2; ++S){
                uint4 bfv = packH[H_W1 + (nb*2 + S)*64 + lane];
                ac0 = MFMA(aS[S][0], bfv, ac0); ac1 = MFMA(aS[S][1], bfv, ac1);
            }
            #pragma unroll
            for (int r = 0; r < 4; ++r){
                *(bf16*)TFA(half*4 + r,      col) = __float2bfloat16(fmaxf(ac0[r], 0.f));
                *(bf16*)TFA(16 + half*4 + r, col) = __float2bfloat16(fmaxf(ac1[r], 0.f));
            }
        }
    }
    __syncthreads();

    // ---- P6: XF += f1@W2 + b2
    {
        int col = w*16 + c15;
        float bias = b2[col];
        f32x4 ac0 = {bias,bias,bias,bias}, ac1 = ac0;
        #pragma unroll
        for (int S = 0; S < 8; ++S){
            uint4 bfv = packH[H_W2 + (w*8 + S)*64 + lane];
            uint4 a0 = *(const uint4*)TFA(c15,      S*32 + half*8);
            uint4 a1 = *(const uint4*)TFA(16 + c15, S*32 + half*8);
            ac0 = MFMA(a0, bfv, ac0); ac1 = MFMA(a1, bfv, ac1);
        }
        #pragma unroll
        for (int r = 0; r < 4; ++r){
            *(float*)XFA(half*4 + r,      col) += ac0[r];
            *(float*)XFA(16 + half*4 + r, col) += ac1[r];
        }
    }
    __syncthreads();

    // ---- P7: LN2 -> T0 (bf16 x2)
    {
        float4 v0 = *(const float4*)XFA(bb, g*8);
        float4 v1 = *(const float4*)XFA(bb, g*8 + 4);
        float vv[8] = {v0.x, v0.y, v0.z, v0.w, v1.x, v1.y, v1.z, v1.w};
        float s = 0.f, s2 = 0.f;
        #pragma unroll
        for (int j = 0; j < 8; ++j){ s += vv[j]; s2 += vv[j]*vv[j]; }
        #pragma unroll
        for (int msk = 1; msk < 8; msk <<= 1){ s += __shfl_xor(s, msk, 8); s2 += __shfl_xor(s2, msk, 8); }
        float mean = s * (1.f/64.f);
        float var  = s2 * (1.f/64.f) - mean*mean;
        float rstd = rsqrtf(var + 1e-5f);
        float xf[8];
        #pragma unroll
        for (int j = 0; j < 8; ++j){
            int c = g*8 + j;
            xf[j] = (vv[j] - mean) * rstd * ln2_g[c] + ln2_b[c];
        }
        uint4 u;
        u.x = pk2(xf[0], xf[1]); u.y = pk2(xf[2], xf[3]);
        u.z = pk2(xf[4], xf[5]); u.w = pk2(xf[6], xf[7]);
        *(uint4*)TBA(T0B, bb, g*8) = u;
    }
    __syncthreads();

    // ---- P8: xr = x2@relu_W + relu_b -> XR
    {
        int col = w*16 + c15;
        float bias = relu_b[col];
        f32x4 ac0 = {bias,bias,bias,bias}, ac1 = ac0;
        #pragma unroll
        for (int S = 0; S < 2; ++S){
            uint4 bfv = packH[H_RELU + (w*2 + S)*64 + lane];
            uint4 a0 = *(const uint4*)TBA(T0B, c15,      S*32 + half*8);
            uint4 a1 = *(const uint4*)TBA(T0B, 16 + c15, S*32 + half*8);
            ac0 = MFMA(a0, bfv, ac0); ac1 = MFMA(a1, bfv, ac1);
        }
        #pragma unroll
        for (int r = 0; r < 4; ++r){
            *(bf16*)TBA(XRB, half*4 + r,      col) = __float2bfloat16(ac0[r]);
            *(bf16*)TBA(XRB, 16 + half*4 + r, col) = __float2bfloat16(ac1[r]);
        }
    }
    __syncthreads();

    // ---- P9: nd = xr@nd_W + nd_b -> T1
    {
        int col = w*16 + c15;
        float bias = nd_b[col];
        f32x4 ac0 = {bias,bias,bias,bias}, ac1 = ac0;
        #pragma unroll
        for (int S = 0; S < 2; ++S){
            uint4 bfv = packH[H_ND + (w*2 + S)*64 + lane];
            uint4 a0 = *(const uint4*)TBA(XRB, c15,      S*32 + half*8);
            uint4 a1 = *(const uint4*)TBA(XRB, 16 + c15, S*32 + half*8);
            ac0 = MFMA(a0, bfv, ac0); ac1 = MFMA(a1, bfv, ac1);
        }
        #pragma unroll
        for (int r = 0; r < 4; ++r){
            *(bf16*)TBA(T1B, half*4 + r,      col) = __float2bfloat16(ac0[r]);
            *(bf16*)TBA(T1B, 16 + half*4 + r, col) = __float2bfloat16(ac1[r]);
        }
    }
    __syncthreads();

    // ---- P10: dT = nd@ldt_W + ldt_b -> dTs + out[:,0]
    {
        uint4 u = *(const uint4*)TBA(T1B, bb, g*8);
        float nf[8]; UNPK(u, nf);
        float p = 0.f;
        #pragma unroll
        for (int j = 0; j < 8; ++j) p = fmaf(nf[j], ldt_W[g*8 + j], p);
        #pragma unroll
        for (int msk = 1; msk < 8; msk <<= 1) p += __shfl_xor(p, msk, 8);
        if (g == 0){
            float dT = p + ldt_b[0];
            dTs[bb] = dT;
            out[(size_t)gb * 26] = dT;
        }
    }
    __syncthreads();

    // ---- P10b: build NZ A-tile [dT, xr, 0-pad] -> T0 (96 cols)
    {
        float dT = dTs[bb];
        for (int c8 = g; c8 < 12; c8 += 8){
            int cb = c8 * 8;
            unsigned pr[4];
            #pragma unroll
            for (int pj = 0; pj < 4; ++pj){
                int c0 = cb + 2*pj, c1 = c0 + 1;
                float v0 = (c0 == 0) ? dT :
                           (c0 <= 64 ? __bfloat162float(*(const bf16*)TBA(XRB, bb, c0-1)) : 0.f);
                float v1 = (c1 <= 64 ? __bfloat162float(*(const bf16*)TBA(XRB, bb, c1-1)) : 0.f);
                pr[pj] = pk2(v0, v1);
            }
            *(uint4*)TBA(T0B, bb, cb) = (uint4){pr[0], pr[1], pr[2], pr[3]};
        }
    }
    __syncthreads();

    // ---- P11: m65 = nza@nz_W + nz_b -> T1 (cols 0..79; zero 80..95)
    {
        uint4 aS[3][2];
        #pragma unroll
        for (int S = 0; S < 3; ++S){
            aS[S][0] = *(const uint4*)TBA(T0B, c15,      S*32 + half*8);
            aS[S][1] = *(const uint4*)TBA(T0B, 16 + c15, S*32 + half*8);
        }
        int nbl[2]; int nnb = 1; nbl[0] = w;
        if (w == 0){ nbl[1] = 4; nnb = 2; }
        for (int q = 0; q < nnb; ++q){
            int nb = nbl[q];
            int col = nb*16 + c15;
            float bias = (col < 65) ? nz_b[col] : 0.f;
            f32x4 ac0 = {bias,bias,bias,bias}, ac1 = ac0;
            #pragma unroll
            for (int S = 0; S < 3; ++S){
                uint4 bfv = packH[H_NZ + (nb*3 + S)*64 + lane];
                ac0 = MFMA(aS[S][0], bfv, ac0); ac1 = MFMA(aS[S][1], bfv, ac1);
            }
            #pragma unroll
            for (int r = 0; r < 4; ++r){
                *(bf16*)TBA(T1B, half*4 + r,      col) = __float2bfloat16(ac0[r]);
                *(bf16*)TBA(T1B, 16 + half*4 + r, col) = __float2bfloat16(ac1[r]);
            }
        }
        if (t < 64){
            int row = t >> 1, seg = t & 1;
            *(uint4*)TBA(T1B, row, 80 + seg*8) = (uint4){0u,0u,0u,0u};
        }
    }
    __syncthreads();

    // ---- P12: mz = m65@lz_W + lz_b -> TQ (bf16) + out[:,1..20] (f32)
    if (w < 2){
        uint4 aS[3][2];
        #pragma unroll
        for (int S = 0; S < 3; ++S){
            aS[S][0] = *(const uint4*)TBA(T1B, c15,      S*32 + half*8);
            aS[S][1] = *(const uint4*)TBA(T1B, 16 + c15, S*32 + half*8);
        }
        int nb = w;
        int col = nb*16 + c15;
        float bias = (col < 20) ? lz_b[col] : 0.f;
        f32x4 ac0 = {bias,bias,bias,bias}, ac1 = ac0;
        #pragma unroll
        for (int S = 0; S < 3; ++S){
            uint4 bfv = packH[H_LZ + (nb*3 + S)*64 + lane];
            ac0 = MFMA(aS[S][0], bfv, ac0); ac1 = MFMA(aS[S][1], bfv, ac1);
        }
        #pragma unroll
        for (int r = 0; r < 4; ++r){
            int r0 = half*4 + r, r1 = 16 + half*4 + r;
            *(bf16*)TBA(TQB, r0, col) = __float2bfloat16(ac0[r]);
            *(bf16*)TBA(TQB, r1, col) = __float2bfloat16(ac1[r]);
            if (col < 20){
                out[(size_t)(B0 + r0) * 26 + 1 + col] = ac0[r];
                out[(size_t)(B0 + r1) * 26 + 1 + col] = ac1[r];
            }
        }
    }
    __syncthreads();

    // ---- P13: build FA tile [mz(20), dT, xr(64), 0-pad] -> T0 (96 cols)
    {
        float dT = dTs[bb];
        for (int c8 = g; c8 < 12; c8 += 8){
            int cb = c8 * 8;
            unsigned pr[4];
            #pragma unroll
            for (int pj = 0; pj < 4; ++pj){
                float vv[2];
                #pragma unroll
                for (int hh = 0; hh < 2; ++hh){
                    int c = cb + 2*pj + hh;
                    float v;
                    if (c < 20)       v = __bfloat162float(*(const bf16*)TBA(TQB, bb, c));
                    else if (c == 20) v = dT;
                    else if (c < 85)  v = __bfloat162float(*(const bf16*)TBA(XRB, bb, c - 21));
                    else              v = 0.f;
                    vv[hh] = v;
                }
                pr[pj] = pk2(vv[0], vv[1]);
            }
            *(uint4*)TBA(T0B, bb, cb) = (uint4){pr[0], pr[1], pr[2], pr[3]};
        }
    }
    __syncthreads();

    // ---- P14: ma1 = fa@na0_W + na0_b -> T1 (96 cols)
    {
        uint4 aS[3][2];
        #pragma unroll
        for (int S = 0; S < 3; ++S){
            aS[S][0] = *(const uint4*)TBA(T0B, c15,      S*32 + half*8);
            aS[S][1] = *(const uint4*)TBA(T0B, 16 + c15, S*32 + half*8);
        }
        int nbl[2]; int nnb = 1; nbl[0] = w;
        if (w < 2){ nbl[1] = 4 + w; nnb = 2; }
        for (int q = 0; q < nnb; ++q){
            int nb = nbl[q];
            int col = nb*16 + c15;
            float bias = (col < 85) ? na0_b[col] : 0.f;
            f32x4 ac0 = {bias,bias,bias,bias}, ac1 = ac0;
            #pragma unroll
            for (int S = 0; S < 3; ++S){
                uint4 bfv = packH[H_NA0 + (nb*3 + S)*64 + lane];
                ac0 = MFMA(aS[S][0], bfv, ac0); ac1 = MFMA(aS[S][1], bfv, ac1);
            }
            #pragma unroll
            for (int r = 0; r < 4; ++r){
                *(bf16*)TBA(T1B, half*4 + r,      col) = __float2bfloat16(ac0[r]);
                *(bf16*)TBA(T1B, 16 + half*4 + r, col) = __float2bfloat16(ac1[r]);
            }
        }
    }
    __syncthreads();

    // ---- P15: ma2 = ma1@na1_W + na1_b -> T0 (96 cols)
    {
        uint4 aS[3][2];
        #pragma unroll
        for (int S = 0; S < 3; ++S){
            aS[S][0] = *(const uint4*)TBA(T1B, c15,      S*32 + half*8);
            aS[S][1] = *(const uint4*)TBA(T1B, 16 + c15, S*32 + half*8);
        }
        int nbl[2]; int nnb = 1; nbl[0] = w;
        if (w < 2){ nbl[1] = 4 + w; nnb = 2; }
        for (int q = 0; q < nnb; ++q){
            int nb = nbl[q];
            int col = nb*16 + c15;
            float bias = (col < 85) ? na1_b[col] : 0.f;
            f32x4 ac0 = {bias,bias,bias,bias}, ac1 = ac0;
            #pragma unroll
            for (int S = 0; S < 3; ++S){
                uint4 bfv = packH[H_NA1 + (nb*3 + S)*64 + lane];
                ac0 = MFMA(aS[S][0], bfv, ac0); ac1 = MFMA(aS[S][1], bfv, ac1);
            }
            #pragma unroll
            for (int r = 0; r < 4; ++r){
                *(bf16*)TBA(T0B, half*4 + r,      col) = __float2bfloat16(ac0[r]);
                *(bf16*)TBA(T0B, 16 + half*4 + r, col) = __float2bfloat16(ac1[r]);
            }
        }
    }
    __syncthreads();

    // ---- P16: ma = ma2@la_W + la_b -> out[:,21..25]
    if (w == 0){
        int col = c15;
        float bias = (col < 5) ? la_b[col] : 0.f;
        f32x4 ac0 = {bias,bias,bias,bias}, ac1 = ac0;
        #pragma unroll
        for (int S = 0; S < 3; ++S){
            uint4 bfv = packH[H_LA + S*64 + lane];
            uint4 a0 = *(const uint4*)TBA(T0B, c15,      S*32 + half*8);
            uint4 a1 = *(const uint4*)TBA(T0B, 16 + c15, S*32 + half*8);
            ac0 = MFMA(a0, bfv, ac0); ac1 = MFMA(a1, bfv, ac1);
        }
        if (col < 5){
            #pragma unroll
            for (int r = 0; r < 4; ++r){
                out[(size_t)(B0 + half*4 + r) * 26 + 21 + col]      = ac0[r];
                out[(size_t)(B0 + 16 + half*4 + r) * 26 + 21 + col] = ac1[r];
            }
        }
    }
}

extern "C" void kernel_launch(void* const* d_in, const int* in_sizes, int n_in,
                              void* d_out, int out_size, void* d_ws, size_t ws_size,
                              hipStream_t stream)
{
    const float* X        = (const float*)d_in[0];
    const float* emb_act  = (const float*)d_in[1];
    const float* emb_zone = (const float*)d_in[2];
    const float* lin0_W   = (const float*)d_in[3];
    const float* lin0_b   = (const float*)d_in[4];
    const float* gat_W    = (const float*)d_in[5];
    const float* gat_b    = (const float*)d_in[6];
    const float* gat_a    = (const float*)d_in[7];
    const float* gl0_W    = (const float*)d_in[8];
    const float* gl0_b    = (const float*)d_in[9];
    const float* gl1_W    = (const float*)d_in[10];
    const float* gl1_b    = (const float*)d_in[11];
    const float* gl2_W    = (const float*)d_in[12];
    const float* gl2_b    = (const float*)d_in[13];
    const float* Wqkv     = (const float*)d_in[14];
    const float* bqkv     = (const float*)d_in[15];
    const float* Wo       = (const float*)d_in[16];
    const float* bo       = (const float*)d_in[17];
    const float* ln1_g    = (const float*)d_in[18];
    const float* ln1_b    = (const float*)d_in[19];
    const float* W1       = (const float*)d_in[20];
    const float* b1       = (const float*)d_in[21];
    const float* W2       = (const float*)d_in[22];
    const float* b2       = (const float*)d_in[23];
    const float* ln2_g    = (const float*)d_in[24];
    const float* ln2_b    = (const float*)d_in[25];
    const float* relu_W   = (const float*)d_in[26];
    const float* relu_b   = (const float*)d_in[27];
    const float* nd_W     = (const float*)d_in[28];
    const float* nd_b     = (const float*)d_in[29];
    const float* ldt_W    = (const float*)d_in[30];
    const float* ldt_b    = (const float*)d_in[31];
    const float* nz_W     = (const float*)d_in[32];
    const float* nz_b     = (const float*)d_in[33];
    const float* lz_W     = (const float*)d_in[34];
    const float* lz_b     = (const float*)d_in[35];
    const float* na0_W    = (const float*)d_in[36];
    const float* na0_b    = (const float*)d_in[37];
    const float* na1_W    = (const float*)d_in[38];
    const float* na1_b    = (const float*)d_in[39];
    const float* la_W     = (const float*)d_in[40];
    const float* la_b     = (const float*)d_in[41];

    char* wsb = (char*)d_ws;
    bf16*  kv       = (bf16*)wsb;
    float* src_last = (float*)(wsb + (size_t)NTOK * 128 * sizeof(bf16));
    uint4* packW    = (uint4*)(wsb + (size_t)NTOK * 128 * sizeof(bf16) + (size_t)B_ * 64 * sizeof(float));
    uint4* packH    = packW + PK_TOT;

    k_pack_all<<<(PK_TOT + H_TOT + 255)/256, 256, 0, stream>>>(
        gl0_W, gl1_W, gl2_W, Wqkv, Wo, W1, W2, relu_W, nd_W, nz_W, lz_W,
        na0_W, na1_W, la_W, packW, packH);

    k_token<<<NTOK/TOKB, TPB, 0, stream>>>(X, emb_act, emb_zone, lin0_W, lin0_b,
        gat_W, gat_b, gat_a, gl0_b, gl1_b, gl2_b, bqkv, packW, kv, src_last);

    k_head2<<<B_/32, 256, 0, stream>>>(kv, src_last, packH, bqkv, bo,
        ln1_g, ln1_b, b1, b2, ln2_g, ln2_b, relu_b, nd_b, ldt_W, ldt_b,
        nz_b, lz_b, na0_b, na1_b, la_b, (float*)d_out);
}

// Round 8
// 76.778 us; speedup vs baseline: 2.4003x; 1.0196x over previous
//
#include <hip/hip_runtime.h>
#include <hip/hip_bf16.h>

typedef __hip_bfloat16 bf16;
typedef float f32x4 __attribute__((ext_vector_type(4)));
typedef short s16x8 __attribute__((ext_vector_type(8)));

#define B_    2048
#define S_    40
#define NTOK  (B_*S_)
#define TPB   256
#define TOKB  64

// ---- k_token LDS layout (dwords). A1 aliases FF (FF dead after phase 1).
#define FF_OFF    0
#define A1_OFFD   0
#define A0_OFFD   4288
#define PE_OFFD   8384
#define S2V_OFFD  8448     // 64 tokens x 23 f32 (stride 23, odd)
#define LDS_DW    9920     // 39680 B -> 4 blocks/CU (158720 <= 163840)

#define A0B (A0_OFFD*4)
#define A1B (A1_OFFD*4)

// ---- packW (token) fragment offsets (uint4 units)
#define PK_GL0 0
#define PK_GL1 1024
#define PK_GL2 1536
#define PK_KV  1664
#define PK_TOT 2688

// ---- packH (head) fragment offsets (uint4 units)
#define H_WQ   0
#define H_WO   512
#define H_W1   1024
#define H_W2   3072
#define H_RELU 5120
#define H_ND   5632
#define H_NZ   6144
#define H_LZ   7104
#define H_NA0  7488
#define H_NA1  8640
#define H_LA   9792
#define H_TOT  9984

__device__ inline unsigned pk2(float a, float b){
    __hip_bfloat16 ha = __float2bfloat16(a), hb = __float2bfloat16(b);
    unsigned short ua = *reinterpret_cast<unsigned short*>(&ha);
    unsigned short ub = *reinterpret_cast<unsigned short*>(&hb);
    return (unsigned)ua | ((unsigned)ub << 16);
}
__device__ inline float blo(unsigned u){ return __uint_as_float(u << 16); }
__device__ inline float bhi(unsigned u){ return __uint_as_float(u & 0xffff0000u); }

__device__ inline float fexp2(float x){
#if __has_builtin(__builtin_amdgcn_exp2f)
    return __builtin_amdgcn_exp2f(x);
#else
    return exp2f(x);
#endif
}

__device__ inline f32x4 MFMA(uint4 a, uint4 b, f32x4 c){
    union { uint4 q; s16x8 s; } A, Bv;
    A.q = a; Bv.q = b;
    return __builtin_amdgcn_mfma_f32_16x16x32_bf16(A.s, Bv.s, c, 0, 0, 0);
}

__device__ inline uint4 packB(const float* W, int ld, int K, int N, int nb, int S, int lane){
    int half = lane >> 4, c15 = lane & 15;
    int col = nb*16 + c15;
    unsigned pr[4];
    #pragma unroll
    for (int jj = 0; jj < 4; ++jj){
        int k0 = S*32 + half*8 + 2*jj;
        float v0 = (k0   < K && col < N) ? W[(size_t)k0*ld + col]     : 0.f;
        float v1 = (k0+1 < K && col < N) ? W[(size_t)(k0+1)*ld + col] : 0.f;
        pr[jj] = pk2(v0, v1);
    }
    return (uint4){pr[0], pr[1], pr[2], pr[3]};
}

// ---------------- Kernel 0: pre-pack ALL weight fragments ----------------
__global__ __launch_bounds__(256) void k_pack_all(
    const float* __restrict__ gl0_W, const float* __restrict__ gl1_W,
    const float* __restrict__ gl2_W, const float* __restrict__ Wqkv,
    const float* __restrict__ Wo,    const float* __restrict__ W1,
    const float* __restrict__ W2,    const float* __restrict__ relu_W,
    const float* __restrict__ nd_W,  const float* __restrict__ nz_W,
    const float* __restrict__ lz_W,  const float* __restrict__ na0_W,
    const float* __restrict__ na1_W, const float* __restrict__ la_W,
    uint4* __restrict__ packW, uint4* __restrict__ packH)
{
    int f = blockIdx.x * 256 + threadIdx.x;
    if (f < PK_TOT){
        unsigned pr[4];
        if (f < PK_GL1){
            int w = f >> 8, r = f & 255, S = r >> 6, lane = r & 63;
            int half = lane >> 4, c15 = lane & 15, col = w * 16 + c15;
            #pragma unroll
            for (int jj = 0; jj < 4; ++jj){
                int k0 = S*32 + half*8 + 2*jj;
                float v0 = (k0   < 110) ? gl0_W[k0*64 + col]     : 0.f;
                float v1 = (k0+1 < 110) ? gl0_W[(k0+1)*64 + col] : 0.f;
                pr[jj] = pk2(v0, v1);
            }
        } else if (f < PK_GL2){
            int g = f - PK_GL1, w = g >> 7, r = g & 127, S = r >> 6, lane = r & 63;
            int half = lane >> 4, c15 = lane & 15, col = w * 16 + c15;
            #pragma unroll
            for (int jj = 0; jj < 4; ++jj){
                int k0 = S*32 + half*8 + 2*jj;
                pr[jj] = pk2(gl1_W[k0*64 + col], gl1_W[(k0+1)*64 + col]);
            }
        } else if (f < PK_KV){
            int g = f - PK_GL2, S = g >> 6, lane = g & 63;
            int half = lane >> 4, c15 = lane & 15;
            #pragma unroll
            for (int jj = 0; jj < 4; ++jj){
                int k0 = S*32 + half*8 + 2*jj;
                pr[jj] = pk2(gl2_W[k0*16 + c15], gl2_W[(k0+1)*16 + c15]);
            }
        } else {
            int g = f - PK_KV, w = g >> 8, r = g & 255, cf = r >> 7, r2 = r & 127;
            int S = r2 >> 6, lane = r2 & 63;
            int half = lane >> 4, c15 = lane & 15, col = 64 + w*32 + cf*16 + c15;
            #pragma unroll
            for (int jj = 0; jj < 4; ++jj){
                int k0 = S*32 + half*8 + 2*jj;
                pr[jj] = pk2(Wqkv[k0*192 + col], Wqkv[(k0+1)*192 + col]);
            }
        }
        packW[f] = (uint4){pr[0], pr[1], pr[2], pr[3]};
        return;
    }
    int f2 = f - PK_TOT;
    if (f2 >= H_TOT) return;
    const float* W; int ld, K, N, St, base;
    if      (f2 < H_WO ){ W=Wqkv;   ld=192; K=64;  N=64;  St=2; base=H_WQ;  }
    else if (f2 < H_W1 ){ W=Wo;     ld=64;  K=64;  N=64;  St=2; base=H_WO;  }
    else if (f2 < H_W2 ){ W=W1;     ld=256; K=64;  N=256; St=2; base=H_W1;  }
    else if (f2 < H_RELU){W=W2;     ld=64;  K=256; N=64;  St=8; base=H_W2;  }
    else if (f2 < H_ND ){ W=relu_W; ld=64;  K=64;  N=64;  St=2; base=H_RELU;}
    else if (f2 < H_NZ ){ W=nd_W;   ld=64;  K=64;  N=64;  St=2; base=H_ND;  }
    else if (f2 < H_LZ ){ W=nz_W;   ld=65;  K=65;  N=65;  St=3; base=H_NZ;  }
    else if (f2 < H_NA0){ W=lz_W;   ld=20;  K=65;  N=20;  St=3; base=H_LZ;  }
    else if (f2 < H_NA1){ W=na0_W;  ld=85;  K=85;  N=85;  St=3; base=H_NA0; }
    else if (f2 < H_LA ){ W=na1_W;  ld=85;  K=85;  N=85;  St=3; base=H_NA1; }
    else               { W=la_W;   ld=5;   K=85;  N=5;   St=3; base=H_LA;  }
    int loc = f2 - base;
    int nb = loc / (St*64);
    int rem = loc - nb*St*64;
    packH[f2] = packB(W, ld, K, N, nb, rem >> 6, rem & 63);
}

// ---------------- Kernel 1: MFMA featurizer ----------------
__global__ __launch_bounds__(TPB) void k_token(
    const float* __restrict__ X,
    const float* __restrict__ emb_act,
    const float* __restrict__ emb_zone,
    const float* __restrict__ lin0_W, const float* __restrict__ lin0_b,
    const float* __restrict__ gat_W,  const float* __restrict__ gat_b,
    const float* __restrict__ gat_a,
    const float* __restrict__ gl0_b,  const float* __restrict__ gl1_b,
    const float* __restrict__ gl2_b,  const float* __restrict__ bqkv,
    const uint4* __restrict__ packW,
    bf16* __restrict__ kv, float* __restrict__ src_last)
{
    __shared__ unsigned L[LDS_DW];
    char* Lb = (char*)L;

    const int t    = threadIdx.x;
    const int w    = t >> 6;
    const int lane = t & 63;
    const int half = (lane >> 4);
    const int c15  = lane & 15;
    const int blk0 = blockIdx.x * TOKB;
    const int swzc = (c15 & 7) << 4;

    // ---------- phase 0 ----------
    for (int task = t; task < TOKB * 22; task += TPB){
        int tt = task / 22;
        int r  = task - tt * 22;
        const float* xp = X + (size_t)(blk0 + tt) * 118 + 8 + r * 5;
        float f0 = xp[0], f1 = xp[1], f2 = xp[2], f3 = xp[3], f4 = xp[4];
        unsigned* dst = &L[FF_OFF + tt * 67 + 3 * r];
        dst[0] = pk2(f0, f1); dst[1] = pk2(f2, f3); dst[2] = pk2(f4, 0.f);
    }
    for (int idx = t; idx < 64 * 9; idx += TPB){
        int row = idx / 9, p = idx - row * 9;
        *(unsigned*)(Lb + A0B + row * 256 + ((220 + 4*p) ^ ((row & 7) << 4))) = 0u;
    }
    float hd[8];
    {
        const float2* xp = (const float2*)(X + (size_t)(blk0 + lane) * 118);
        #pragma unroll
        for (int p = 0; p < 4; ++p){ float2 v = xp[p]; hd[2*p] = v.x; hd[2*p+1] = v.y; }
    }
    if (t < TOKB){
        int tok = blk0 + t;
        int b = tok / 40, s = tok - b * 40;
        float expo = (2.0f * (float)s) / 40.0f;
        float inv100 = fexp2(-expo * 6.6438561897747395f);   // 100^-expo
        float ang = (float)b * inv100;
        float pe = ((s & 1) == 0) ? __sinf(ang) : __cosf(ang);
        ((float*)&L[PE_OFFD])[t] = pe;
    }
    __syncthreads();

    // ---------- GAT constants (prescaled by log2e) ----------
    const float LOG2E = 1.4426950408889634f;
    const unsigned tb = FF_OFF + lane * 67;
    float va1[5], va2[5];
    float cc1 = 0.f, cc2 = 0.f;
    #pragma unroll
    for (int e = 0; e < 5; ++e){
        float u1 = 0.f, u2 = 0.f;
        #pragma unroll
        for (int d = 0; d < 5; ++d){
            u1 += gat_W[e*5+d] * gat_a[d];
            u2 += gat_W[e*5+d] * gat_a[5+d];
        }
        va1[e] = u1 * LOG2E; va2[e] = u2 * LOG2E;
    }
    #pragma unroll
    for (int d = 0; d < 5; ++d){ cc1 += gat_b[d]*gat_a[d]; cc2 += gat_b[d]*gat_a[5+d]; }
    cc1 *= LOG2E; cc2 *= LOG2E;

    // ---------- phase 1a: cooperative s2v' (wave w covers j = 6w..) ----------
    {
        float* s2vL = (float*)&L[S2V_OFFD];
        const int njj = (w == 3) ? 4 : 6;
        #pragma unroll
        for (int jj = 0; jj < 6; ++jj){
            if (jj < njj){
                int j = w*6 + jj;
                unsigned u0 = L[tb + 3*j], u1 = L[tb + 3*j + 1], u2 = L[tb + 3*j + 2];
                float f0 = blo(u0), f1 = bhi(u0), f2 = blo(u1), f3 = bhi(u1), f4 = blo(u2);
                s2vL[lane*23 + j] = cc2 + f0*va2[0] + f1*va2[1] + f2*va2[2] + f3*va2[3] + f4*va2[4];
            }
        }
    }
    __syncthreads();

    // ---------- phase 1b: GAT main -> hp (bf16) into A0 (k = 5i+d) ----------
    {
        const float* s2vL = (const float*)&L[S2V_OFFD];
        float s2v[22];
        float m2 = -1e30f;
        #pragma unroll
        for (int j = 0; j < 22; ++j){
            s2v[j] = s2vL[lane*23 + j];
            m2 = fmaxf(m2, s2v[j]);
        }

        const int wbase = w * 6;
        float s1own[6], negmi[6], Z[6], ffp[6][5];
        #pragma unroll
        for (int ii = 0; ii < 6; ++ii){
            int i = wbase + ii; if (i > 21) i = 21;
            unsigned u0 = L[tb + 3*i], u1 = L[tb + 3*i + 1], u2 = L[tb + 3*i + 2];
            float f0 = blo(u0), f1 = bhi(u0), f2 = blo(u1), f3 = bhi(u1), f4 = blo(u2);
            float s1 = cc1 + f0*va1[0] + f1*va1[1] + f2*va1[2] + f3*va1[3] + f4*va1[4];
            s1own[ii] = s1;
            float em = s1 + m2;
            negmi[ii] = -fmaxf(em, 0.2f * em);
            Z[ii] = 0.f;
            #pragma unroll
            for (int e = 0; e < 5; ++e) ffp[ii][e] = 0.f;
        }

        #pragma unroll
        for (int j = 0; j < 22; ++j){
            unsigned u0 = L[tb + 3*j], u1 = L[tb + 3*j + 1], u2 = L[tb + 3*j + 2];
            float f0 = blo(u0), f1 = bhi(u0), f2 = blo(u1), f3 = bhi(u1), f4 = blo(u2);
            float s2j = s2v[j];
            #pragma unroll
            for (int ii = 0; ii < 6; ++ii){
                float e2 = s1own[ii] + s2j;
                float a  = e2 + negmi[ii];
                float bq = fmaf(0.2f, e2, negmi[ii]);
                float wg = fexp2(fmaxf(a, bq));
                Z[ii] += wg;
                ffp[ii][0] = fmaf(wg, f0, ffp[ii][0]);
                ffp[ii][1] = fmaf(wg, f1, ffp[ii][1]);
                ffp[ii][2] = fmaf(wg, f2, ffp[ii][2]);
                ffp[ii][3] = fmaf(wg, f3, ffp[ii][3]);
                ffp[ii][4] = fmaf(wg, f4, ffp[ii][4]);
            }
        }

        const int rswz = (lane & 7) << 4;
        #pragma unroll
        for (int ii = 0; ii < 6; ++ii){
            int i = wbase + ii;
            if (i < 22){
                float rz = 1.f / Z[ii];
                #pragma unroll
                for (int d = 0; d < 5; ++d){
                    float u = 0.f;
                    #pragma unroll
                    for (int e = 0; e < 5; ++e) u += ffp[ii][e] * gat_W[e*5+d];
                    float h = u * rz + gat_b[d];
                    *(bf16*)(Lb + A0B + lane*256 + ((10*i + 2*d) ^ rswz)) = __float2bfloat16(h);
                }
            }
        }
    }
    __syncthreads();

    // ---------- phase 2: gl0 MFMA (K=128) -> A1 ----------
    {
        uint4 bfr[4];
        #pragma unroll
        for (int S = 0; S < 4; ++S) bfr[S] = packW[PK_GL0 + (w*4 + S)*64 + lane];
        const int col = w * 16 + c15;
        float bias = gl0_b[col];
        f32x4 ac0 = {bias,bias,bias,bias}, ac1 = ac0, ac2 = ac0, ac3 = ac0;
        #pragma unroll
        for (int S = 0; S < 4; ++S){
            int koff = S*64 + half*16;
            uint4 a0 = *(const uint4*)(Lb + A0B + (0*16 + c15)*256 + (koff ^ swzc));
            uint4 a1 = *(const uint4*)(Lb + A0B + (1*16 + c15)*256 + (koff ^ swzc));
            uint4 a2 = *(const uint4*)(Lb + A0B + (2*16 + c15)*256 + (koff ^ swzc));
            uint4 a3 = *(const uint4*)(Lb + A0B + (3*16 + c15)*256 + (koff ^ swzc));
            ac0 = MFMA(a0, bfr[S], ac0);
            ac1 = MFMA(a1, bfr[S], ac1);
            ac2 = MFMA(a2, bfr[S], ac2);
            ac3 = MFMA(a3, bfr[S], ac3);
        }
        const int off = col * 2;
        #pragma unroll
        for (int r = 0; r < 4; ++r){
            int row0 = 0*16 + half*4 + r;
            int row1 = 1*16 + half*4 + r;
            int row2 = 2*16 + half*4 + r;
            int row3 = 3*16 + half*4 + r;
            *(bf16*)(Lb + A1B + row0*128 + (off ^ ((row0 & 7) << 4))) = __float2bfloat16(fmaxf(ac0[r], 0.f));
            *(bf16*)(Lb + A1B + row1*128 + (off ^ ((row1 & 7) << 4))) = __float2bfloat16(fmaxf(ac1[r], 0.f));
            *(bf16*)(Lb + A1B + row2*128 + (off ^ ((row2 & 7) << 4))) = __float2bfloat16(fmaxf(ac2[r], 0.f));
            *(bf16*)(Lb + A1B + row3*128 + (off ^ ((row3 & 7) << 4))) = __float2bfloat16(fmaxf(ac3[r], 0.f));
        }
    }
    __syncthreads();

    // ---------- phase 3: gl1 MFMA (A1 -> A0, stride 128B) ----------
    {
        uint4 bfr[2];
        #pragma unroll
        for (int S = 0; S < 2; ++S) bfr[S] = packW[PK_GL1 + (w*2 + S)*64 + lane];
        const int col = w * 16 + c15;
        float bias = gl1_b[col];
        f32x4 ac0 = {bias,bias,bias,bias}, ac1 = ac0, ac2 = ac0, ac3 = ac0;
        #pragma unroll
        for (int S = 0; S < 2; ++S){
            int koff = S*64 + half*16;
            uint4 a0 = *(const uint4*)(Lb + A1B + (0*16 + c15)*128 + (koff ^ swzc));
            uint4 a1 = *(const uint4*)(Lb + A1B + (1*16 + c15)*128 + (koff ^ swzc));
            uint4 a2 = *(const uint4*)(Lb + A1B + (2*16 + c15)*128 + (koff ^ swzc));
            uint4 a3 = *(const uint4*)(Lb + A1B + (3*16 + c15)*128 + (koff ^ swzc));
            ac0 = MFMA(a0, bfr[S], ac0);
            ac1 = MFMA(a1, bfr[S], ac1);
            ac2 = MFMA(a2, bfr[S], ac2);
            ac3 = MFMA(a3, bfr[S], ac3);
        }
        const int off = col * 2;
        #pragma unroll
        for (int r = 0; r < 4; ++r){
            int row0 = 0*16 + half*4 + r;
            int row1 = 1*16 + half*4 + r;
            int row2 = 2*16 + half*4 + r;
            int row3 = 3*16 + half*4 + r;
            *(bf16*)(Lb + A0B + row0*128 + (off ^ ((row0 & 7) << 4))) = __float2bfloat16(fmaxf(ac0[r], 0.f));
            *(bf16*)(Lb + A0B + row1*128 + (off ^ ((row1 & 7) << 4))) = __float2bfloat16(fmaxf(ac1[r], 0.f));
            *(bf16*)(Lb + A0B + row2*128 + (off ^ ((row2 & 7) << 4))) = __float2bfloat16(fmaxf(ac2[r], 0.f));
            *(bf16*)(Lb + A0B + row3*128 + (off ^ ((row3 & 7) << 4))) = __float2bfloat16(fmaxf(ac3[r], 0.f));
        }
    }
    __syncthreads();

    // ---------- phase 4: gl2 MFMA + src build into A1 ----------
    {
        uint4 bfr[2];
        #pragma unroll
        for (int S = 0; S < 2; ++S) bfr[S] = packW[PK_GL2 + S*64 + lane];
        float bias = gl2_b[c15];
        f32x4 ac = {bias,bias,bias,bias};
        #pragma unroll
        for (int S = 0; S < 2; ++S){
            int koff = S*64 + half*16;
            uint4 a = *(const uint4*)(Lb + A0B + (w*16 + c15)*128 + (koff ^ swzc));
            ac = MFMA(a, bfr[S], ac);
        }
        const float* pef = (const float*)&L[PE_OFFD];
        const int off = (48 + c15) * 2;
        #pragma unroll
        for (int r = 0; r < 4; ++r){
            int row = w*16 + half*4 + r;
            float v = fmaxf(ac[r], 0.f) + pef[row];
            *(bf16*)(Lb + A1B + row*128 + (off ^ ((row & 7) << 4))) = __float2bfloat16(v);
        }

        float pe = pef[lane];
        int ia = (int)hd[0], iz = (int)hd[1];
        const int tswz = (lane & 7) << 4;
        #pragma unroll
        for (int pp = 0; pp < 6; ++pp){
            int p = w * 6 + pp;
            int c0 = 2 * p;
            float v0, v1;
            if (p < 8)        { v0 = emb_act[ia*16 + c0];        v1 = emb_act[ia*16 + c0 + 1]; }
            else if (p < 16)  { v0 = emb_zone[iz*16 + c0 - 16];  v1 = emb_zone[iz*16 + c0 - 15]; }
            else {
                int cc = c0 - 32;
                float o0 = lin0_b[cc], o1 = lin0_b[cc+1];
                #pragma unroll
                for (int e = 0; e < 6; ++e){
                    float f = hd[2 + e];
                    o0 = fmaf(f, lin0_W[e*16 + cc], o0);
                    o1 = fmaf(f, lin0_W[e*16 + cc + 1], o1);
                }
                v0 = o0; v1 = o1;
            }
            *(unsigned*)(Lb + A1B + lane*128 + ((4*p) ^ tswz)) = pk2(v0 + pe, v1 + pe);
        }
    }
    __syncthreads();

    // ---------- phase 5: src_last + KV MFMA ----------
    {
        int r0 = 39 - (blk0 % 40);
        if (t < 128){
            int tok = r0 + 40 * (t >> 6);
            if (tok < 64){
                int col = t & 63;
                bf16 hv = *(const bf16*)(Lb + A1B + tok*128 + ((col*2) ^ ((tok & 7) << 4)));
                src_last[(size_t)((blk0 + tok) / 40) * 64 + col] = __bfloat162float(hv);
            }
        }

        uint4 bfk[2][2];
        #pragma unroll
        for (int cf = 0; cf < 2; ++cf)
            #pragma unroll
            for (int S = 0; S < 2; ++S)
                bfk[cf][S] = packW[PK_KV + ((w*2 + cf)*2 + S)*64 + lane];

        float b0v = bqkv[64 + w*32 + c15];
        float b1v = bqkv[64 + w*32 + 16 + c15];
        f32x4 acc[4][2];
        #pragma unroll
        for (int R = 0; R < 4; ++R){
            acc[R][0] = (f32x4){b0v, b0v, b0v, b0v};
            acc[R][1] = (f32x4){b1v, b1v, b1v, b1v};
        }
        #pragma unroll
        for (int S = 0; S < 2; ++S){
            int koff = S*64 + half*16;
            #pragma unroll
            for (int R = 0; R < 4; ++R){
                uint4 a = *(const uint4*)(Lb + A1B + (R*16 + c15)*128 + (koff ^ swzc));
                acc[R][0] = MFMA(a, bfk[0][S], acc[R][0]);
                acc[R][1] = MFMA(a, bfk[1][S], acc[R][1]);
            }
        }
        #pragma unroll
        for (int R = 0; R < 4; ++R){
            #pragma unroll
            for (int cf = 0; cf < 2; ++cf){
                int lcol = w*32 + cf*16 + c15;
                int off = lcol * 2;
                #pragma unroll
                for (int r = 0; r < 4; ++r){
                    int row = R*16 + half*4 + r;
                    *(bf16*)(Lb + A0B + row*256 + (off ^ ((row & 7) << 4))) = __float2bfloat16(acc[R][cf][r]);
                }
            }
        }
    }
    __syncthreads();

    {
        int row = t >> 2;
        int q = t & 3;
        #pragma unroll
        for (int c = 0; c < 4; ++c){
            int chunk = q*4 + c;
            uint4 d = *(const uint4*)(Lb + A0B + row*256 + ((chunk*16) ^ ((row & 7) << 4)));
            *((uint4*)(kv + (size_t)(blk0 + row) * 128 + chunk * 8)) = d;
        }
    }
}

// ---------------- Kernel 2: MFMA head (32 batches/block) ----------------
#define T0B 0
#define T1B 8192
#define TQB 16384
#define XRB 24576
#define XFB 32768
#define TFB 40960
#define DTS 57344

#define TBA(base, row, col) (Lb + (base) + (row)*256 + ((((col)*2)) ^ (((row)&7)<<4)))
#define TFA(row, col)       (Lb + TFB   + (row)*512 + ((((col)*2)) ^ (((row)&7)<<4)))
#define XFA(row, col)       (Lb + XFB   + (row)*256 + ((((col)*4)) ^ (((row)&7)<<4)))

#define UNPK(u, arr) { arr[0]=blo(u.x); arr[1]=bhi(u.x); arr[2]=blo(u.y); arr[3]=bhi(u.y); \
                       arr[4]=blo(u.z); arr[5]=bhi(u.z); arr[6]=blo(u.w); arr[7]=bhi(u.w); }

__global__ __launch_bounds__(256) void k_head2(
    const bf16* __restrict__ kv, const float* __restrict__ src_last,
    const uint4* __restrict__ packH,
    const float* __restrict__ bqkv,  const float* __restrict__ bo,
    const float* __restrict__ ln1_g, const float* __restrict__ ln1_b,
    const float* __restrict__ b1,    const float* __restrict__ b2,
    const float* __restrict__ ln2_g, const float* __restrict__ ln2_b,
    const float* __restrict__ relu_b, const float* __restrict__ nd_b,
    const float* __restrict__ ldt_W, const float* __restrict__ ldt_b,
    const float* __restrict__ nz_b,  const float* __restrict__ lz_b,
    const float* __restrict__ na0_b, const float* __restrict__ na1_b,
    const float* __restrict__ la_b,
    float* __restrict__ out)
{
    __shared__ uint4 Lsh[3592];
    char* Lb = (char*)Lsh;
    float* dTs = (float*)(Lb + DTS);

    const int t    = threadIdx.x;
    const int w    = t >> 6;
    const int lane = t & 63;
    const int half = lane >> 4;
    const int c15  = lane & 15;
    const int B0   = blockIdx.x * 32;
    const int bb   = t >> 3;
    const int g    = t & 7;
    const int gb   = B0 + bb;

    {
        const float4* sp = (const float4*)(src_last + (size_t)gb * 64 + g * 8);
        float4 v0 = sp[0], v1 = sp[1];
        *(float4*)XFA(bb, g*8)     = v0;
        *(float4*)XFA(bb, g*8 + 4) = v1;
        uint4 u;
        u.x = pk2(v0.x, v0.y); u.y = pk2(v0.z, v0.w);
        u.z = pk2(v1.x, v1.y); u.w = pk2(v1.z, v1.w);
        *(uint4*)TBA(T0B, bb, g*8) = u;
    }
    __syncthreads();

    {
        int col = w*16 + c15;
        float bias = bqkv[col];
        f32x4 ac0 = {bias,bias,bias,bias}, ac1 = ac0;
        #pragma unroll
        for (int S = 0; S < 2; ++S){
            uint4 bfv = packH[H_WQ + (w*2 + S)*64 + lane];
            uint4 a0 = *(const uint4*)TBA(T0B, c15,      S*32 + half*8);
            uint4 a1 = *(const uint4*)TBA(T0B, 16 + c15, S*32 + half*8);
            ac0 = MFMA(a0, bfv, ac0); ac1 = MFMA(a1, bfv, ac1);
        }
        #pragma unroll
        for (int r = 0; r < 4; ++r){
            *(bf16*)TBA(TQB, half*4 + r,      col) = __float2bfloat16(ac0[r] * 0.35355339059327373f);
            *(bf16*)TBA(TQB, 16 + half*4 + r, col) = __float2bfloat16(ac1[r] * 0.35355339059327373f);
        }
    }
    __syncthreads();

    {
        int pb = t >> 3, h = t & 7;
        int gpb = B0 + pb;
        uint4 qu = *(const uint4*)TBA(TQB, pb, h*8);
        float qh[8]; UNPK(qu, qh);
        const uint4* kp = (const uint4*)(kv + (size_t)gpb * 40 * 128 + h*8);
        const uint4* vp = (const uint4*)(kv + (size_t)gpb * 40 * 128 + 64 + h*8);
        float sc[40];
        float m = -1e30f;
        #pragma unroll 4
        for (int j = 0; j < 40; ++j){
            uint4 ku = kp[j*16];
            float kf[8]; UNPK(ku, kf);
            float a = qh[0]*kf[0] + qh[1]*kf[1] + qh[2]*kf[2] + qh[3]*kf[3]
                    + qh[4]*kf[4] + qh[5]*kf[5] + qh[6]*kf[6] + qh[7]*kf[7];
            sc[j] = a; m = fmaxf(m, a);
        }
        float Z = 0.f;
        float o[8] = {0.f,0.f,0.f,0.f,0.f,0.f,0.f,0.f};
        #pragma unroll 4
        for (int j = 0; j < 40; ++j){
            float wj = __expf(sc[j] - m);
            Z += wj;
            uint4 vu = vp[j*16];
            float vf[8]; UNPK(vu, vf);
            #pragma unroll
            for (int d = 0; d < 8; ++d) o[d] = fmaf(wj, vf[d], o[d]);
        }
        float rz = 1.f / Z;
        uint4 u;
        u.x = pk2(o[0]*rz, o[1]*rz); u.y = pk2(o[2]*rz, o[3]*rz);
        u.z = pk2(o[4]*rz, o[5]*rz); u.w = pk2(o[6]*rz, o[7]*rz);
        *(uint4*)TBA(T1B, pb, h*8) = u;
    }
    __syncthreads();

    {
        int col = w*16 + c15;
        float bias = bo[col];
        f32x4 ac0 = {bias,bias,bias,bias}, ac1 = ac0;
        #pragma unroll
        for (int S = 0; S < 2; ++S){
            uint4 bfv = packH[H_WO + (w*2 + S)*64 + lane];
            uint4 a0 = *(const uint4*)TBA(T1B, c15,      S*32 + half*8);
            uint4 a1 = *(const uint4*)TBA(T1B, 16 + c15, S*32 + half*8);
            ac0 = MFMA(a0, bfv, ac0); ac1 = MFMA(a1, bfv, ac1);
        }
        #pragma unroll
        for (int r = 0; r < 4; ++r){
            *(float*)XFA(half*4 + r,      col) += ac0[r];
            *(float*)XFA(16 + half*4 + r, col) += ac1[r];
        }
    }
    __syncthreads();

    {
        float4 v0 = *(const float4*)XFA(bb, g*8);
        float4 v1 = *(const float4*)XFA(bb, g*8 + 4);
        float vv[8] = {v0.x, v0.y, v0.z, v0.w, v1.x, v1.y, v1.z, v1.w};
        float s = 0.f, s2 = 0.f;
        #pragma unroll
        for (int j = 0; j < 8; ++j){ s += vv[j]; s2 += vv[j]*vv[j]; }
        #pragma unroll
        for (int msk = 1; msk < 8; msk <<= 1){ s += __shfl_xor(s, msk, 8); s2 += __shfl_xor(s2, msk, 8); }
        float mean = s * (1.f/64.f);
        float var  = s2 * (1.f/64.f) - mean*mean;
        float rstd = rsqrtf(var + 1e-5f);
        float xf[8];
        #pragma unroll
        for (int j = 0; j < 8; ++j){
            int c = g*8 + j;
            xf[j] = (vv[j] - mean) * rstd * ln1_g[c] + ln1_b[c];
        }
        uint4 u;
        u.x = pk2(xf[0], xf[1]); u.y = pk2(xf[2], xf[3]);
        u.z = pk2(xf[4], xf[5]); u.w = pk2(xf[6], xf[7]);
        *(uint4*)TBA(T0B, bb, g*8) = u;
        *(float4*)XFA(bb, g*8)     = (float4){xf[0], xf[1], xf[2], xf[3]};
        *(float4*)XFA(bb, g*8 + 4) = (float4){xf[4], xf[5], xf[6], xf[7]};
    }
    __syncthreads();

    {
        uint4 aS[2][2];
        #pragma unroll
        for (int S = 0; S < 2; ++S){
            aS[S][0] = *(const uint4*)TBA(T0B, c15,      S*32 + half*8);
            aS[S][1] = *(const uint4*)TBA(T0B, 16 + c15, S*32 + half*8);
        }
        #pragma unroll
        for (int k = 0; k < 4; ++k){
            int nb = k*4 + w;
            int col = nb*16 + c15;
            float bias = b1[col];
            f32x4 ac0 = {bias,bias,bias,bias}, ac1 = ac0;
            #pragma unroll
            for (int S = 0; S < 2; ++S){
                uint4 bfv = packH[H_W1 + (nb*2 + S)*64 + lane];
                ac0 = MFMA(aS[S][0], bfv, ac0); ac1 = MFMA(aS[S][1], bfv, ac1);
            }
            #pragma unroll
            for (int r = 0; r < 4; ++r){
                *(bf16*)TFA(half*4 + r,      col) = __float2bfloat16(fmaxf(ac0[r], 0.f));
                *(bf16*)TFA(16 + half*4 + r, col) = __float2bfloat16(fmaxf(ac1[r], 0.f));
            }
        }
    }
    __syncthreads();

    {
        int col = w*16 + c15;
        float bias = b2[col];
        f32x4 ac0 = {bias,bias,bias,bias}, ac1 = ac0;
        #pragma unroll
        for (int S = 0; S < 8; ++S){
            uint4 bfv = packH[H_W2 + (w*8 + S)*64 + lane];
            uint4 a0 = *(const uint4*)TFA(c15,      S*32 + half*8);
            uint4 a1 = *(const uint4*)TFA(16 + c15, S*32 + half*8);
            ac0 = MFMA(a0, bfv, ac0); ac1 = MFMA(a1, bfv, ac1);
        }
        #pragma unroll
        for (int r = 0; r < 4; ++r){
            *(float*)XFA(half*4 + r,      col) += ac0[r];
            *(float*)XFA(16 + half*4 + r, col) += ac1[r];
        }
    }
    __syncthreads();

    {
        float4 v0 = *(const float4*)XFA(bb, g*8);
        float4 v1 = *(const float4*)XFA(bb, g*8 + 4);
        float vv[8] = {v0.x, v0.y, v0.z, v0.w, v1.x, v1.y, v1.z, v1.w};
        float s = 0.f, s2 = 0.f;
        #pragma unroll
        for (int j = 0; j < 8; ++j){ s += vv[j]; s2 += vv[j]*vv[j]; }
        #pragma unroll
        for (int msk = 1; msk < 8; msk <<= 1){ s += __shfl_xor(s, msk, 8); s2 += __shfl_xor(s2, msk, 8); }
        float mean = s * (1.f/64.f);
        float var  = s2 * (1.f/64.f) - mean*mean;
        float rstd = rsqrtf(var + 1e-5f);
        float xf[8];
        #pragma unroll
        for (int j = 0; j < 8; ++j){
            int c = g*8 + j;
            xf[j] = (vv[j] - mean) * rstd * ln2_g[c] + ln2_b[c];
        }
        uint4 u;
        u.x = pk2(xf[0], xf[1]); u.y = pk2(xf[2], xf[3]);
        u.z = pk2(xf[4], xf[5]); u.w = pk2(xf[6], xf[7]);
        *(uint4*)TBA(T0B, bb, g*8) = u;
    }
    __syncthreads();

    {
        int col = w*16 + c15;
        float bias = relu_b[col];
        f32x4 ac0 = {bias,bias,bias,bias}, ac1 = ac0;
        #pragma unroll
        for (int S = 0; S < 2; ++S){
            uint4 bfv = packH[H_RELU + (w*2 + S)*64 + lane];
            uint4 a0 = *(const uint4*)TBA(T0B, c15,      S*32 + half*8);
            uint4 a1 = *(const uint4*)TBA(T0B, 16 + c15, S*32 + half*8);
            ac0 = MFMA(a0, bfv, ac0); ac1 = MFMA(a1, bfv, ac1);
        }
        #pragma unroll
        for (int r = 0; r < 4; ++r){
            *(bf16*)TBA(XRB, half*4 + r,      col) = __float2bfloat16(ac0[r]);
            *(bf16*)TBA(XRB, 16 + half*4 + r, col) = __float2bfloat16(ac1[r]);
        }
    }
    __syncthreads();

    {
        int col = w*16 + c15;
        float bias = nd_b[col];
        f32x4 ac0 = {bias,bias,bias,bias}, ac1 = ac0;
        #pragma unroll
        for (int S = 0; S < 2; ++S){
            uint4 bfv = packH[H_ND + (w*2 + S)*64 + lane];
            uint4 a0 = *(const uint4*)TBA(XRB, c15,      S*32 + half*8);
            uint4 a1 = *(const uint4*)TBA(XRB, 16 + c15, S*32 + half*8);
            ac0 = MFMA(a0, bfv, ac0); ac1 = MFMA(a1, bfv, ac1);
        }
        #pragma unroll
        for (int r = 0; r < 4; ++r){
            *(bf16*)TBA(T1B, half*4 + r,      col) = __float2bfloat16(ac0[r]);
            *(bf16*)TBA(T1B, 16 + half*4 + r, col) = __float2bfloat16(ac1[r]);
        }
    }
    __syncthreads();

    {
        uint4 u = *(const uint4*)TBA(T1B, bb, g*8);
        float nf[8]; UNPK(u, nf);
        float p = 0.f;
        #pragma unroll
        for (int j = 0; j < 8; ++j) p = fmaf(nf[j], ldt_W[g*8 + j], p);
        #pragma unroll
        for (int msk = 1; msk < 8; msk <<= 1) p += __shfl_xor(p, msk, 8);
        if (g == 0){
            float dT = p + ldt_b[0];
            dTs[bb] = dT;
            out[(size_t)gb * 26] = dT;
        }
    }
    __syncthreads();

    {
        float dT = dTs[bb];
        for (int c8 = g; c8 < 12; c8 += 8){
            int cb = c8 * 8;
            unsigned pr[4];
            #pragma unroll
            for (int pj = 0; pj < 4; ++pj){
                int c0 = cb + 2*pj, c1 = c0 + 1;
                float v0 = (c0 == 0) ? dT :
                           (c0 <= 64 ? __bfloat162float(*(const bf16*)TBA(XRB, bb, c0-1)) : 0.f);
                float v1 = (c1 <= 64 ? __bfloat162float(*(const bf16*)TBA(XRB, bb, c1-1)) : 0.f);
                pr[pj] = pk2(v0, v1);
            }
            *(uint4*)TBA(T0B, bb, cb) = (uint4){pr[0], pr[1], pr[2], pr[3]};
        }
    }
    __syncthreads();

    {
        uint4 aS[3][2];
        #pragma unroll
        for (int S = 0; S < 3; ++S){
            aS[S][0] = *(const uint4*)TBA(T0B, c15,      S*32 + half*8);
            aS[S][1] = *(const uint4*)TBA(T0B, 16 + c15, S*32 + half*8);
        }
        int nbl[2]; int nnb = 1; nbl[0] = w;
        if (w == 0){ nbl[1] = 4; nnb = 2; }
        for (int q = 0; q < nnb; ++q){
            int nb = nbl[q];
            int col = nb*16 + c15;
            float bias = (col < 65) ? nz_b[col] : 0.f;
            f32x4 ac0 = {bias,bias,bias,bias}, ac1 = ac0;
            #pragma unroll
            for (int S = 0; S < 3; ++S){
                uint4 bfv = packH[H_NZ + (nb*3 + S)*64 + lane];
                ac0 = MFMA(aS[S][0], bfv, ac0); ac1 = MFMA(aS[S][1], bfv, ac1);
            }
            #pragma unroll
            for (int r = 0; r < 4; ++r){
                *(bf16*)TBA(T1B, half*4 + r,      col) = __float2bfloat16(ac0[r]);
                *(bf16*)TBA(T1B, 16 + half*4 + r, col) = __float2bfloat16(ac1[r]);
            }
        }
        if (t < 64){
            int row = t >> 1, seg = t & 1;
            *(uint4*)TBA(T1B, row, 80 + seg*8) = (uint4){0u,0u,0u,0u};
        }
    }
    __syncthreads();

    if (w < 2){
        uint4 aS[3][2];
        #pragma unroll
        for (int S = 0; S < 3; ++S){
            aS[S][0] = *(const uint4*)TBA(T1B, c15,      S*32 + half*8);
            aS[S][1] = *(const uint4*)TBA(T1B, 16 + c15, S*32 + half*8);
        }
        int nb = w;
        int col = nb*16 + c15;
        float bias = (col < 20) ? lz_b[col] : 0.f;
        f32x4 ac0 = {bias,bias,bias,bias}, ac1 = ac0;
        #pragma unroll
        for (int S = 0; S < 3; ++S){
            uint4 bfv = packH[H_LZ + (nb*3 + S)*64 + lane];
            ac0 = MFMA(aS[S][0], bfv, ac0); ac1 = MFMA(aS[S][1], bfv, ac1);
        }
        #pragma unroll
        for (int r = 0; r < 4; ++r){
            int r0 = half*4 + r, r1 = 16 + half*4 + r;
            *(bf16*)TBA(TQB, r0, col) = __float2bfloat16(ac0[r]);
            *(bf16*)TBA(TQB, r1, col) = __float2bfloat16(ac1[r]);
            if (col < 20){
                out[(size_t)(B0 + r0) * 26 + 1 + col] = ac0[r];
                out[(size_t)(B0 + r1) * 26 + 1 + col] = ac1[r];
            }
        }
    }
    __syncthreads();

    {
        float dT = dTs[bb];
        for (int c8 = g; c8 < 12; c8 += 8){
            int cb = c8 * 8;
            unsigned pr[4];
            #pragma unroll
            for (int pj = 0; pj < 4; ++pj){
                float vv[2];
                #pragma unroll
                for (int hh = 0; hh < 2; ++hh){
                    int c = cb + 2*pj + hh;
                    float v;
                    if (c < 20)       v = __bfloat162float(*(const bf16*)TBA(TQB, bb, c));
                    else if (c == 20) v = dT;
                    else if (c < 85)  v = __bfloat162float(*(const bf16*)TBA(XRB, bb, c - 21));
                    else              v = 0.f;
                    vv[hh] = v;
                }
                pr[pj] = pk2(vv[0], vv[1]);
            }
            *(uint4*)TBA(T0B, bb, cb) = (uint4){pr[0], pr[1], pr[2], pr[3]};
        }
    }
    __syncthreads();

    {
        uint4 aS[3][2];
        #pragma unroll
        for (int S = 0; S < 3; ++S){
            aS[S][0] = *(const uint4*)TBA(T0B, c15,      S*32 + half*8);
            aS[S][1] = *(const uint4*)TBA(T0B, 16 + c15, S*32 + half*8);
        }
        int nbl[2]; int nnb = 1; nbl[0] = w;
        if (w < 2){ nbl[1] = 4 + w; nnb = 2; }
        for (int q = 0; q < nnb; ++q){
            int nb = nbl[q];
            int col = nb*16 + c15;
            float bias = (col < 85) ? na0_b[col] : 0.f;
            f32x4 ac0 = {bias,bias,bias,bias}, ac1 = ac0;
            #pragma unroll
            for (int S = 0; S < 3; ++S){
                uint4 bfv = packH[H_NA0 + (nb*3 + S)*64 + lane];
                ac0 = MFMA(aS[S][0], bfv, ac0); ac1 = MFMA(aS[S][1], bfv, ac1);
            }
            #pragma unroll
            for (int r = 0; r < 4; ++r){
                *(bf16*)TBA(T1B, half*4 + r,      col) = __float2bfloat16(ac0[r]);
                *(bf16*)TBA(T1B, 16 + half*4 + r, col) = __float2bfloat16(ac1[r]);
            }
        }
    }
    __syncthreads();

    {
        uint4 aS[3][2];
        #pragma unroll
        for (int S = 0; S < 3; ++S){
            aS[S][0] = *(const uint4*)TBA(T1B, c15,      S*32 + half*8);
            aS[S][1] = *(const uint4*)TBA(T1B, 16 + c15, S*32 + half*8);
        }
        int nbl[2]; int nnb = 1; nbl[0] = w;
        if (w < 2){ nbl[1] = 4 + w; nnb = 2; }
        for (int q = 0; q < nnb; ++q){
            int nb = nbl[q];
            int col = nb*16 + c15;
            float bias = (col < 85) ? na1_b[col] : 0.f;
            f32x4 ac0 = {bias,bias,bias,bias}, ac1 = ac0;
            #pragma unroll
            for (int S = 0; S < 3; ++S){
                uint4 bfv = packH[H_NA1 + (nb*3 + S)*64 + lane];
                ac0 = MFMA(aS[S][0], bfv, ac0); ac1 = MFMA(aS[S][1], bfv, ac1);
            }
            #pragma unroll
            for (int r = 0; r < 4; ++r){
                *(bf16*)TBA(T0B, half*4 + r,      col) = __float2bfloat16(ac0[r]);
                *(bf16*)TBA(T0B, 16 + half*4 + r, col) = __float2bfloat16(ac1[r]);
            }
        }
    }
    __syncthreads();

    if (w == 0){
        int col = c15;
        float bias = (col < 5) ? la_b[col] : 0.f;
        f32x4 ac0 = {bias,bias,bias,bias}, ac1 = ac0;
        #pragma unroll
        for (int S = 0; S < 3; ++S){
            uint4 bfv = packH[H_LA + S*64 + lane];
            uint4 a0 = *(const uint4*)TBA(T0B, c15,      S*32 + half*8);
            uint4 a1 = *(const uint4*)TBA(T0B, 16 + c15, S*32 + half*8);
            ac0 = MFMA(a0, bfv, ac0); ac1 = MFMA(a1, bfv, ac1);
        }
        if (col < 5){
            #pragma unroll
            for (int r = 0; r < 4; ++r){
                out[(size_t)(B0 + half*4 + r) * 26 + 21 + col]      = ac0[r];
                out[(size_t)(B0 + 16 + half*4 + r) * 26 + 21 + col] = ac1[r];
            }
        }
    }
}

extern "C" void kernel_launch(void* const* d_in, const int* in_sizes, int n_in,
                              void* d_out, int out_size, void* d_ws, size_t ws_size,
                              hipStream_t stream)
{
    const float* X        = (const float*)d_in[0];
    const float* emb_act  = (const float*)d_in[1];
    const float* emb_zone = (const float*)d_in[2];
    const float* lin0_W   = (const float*)d_in[3];
    const float* lin0_b   = (const float*)d_in[4];
    const float* gat_W    = (const float*)d_in[5];
    const float* gat_b    = (const float*)d_in[6];
    const float* gat_a    = (const float*)d_in[7];
    const float* gl0_W    = (const float*)d_in[8];
    const float* gl0_b    = (const float*)d_in[9];
    const float* gl1_W    = (const float*)d_in[10];
    const float* gl1_b    = (const float*)d_in[11];
    const float* gl2_W    = (const float*)d_in[12];
    const float* gl2_b    = (const float*)d_in[13];
    const float* Wqkv     = (const float*)d_in[14];
    const float* bqkv     = (const float*)d_in[15];
    const float* Wo       = (const float*)d_in[16];
    const float* bo       = (const float*)d_in[17];
    const float* ln1_g    = (const float*)d_in[18];
    const float* ln1_b    = (const float*)d_in[19];
    const float* W1       = (const float*)d_in[20];
    const float* b1       = (const float*)d_in[21];
    const float* W2       = (const float*)d_in[22];
    const float* b2       = (const float*)d_in[23];
    const float* ln2_g    = (const float*)d_in[24];
    const float* ln2_b    = (const float*)d_in[25];
    const float* relu_W   = (const float*)d_in[26];
    const float* relu_b   = (const float*)d_in[27];
    const float* nd_W     = (const float*)d_in[28];
    const float* nd_b     = (const float*)d_in[29];
    const float* ldt_W    = (const float*)d_in[30];
    const float* ldt_b    = (const float*)d_in[31];
    const float* nz_W     = (const float*)d_in[32];
    const float* nz_b     = (const float*)d_in[33];
    const float* lz_W     = (const float*)d_in[34];
    const float* lz_b     = (const float*)d_in[35];
    const float* na0_W    = (const float*)d_in[36];
    const float* na0_b    = (const float*)d_in[37];
    const float* na1_W    = (const float*)d_in[38];
    const float* na1_b    = (const float*)d_in[39];
    const float* la_W     = (const float*)d_in[40];
    const float* la_b     = (const float*)d_in[41];

    char* wsb = (char*)d_ws;
    bf16*  kv       = (bf16*)wsb;
    float* src_last = (float*)(wsb + (size_t)NTOK * 128 * sizeof(bf16));
    uint4* packW    = (uint4*)(wsb + (size_t)NTOK * 128 * sizeof(bf16) + (size_t)B_ * 64 * sizeof(float));
    uint4* packH    = packW + PK_TOT;

    k_pack_all<<<(PK_TOT + H_TOT + 255)/256, 256, 0, stream>>>(
        gl0_W, gl1_W, gl2_W, Wqkv, Wo, W1, W2, relu_W, nd_W, nz_W, lz_W,
        na0_W, na1_W, la_W, packW, packH);

    k_token<<<NTOK/TOKB, TPB, 0, stream>>>(X, emb_act, emb_zone, lin0_W, lin0_b,
        gat_W, gat_b, gat_a, gl0_b, gl1_b, gl2_b, bqkv, packW, kv, src_last);

    k_head2<<<B_/32, 256, 0, stream>>>(kv, src_last, packH, bqkv, bo,
        ln1_g, ln1_b, b1, b2, ln2_g, ln2_b, relu_b, nd_b, ldt_W, ldt_b,
        nz_b, lz_b, na0_b, na1_b, la_b, (float*)d_out);
}

// Round 9
// 74.431 us; speedup vs baseline: 2.4760x; 1.0315x over previous
//
#include <hip/hip_runtime.h>
#include <hip/hip_bf16.h>

typedef __hip_bfloat16 bf16;
typedef float f32x4 __attribute__((ext_vector_type(4)));
typedef short s16x8 __attribute__((ext_vector_type(8)));

#define B_    2048
#define S_    40
#define NTOK  (B_*S_)
#define TPB   256
#define TOKB  64

// ---- k_token LDS layout (dwords). A1 aliases FF (FF dead after phase 1).
#define FF_OFF    0        // 64 tokens x 55 u32 (110 bf16 contiguous, stride 55 odd)
#define A1_OFFD   0        // A1: 64 rows x 128B bf16 (aliases FF)
#define A0_OFFD   3520     // A0: 64 rows x 256B bf16 (K=128, k=5i+d); also KV staging
#define PE_OFFD   7616     // 64 f32
#define IA_OFFD   7680     // 64 u32 (ia<<16 | iz)
#define HD_OFFD   7744     // 64 x 6 f32 (X cols 2..7), stride 6
#define LDS_DW    8128     // 32512 B -> 5 blocks/CU

#define A0B (A0_OFFD*4)
#define A1B (A1_OFFD*4)

// ---- packW (token) fragment offsets (uint4 units)
#define PK_GL0 0
#define PK_GL1 1024
#define PK_GL2 1536
#define PK_KV  1664
#define PK_TOT 2688

// ---- packH (head) fragment offsets (uint4 units)
#define H_WQ   0
#define H_WO   512
#define H_W1   1024
#define H_W2   3072
#define H_RELU 5120
#define H_ND   5632
#define H_NZ   6144
#define H_LZ   7104
#define H_NA0  7488
#define H_NA1  8640
#define H_LA   9792
#define H_TOT  9984

__device__ inline unsigned pk2(float a, float b){
    __hip_bfloat16 ha = __float2bfloat16(a), hb = __float2bfloat16(b);
    unsigned short ua = *reinterpret_cast<unsigned short*>(&ha);
    unsigned short ub = *reinterpret_cast<unsigned short*>(&hb);
    return (unsigned)ua | ((unsigned)ub << 16);
}
__device__ inline float blo(unsigned u){ return __uint_as_float(u << 16); }
__device__ inline float bhi(unsigned u){ return __uint_as_float(u & 0xffff0000u); }

__device__ inline float fexp2(float x){
#if __has_builtin(__builtin_amdgcn_exp2f)
    return __builtin_amdgcn_exp2f(x);
#else
    return exp2f(x);
#endif
}

__device__ inline f32x4 MFMA(uint4 a, uint4 b, f32x4 c){
    union { uint4 q; s16x8 s; } A, Bv;
    A.q = a; Bv.q = b;
    return __builtin_amdgcn_mfma_f32_16x16x32_bf16(A.s, Bv.s, c, 0, 0, 0);
}

// load ff row j (5 bf16 at bf16-index 5j) from contiguous packing
__device__ inline void ldff(const unsigned* L, unsigned tb, int j, float f[5]){
    int k = (5*j) >> 1;
    unsigned u0 = L[tb + k], u1 = L[tb + k + 1], u2 = L[tb + k + 2];
    if ((j & 1) == 0){
        f[0]=blo(u0); f[1]=bhi(u0); f[2]=blo(u1); f[3]=bhi(u1); f[4]=blo(u2);
    } else {
        f[0]=bhi(u0); f[1]=blo(u1); f[2]=bhi(u1); f[3]=blo(u2); f[4]=bhi(u2);
    }
}

__device__ inline uint4 packB(const float* W, int ld, int K, int N, int nb, int S, int lane){
    int half = lane >> 4, c15 = lane & 15;
    int col = nb*16 + c15;
    unsigned pr[4];
    #pragma unroll
    for (int jj = 0; jj < 4; ++jj){
        int k0 = S*32 + half*8 + 2*jj;
        float v0 = (k0   < K && col < N) ? W[(size_t)k0*ld + col]     : 0.f;
        float v1 = (k0+1 < K && col < N) ? W[(size_t)(k0+1)*ld + col] : 0.f;
        pr[jj] = pk2(v0, v1);
    }
    return (uint4){pr[0], pr[1], pr[2], pr[3]};
}

// ---------------- Kernel 0: pre-pack ALL weight fragments ----------------
__global__ __launch_bounds__(256) void k_pack_all(
    const float* __restrict__ gl0_W, const float* __restrict__ gl1_W,
    const float* __restrict__ gl2_W, const float* __restrict__ Wqkv,
    const float* __restrict__ Wo,    const float* __restrict__ W1,
    const float* __restrict__ W2,    const float* __restrict__ relu_W,
    const float* __restrict__ nd_W,  const float* __restrict__ nz_W,
    const float* __restrict__ lz_W,  const float* __restrict__ na0_W,
    const float* __restrict__ na1_W, const float* __restrict__ la_W,
    uint4* __restrict__ packW, uint4* __restrict__ packH)
{
    int f = blockIdx.x * 256 + threadIdx.x;
    if (f < PK_TOT){
        unsigned pr[4];
        if (f < PK_GL1){
            int w = f >> 8, r = f & 255, S = r >> 6, lane = r & 63;
            int half = lane >> 4, c15 = lane & 15, col = w * 16 + c15;
            #pragma unroll
            for (int jj = 0; jj < 4; ++jj){
                int k0 = S*32 + half*8 + 2*jj;
                float v0 = (k0   < 110) ? gl0_W[k0*64 + col]     : 0.f;
                float v1 = (k0+1 < 110) ? gl0_W[(k0+1)*64 + col] : 0.f;
                pr[jj] = pk2(v0, v1);
            }
        } else if (f < PK_GL2){
            int g = f - PK_GL1, w = g >> 7, r = g & 127, S = r >> 6, lane = r & 63;
            int half = lane >> 4, c15 = lane & 15, col = w * 16 + c15;
            #pragma unroll
            for (int jj = 0; jj < 4; ++jj){
                int k0 = S*32 + half*8 + 2*jj;
                pr[jj] = pk2(gl1_W[k0*64 + col], gl1_W[(k0+1)*64 + col]);
            }
        } else if (f < PK_KV){
            int g = f - PK_GL2, S = g >> 6, lane = g & 63;
            int half = lane >> 4, c15 = lane & 15;
            #pragma unroll
            for (int jj = 0; jj < 4; ++jj){
                int k0 = S*32 + half*8 + 2*jj;
                pr[jj] = pk2(gl2_W[k0*16 + c15], gl2_W[(k0+1)*16 + c15]);
            }
        } else {
            int g = f - PK_KV, w = g >> 8, r = g & 255, cf = r >> 7, r2 = r & 127;
            int S = r2 >> 6, lane = r2 & 63;
            int half = lane >> 4, c15 = lane & 15, col = 64 + w*32 + cf*16 + c15;
            #pragma unroll
            for (int jj = 0; jj < 4; ++jj){
                int k0 = S*32 + half*8 + 2*jj;
                pr[jj] = pk2(Wqkv[k0*192 + col], Wqkv[(k0+1)*192 + col]);
            }
        }
        packW[f] = (uint4){pr[0], pr[1], pr[2], pr[3]};
        return;
    }
    int f2 = f - PK_TOT;
    if (f2 >= H_TOT) return;
    const float* W; int ld, K, N, St, base;
    if      (f2 < H_WO ){ W=Wqkv;   ld=192; K=64;  N=64;  St=2; base=H_WQ;  }
    else if (f2 < H_W1 ){ W=Wo;     ld=64;  K=64;  N=64;  St=2; base=H_WO;  }
    else if (f2 < H_W2 ){ W=W1;     ld=256; K=64;  N=256; St=2; base=H_W1;  }
    else if (f2 < H_RELU){W=W2;     ld=64;  K=256; N=64;  St=8; base=H_W2;  }
    else if (f2 < H_ND ){ W=relu_W; ld=64;  K=64;  N=64;  St=2; base=H_RELU;}
    else if (f2 < H_NZ ){ W=nd_W;   ld=64;  K=64;  N=64;  St=2; base=H_ND;  }
    else if (f2 < H_LZ ){ W=nz_W;   ld=65;  K=65;  N=65;  St=3; base=H_NZ;  }
    else if (f2 < H_NA0){ W=lz_W;   ld=20;  K=65;  N=20;  St=3; base=H_LZ;  }
    else if (f2 < H_NA1){ W=na0_W;  ld=85;  K=85;  N=85;  St=3; base=H_NA0; }
    else if (f2 < H_LA ){ W=na1_W;  ld=85;  K=85;  N=85;  St=3; base=H_NA1; }
    else               { W=la_W;   ld=5;   K=85;  N=5;   St=3; base=H_LA;  }
    int loc = f2 - base;
    int nb = loc / (St*64);
    int rem = loc - nb*St*64;
    packH[f2] = packB(W, ld, K, N, nb, rem >> 6, rem & 63);
}

// ---------------- Kernel 1: MFMA featurizer ----------------
__global__ __launch_bounds__(TPB) void k_token(
    const float* __restrict__ X,
    const float* __restrict__ emb_act,
    const float* __restrict__ emb_zone,
    const float* __restrict__ lin0_W, const float* __restrict__ lin0_b,
    const float* __restrict__ gat_W,  const float* __restrict__ gat_b,
    const float* __restrict__ gat_a,
    const float* __restrict__ gl0_b,  const float* __restrict__ gl1_b,
    const float* __restrict__ gl2_b,  const float* __restrict__ bqkv,
    const uint4* __restrict__ packW,
    bf16* __restrict__ kv, float* __restrict__ src_last)
{
    __shared__ unsigned L[LDS_DW];
    char* Lb = (char*)L;

    const int t    = threadIdx.x;
    const int w    = t >> 6;
    const int lane = t & 63;
    const int half = (lane >> 4);
    const int c15  = lane & 15;
    const int blk0 = blockIdx.x * TOKB;
    const int swzc = (c15 & 7) << 4;

    // ---------- phase 0: ff (row pairs -> 5 u32), head/pe/ia -> LDS, A0 pad zero ----------
    for (int task = t; task < TOKB * 11; task += TPB){
        int tt = task / 11;
        int p  = task - tt * 11;
        const float2* xp = (const float2*)(X + (size_t)(blk0 + tt) * 118 + 8 + 10 * p);
        float2 a0 = xp[0], a1 = xp[1], a2 = xp[2], a3 = xp[3], a4 = xp[4];
        unsigned* dst = &L[FF_OFF + tt * 55 + 5 * p];
        dst[0] = pk2(a0.x, a0.y);
        dst[1] = pk2(a1.x, a1.y);
        dst[2] = pk2(a2.x, a2.y);
        dst[3] = pk2(a3.x, a3.y);
        dst[4] = pk2(a4.x, a4.y);
    }
    // zero-pad A0 k in [110,128): bytes [220,256)
    for (int idx = t; idx < 64 * 9; idx += TPB){
        int row = idx / 9, p = idx - row * 9;
        *(unsigned*)(Lb + A0B + row * 256 + ((220 + 4*p) ^ ((row & 7) << 4))) = 0u;
    }
    if (t < TOKB){
        int tok = blk0 + t;
        const float2* xp = (const float2*)(X + (size_t)tok * 118);
        float2 v0 = xp[0], v1 = xp[1], v2 = xp[2], v3 = xp[3];
        int b = tok / 40, s = tok - b * 40;
        float expo = (2.0f * (float)s) / 40.0f;
        float inv100 = fexp2(-expo * 6.6438561897747395f);   // 100^-expo
        float ang = (float)b * inv100;
        float pe = ((s & 1) == 0) ? __sinf(ang) : __cosf(ang);
        ((float*)&L[PE_OFFD])[t] = pe;
        L[IA_OFFD + t] = (((unsigned)(int)v0.x) << 16) | ((unsigned)(int)v0.y & 0xffffu);
        float* hdL = (float*)&L[HD_OFFD + t * 6];
        hdL[0] = v1.x; hdL[1] = v1.y; hdL[2] = v2.x;
        hdL[3] = v2.y; hdL[4] = v3.x; hdL[5] = v3.y;
    }
    __syncthreads();

    // ---------- phase 1: GAT -> hp (bf16) into A0 (k = 5i+d, K=128) ----------
    {
        const float LOG2E = 1.4426950408889634f;
        const unsigned tb = FF_OFF + lane * 55;
        float va1[5], va2[5];
        float cc1 = 0.f, cc2 = 0.f;
        #pragma unroll
        for (int e = 0; e < 5; ++e){
            float u1 = 0.f, u2 = 0.f;
            #pragma unroll
            for (int d = 0; d < 5; ++d){
                u1 += gat_W[e*5+d] * gat_a[d];
                u2 += gat_W[e*5+d] * gat_a[5+d];
            }
            va1[e] = u1 * LOG2E; va2[e] = u2 * LOG2E;
        }
        #pragma unroll
        for (int d = 0; d < 5; ++d){ cc1 += gat_b[d]*gat_a[d]; cc2 += gat_b[d]*gat_a[5+d]; }
        cc1 *= LOG2E; cc2 *= LOG2E;

        // prepass: m2 = max_j s2'_j (no storage)
        float m2 = -1e30f;
        #pragma unroll
        for (int j = 0; j < 22; ++j){
            float f[5]; ldff(L, tb, j, f);
            float s2j = cc2 + f[0]*va2[0] + f[1]*va2[1] + f[2]*va2[2] + f[3]*va2[3] + f[4]*va2[4];
            m2 = fmaxf(m2, s2j);
        }

        const int wbase = w * 6;
        float s1own[6], negmi[6], Z[6], ffp[6][5];
        #pragma unroll
        for (int ii = 0; ii < 6; ++ii){
            int i = wbase + ii; if (i > 21) i = 21;
            float f[5]; ldff(L, tb, i, f);
            float s1 = cc1 + f[0]*va1[0] + f[1]*va1[1] + f[2]*va1[2] + f[3]*va1[3] + f[4]*va1[4];
            s1own[ii] = s1;
            float em = s1 + m2;
            negmi[ii] = -fmaxf(em, 0.2f * em);
            Z[ii] = 0.f;
            #pragma unroll
            for (int e = 0; e < 5; ++e) ffp[ii][e] = 0.f;
        }

        #pragma unroll
        for (int j = 0; j < 22; ++j){
            float f[5]; ldff(L, tb, j, f);
            float s2j = cc2 + f[0]*va2[0] + f[1]*va2[1] + f[2]*va2[2] + f[3]*va2[3] + f[4]*va2[4];
            #pragma unroll
            for (int ii = 0; ii < 6; ++ii){
                float e2 = s1own[ii] + s2j;
                float a  = e2 + negmi[ii];
                float bq = fmaf(0.2f, e2, negmi[ii]);
                float wg = fexp2(fmaxf(a, bq));
                Z[ii] += wg;
                ffp[ii][0] = fmaf(wg, f[0], ffp[ii][0]);
                ffp[ii][1] = fmaf(wg, f[1], ffp[ii][1]);
                ffp[ii][2] = fmaf(wg, f[2], ffp[ii][2]);
                ffp[ii][3] = fmaf(wg, f[3], ffp[ii][3]);
                ffp[ii][4] = fmaf(wg, f[4], ffp[ii][4]);
            }
        }

        const int rswz = (lane & 7) << 4;
        #pragma unroll
        for (int ii = 0; ii < 6; ++ii){
            int i = wbase + ii;
            if (i < 22){
                float rz = 1.f / Z[ii];
                #pragma unroll
                for (int d = 0; d < 5; ++d){
                    float u = 0.f;
                    #pragma unroll
                    for (int e = 0; e < 5; ++e) u += ffp[ii][e] * gat_W[e*5+d];
                    float h = u * rz + gat_b[d];
                    *(bf16*)(Lb + A0B + lane*256 + ((10*i + 2*d) ^ rswz)) = __float2bfloat16(h);
                }
            }
        }
    }
    __syncthreads();

    // ---------- phase 2: gl0 MFMA (K=128) -> A1 ----------
    {
        uint4 bfr[4];
        #pragma unroll
        for (int S = 0; S < 4; ++S) bfr[S] = packW[PK_GL0 + (w*4 + S)*64 + lane];
        const int col = w * 16 + c15;
        float bias = gl0_b[col];
        f32x4 ac0 = {bias,bias,bias,bias}, ac1 = ac0, ac2 = ac0, ac3 = ac0;
        #pragma unroll
        for (int S = 0; S < 4; ++S){
            int koff = S*64 + half*16;
            uint4 a0 = *(const uint4*)(Lb + A0B + (0*16 + c15)*256 + (koff ^ swzc));
            uint4 a1 = *(const uint4*)(Lb + A0B + (1*16 + c15)*256 + (koff ^ swzc));
            uint4 a2 = *(const uint4*)(Lb + A0B + (2*16 + c15)*256 + (koff ^ swzc));
            uint4 a3 = *(const uint4*)(Lb + A0B + (3*16 + c15)*256 + (koff ^ swzc));
            ac0 = MFMA(a0, bfr[S], ac0);
            ac1 = MFMA(a1, bfr[S], ac1);
            ac2 = MFMA(a2, bfr[S], ac2);
            ac3 = MFMA(a3, bfr[S], ac3);
        }
        const int off = col * 2;
        #pragma unroll
        for (int r = 0; r < 4; ++r){
            int row0 = 0*16 + half*4 + r;
            int row1 = 1*16 + half*4 + r;
            int row2 = 2*16 + half*4 + r;
            int row3 = 3*16 + half*4 + r;
            *(bf16*)(Lb + A1B + row0*128 + (off ^ ((row0 & 7) << 4))) = __float2bfloat16(fmaxf(ac0[r], 0.f));
            *(bf16*)(Lb + A1B + row1*128 + (off ^ ((row1 & 7) << 4))) = __float2bfloat16(fmaxf(ac1[r], 0.f));
            *(bf16*)(Lb + A1B + row2*128 + (off ^ ((row2 & 7) << 4))) = __float2bfloat16(fmaxf(ac2[r], 0.f));
            *(bf16*)(Lb + A1B + row3*128 + (off ^ ((row3 & 7) << 4))) = __float2bfloat16(fmaxf(ac3[r], 0.f));
        }
    }
    __syncthreads();

    // ---------- phase 3: gl1 MFMA (A1 -> A0, stride 128B) ----------
    {
        uint4 bfr[2];
        #pragma unroll
        for (int S = 0; S < 2; ++S) bfr[S] = packW[PK_GL1 + (w*2 + S)*64 + lane];
        const int col = w * 16 + c15;
        float bias = gl1_b[col];
        f32x4 ac0 = {bias,bias,bias,bias}, ac1 = ac0, ac2 = ac0, ac3 = ac0;
        #pragma unroll
        for (int S = 0; S < 2; ++S){
            int koff = S*64 + half*16;
            uint4 a0 = *(const uint4*)(Lb + A1B + (0*16 + c15)*128 + (koff ^ swzc));
            uint4 a1 = *(const uint4*)(Lb + A1B + (1*16 + c15)*128 + (koff ^ swzc));
            uint4 a2 = *(const uint4*)(Lb + A1B + (2*16 + c15)*128 + (koff ^ swzc));
            uint4 a3 = *(const uint4*)(Lb + A1B + (3*16 + c15)*128 + (koff ^ swzc));
            ac0 = MFMA(a0, bfr[S], ac0);
            ac1 = MFMA(a1, bfr[S], ac1);
            ac2 = MFMA(a2, bfr[S], ac2);
            ac3 = MFMA(a3, bfr[S], ac3);
        }
        const int off = col * 2;
        #pragma unroll
        for (int r = 0; r < 4; ++r){
            int row0 = 0*16 + half*4 + r;
            int row1 = 1*16 + half*4 + r;
            int row2 = 2*16 + half*4 + r;
            int row3 = 3*16 + half*4 + r;
            *(bf16*)(Lb + A0B + row0*128 + (off ^ ((row0 & 7) << 4))) = __float2bfloat16(fmaxf(ac0[r], 0.f));
            *(bf16*)(Lb + A0B + row1*128 + (off ^ ((row1 & 7) << 4))) = __float2bfloat16(fmaxf(ac1[r], 0.f));
            *(bf16*)(Lb + A0B + row2*128 + (off ^ ((row2 & 7) << 4))) = __float2bfloat16(fmaxf(ac2[r], 0.f));
            *(bf16*)(Lb + A0B + row3*128 + (off ^ ((row3 & 7) << 4))) = __float2bfloat16(fmaxf(ac3[r], 0.f));
        }
    }
    __syncthreads();

    // ---------- phase 4: gl2 MFMA + src build into A1 ----------
    {
        uint4 bfr[2];
        #pragma unroll
        for (int S = 0; S < 2; ++S) bfr[S] = packW[PK_GL2 + S*64 + lane];
        float bias = gl2_b[c15];
        f32x4 ac = {bias,bias,bias,bias};
        #pragma unroll
        for (int S = 0; S < 2; ++S){
            int koff = S*64 + half*16;
            uint4 a = *(const uint4*)(Lb + A0B + (w*16 + c15)*128 + (koff ^ swzc));
            ac = MFMA(a, bfr[S], ac);
        }
        const float* pef = (const float*)&L[PE_OFFD];
        const int off = (48 + c15) * 2;
        #pragma unroll
        for (int r = 0; r < 4; ++r){
            int row = w*16 + half*4 + r;
            float v = fmaxf(ac[r], 0.f) + pef[row];
            *(bf16*)(Lb + A1B + row*128 + (off ^ ((row & 7) << 4))) = __float2bfloat16(v);
        }

        float pe = pef[lane];
        unsigned iaz = L[IA_OFFD + lane];
        int ia = (int)(iaz >> 16), iz = (int)(iaz & 0xffffu);
        const float* hdL = (const float*)&L[HD_OFFD + lane * 6];
        const int tswz = (lane & 7) << 4;
        #pragma unroll
        for (int pp = 0; pp < 6; ++pp){
            int p = w * 6 + pp;
            int c0 = 2 * p;
            float v0, v1;
            if (p < 8)        { v0 = emb_act[ia*16 + c0];        v1 = emb_act[ia*16 + c0 + 1]; }
            else if (p < 16)  { v0 = emb_zone[iz*16 + c0 - 16];  v1 = emb_zone[iz*16 + c0 - 15]; }
            else {
                int cc = c0 - 32;
                float o0 = lin0_b[cc], o1 = lin0_b[cc+1];
                #pragma unroll
                for (int e = 0; e < 6; ++e){
                    float f = hdL[e];
                    o0 = fmaf(f, lin0_W[e*16 + cc], o0);
                    o1 = fmaf(f, lin0_W[e*16 + cc + 1], o1);
                }
                v0 = o0; v1 = o1;
            }
            *(unsigned*)(Lb + A1B + lane*128 + ((4*p) ^ tswz)) = pk2(v0 + pe, v1 + pe);
        }
    }
    __syncthreads();

    // ---------- phase 5: src_last + KV MFMA ----------
    {
        int r0 = 39 - (blk0 % 40);
        if (t < 128){
            int tok = r0 + 40 * (t >> 6);
            if (tok < 64){
                int col = t & 63;
                bf16 hv = *(const bf16*)(Lb + A1B + tok*128 + ((col*2) ^ ((tok & 7) << 4)));
                src_last[(size_t)((blk0 + tok) / 40) * 64 + col] = __bfloat162float(hv);
            }
        }

        uint4 bfk[2][2];
        #pragma unroll
        for (int cf = 0; cf < 2; ++cf)
            #pragma unroll
            for (int S = 0; S < 2; ++S)
                bfk[cf][S] = packW[PK_KV + ((w*2 + cf)*2 + S)*64 + lane];

        float b0v = bqkv[64 + w*32 + c15];
        float b1v = bqkv[64 + w*32 + 16 + c15];
        f32x4 acc[4][2];
        #pragma unroll
        for (int R = 0; R < 4; ++R){
            acc[R][0] = (f32x4){b0v, b0v, b0v, b0v};
            acc[R][1] = (f32x4){b1v, b1v, b1v, b1v};
        }
        #pragma unroll
        for (int S = 0; S < 2; ++S){
            int koff = S*64 + half*16;
            #pragma unroll
            for (int R = 0; R < 4; ++R){
                uint4 a = *(const uint4*)(Lb + A1B + (R*16 + c15)*128 + (koff ^ swzc));
                acc[R][0] = MFMA(a, bfk[0][S], acc[R][0]);
                acc[R][1] = MFMA(a, bfk[1][S], acc[R][1]);
            }
        }
        #pragma unroll
        for (int R = 0; R < 4; ++R){
            #pragma unroll
            for (int cf = 0; cf < 2; ++cf){
                int lcol = w*32 + cf*16 + c15;
                int off = lcol * 2;
                #pragma unroll
                for (int r = 0; r < 4; ++r){
                    int row = R*16 + half*4 + r;
                    *(bf16*)(Lb + A0B + row*256 + (off ^ ((row & 7) << 4))) = __float2bfloat16(acc[R][cf][r]);
                }
            }
        }
    }
    __syncthreads();

    {
        int row = t >> 2;
        int q = t & 3;
        #pragma unroll
        for (int c = 0; c < 4; ++c){
            int chunk = q*4 + c;
            uint4 d = *(const uint4*)(Lb + A0B + row*256 + ((chunk*16) ^ ((row & 7) << 4)));
            *((uint4*)(kv + (size_t)(blk0 + row) * 128 + chunk * 8)) = d;
        }
    }
}

// ---------------- Kernel 2: MFMA head (32 batches/block) ----------------
#define T0B 0
#define T1B 8192
#define TQB 16384
#define XRB 24576
#define XFB 32768
#define TFB 40960
#define DTS 57344

#define TBA(base, row, col) (Lb + (base) + (row)*256 + ((((col)*2)) ^ (((row)&7)<<4)))
#define TFA(row, col)       (Lb + TFB   + (row)*512 + ((((col)*2)) ^ (((row)&7)<<4)))
#define XFA(row, col)       (Lb + XFB   + (row)*256 + ((((col)*4)) ^ (((row)&7)<<4)))

#define UNPK(u, arr) { arr[0]=blo(u.x); arr[1]=bhi(u.x); arr[2]=blo(u.y); arr[3]=bhi(u.y); \
                       arr[4]=blo(u.z); arr[5]=bhi(u.z); arr[6]=blo(u.w); arr[7]=bhi(u.w); }

__global__ __launch_bounds__(256) void k_head2(
    const bf16* __restrict__ kv, const float* __restrict__ src_last,
    const uint4* __restrict__ packH,
    const float* __restrict__ bqkv,  const float* __restrict__ bo,
    const float* __restrict__ ln1_g, const float* __restrict__ ln1_b,
    const float* __restrict__ b1,    const float* __restrict__ b2,
    const float* __restrict__ ln2_g, const float* __restrict__ ln2_b,
    const float* __restrict__ relu_b, const float* __restrict__ nd_b,
    const float* __restrict__ ldt_W, const float* __restrict__ ldt_b,
    const float* __restrict__ nz_b,  const float* __restrict__ lz_b,
    const float* __restrict__ na0_b, const float* __restrict__ na1_b,
    const float* __restrict__ la_b,
    float* __restrict__ out)
{
    __shared__ uint4 Lsh[3592];
    char* Lb = (char*)Lsh;
    float* dTs = (float*)(Lb + DTS);

    const int t    = threadIdx.x;
    const int w    = t >> 6;
    const int lane = t & 63;
    const int half = lane >> 4;
    const int c15  = lane & 15;
    const int B0   = blockIdx.x * 32;
    const int bb   = t >> 3;
    const int g    = t & 7;
    const int gb   = B0 + bb;

    {
        const float4* sp = (const float4*)(src_last + (size_t)gb * 64 + g * 8);
        float4 v0 = sp[0], v1 = sp[1];
        *(float4*)XFA(bb, g*8)     = v0;
        *(float4*)XFA(bb, g*8 + 4) = v1;
        uint4 u;
        u.x = pk2(v0.x, v0.y); u.y = pk2(v0.z, v0.w);
        u.z = pk2(v1.x, v1.y); u.w = pk2(v1.z, v1.w);
        *(uint4*)TBA(T0B, bb, g*8) = u;
    }
    __syncthreads();

    {
        int col = w*16 + c15;
        float bias = bqkv[col];
        f32x4 ac0 = {bias,bias,bias,bias}, ac1 = ac0;
        #pragma unroll
        for (int S = 0; S < 2; ++S){
            uint4 bfv = packH[H_WQ + (w*2 + S)*64 + lane];
            uint4 a0 = *(const uint4*)TBA(T0B, c15,      S*32 + half*8);
            uint4 a1 = *(const uint4*)TBA(T0B, 16 + c15, S*32 + half*8);
            ac0 = MFMA(a0, bfv, ac0); ac1 = MFMA(a1, bfv, ac1);
        }
        #pragma unroll
        for (int r = 0; r < 4; ++r){
            *(bf16*)TBA(TQB, half*4 + r,      col) = __float2bfloat16(ac0[r] * 0.35355339059327373f);
            *(bf16*)TBA(TQB, 16 + half*4 + r, col) = __float2bfloat16(ac1[r] * 0.35355339059327373f);
        }
    }
    __syncthreads();

    {
        int pb = t >> 3, h = t & 7;
        int gpb = B0 + pb;
        uint4 qu = *(const uint4*)TBA(TQB, pb, h*8);
        float qh[8]; UNPK(qu, qh);
        const uint4* kp = (const uint4*)(kv + (size_t)gpb * 40 * 128 + h*8);
        const uint4* vp = (const uint4*)(kv + (size_t)gpb * 40 * 128 + 64 + h*8);
        float sc[40];
        float m = -1e30f;
        #pragma unroll 4
        for (int j = 0; j < 40; ++j){
            uint4 ku = kp[j*16];
            float kf[8]; UNPK(ku, kf);
            float a = qh[0]*kf[0] + qh[1]*kf[1] + qh[2]*kf[2] + qh[3]*kf[3]
                    + qh[4]*kf[4] + qh[5]*kf[5] + qh[6]*kf[6] + qh[7]*kf[7];
            sc[j] = a; m = fmaxf(m, a);
        }
        float Z = 0.f;
        float o[8] = {0.f,0.f,0.f,0.f,0.f,0.f,0.f,0.f};
        #pragma unroll 4
        for (int j = 0; j < 40; ++j){
            float wj = __expf(sc[j] - m);
            Z += wj;
            uint4 vu = vp[j*16];
            float vf[8]; UNPK(vu, vf);
            #pragma unroll
            for (int d = 0; d < 8; ++d) o[d] = fmaf(wj, vf[d], o[d]);
        }
        float rz = 1.f / Z;
        uint4 u;
        u.x = pk2(o[0]*rz, o[1]*rz); u.y = pk2(o[2]*rz, o[3]*rz);
        u.z = pk2(o[4]*rz, o[5]*rz); u.w = pk2(o[6]*rz, o[7]*rz);
        *(uint4*)TBA(T1B, pb, h*8) = u;
    }
    __syncthreads();

    {
        int col = w*16 + c15;
        float bias = bo[col];
        f32x4 ac0 = {bias,bias,bias,bias}, ac1 = ac0;
        #pragma unroll
        for (int S = 0; S < 2; ++S){
            uint4 bfv = packH[H_WO + (w*2 + S)*64 + lane];
            uint4 a0 = *(const uint4*)TBA(T1B, c15,      S*32 + half*8);
            uint4 a1 = *(const uint4*)TBA(T1B, 16 + c15, S*32 + half*8);
            ac0 = MFMA(a0, bfv, ac0); ac1 = MFMA(a1, bfv, ac1);
        }
        #pragma unroll
        for (int r = 0; r < 4; ++r){
            *(float*)XFA(half*4 + r,      col) += ac0[r];
            *(float*)XFA(16 + half*4 + r, col) += ac1[r];
        }
    }
    __syncthreads();

    {
        float4 v0 = *(const float4*)XFA(bb, g*8);
        float4 v1 = *(const float4*)XFA(bb, g*8 + 4);
        float vv[8] = {v0.x, v0.y, v0.z, v0.w, v1.x, v1.y, v1.z, v1.w};
        float s = 0.f, s2 = 0.f;
        #pragma unroll
        for (int j = 0; j < 8; ++j){ s += vv[j]; s2 += vv[j]*vv[j]; }
        #pragma unroll
        for (int msk = 1; msk < 8; msk <<= 1){ s += __shfl_xor(s, msk, 8); s2 += __shfl_xor(s2, msk, 8); }
        float mean = s * (1.f/64.f);
        float var  = s2 * (1.f/64.f) - mean*mean;
        float rstd = rsqrtf(var + 1e-5f);
        float xf[8];
        #pragma unroll
        for (int j = 0; j < 8; ++j){
            int c = g*8 + j;
            xf[j] = (vv[j] - mean) * rstd * ln1_g[c] + ln1_b[c];
        }
        uint4 u;
        u.x = pk2(xf[0], xf[1]); u.y = pk2(xf[2], xf[3]);
        u.z = pk2(xf[4], xf[5]); u.w = pk2(xf[6], xf[7]);
        *(uint4*)TBA(T0B, bb, g*8) = u;
        *(float4*)XFA(bb, g*8)     = (float4){xf[0], xf[1], xf[2], xf[3]};
        *(float4*)XFA(bb, g*8 + 4) = (float4){xf[4], xf[5], xf[6], xf[7]};
    }
    __syncthreads();

    {
        uint4 aS[2][2];
        #pragma unroll
        for (int S = 0; S < 2; ++S){
            aS[S][0] = *(const uint4*)TBA(T0B, c15,      S*32 + half*8);
            aS[S][1] = *(const uint4*)TBA(T0B, 16 + c15, S*32 + half*8);
        }
        #pragma unroll
        for (int k = 0; k < 4; ++k){
            int nb = k*4 + w;
            int col = nb*16 + c15;
            float bias = b1[col];
            f32x4 ac0 = {bias,bias,bias,bias}, ac1 = ac0;
            #pragma unroll
            for (int S = 0; S < 2; ++S){
                uint4 bfv = packH[H_W1 + (nb*2 + S)*64 + lane];
                ac0 = MFMA(aS[S][0], bfv, ac0); ac1 = MFMA(aS[S][1], bfv, ac1);
            }
            #pragma unroll
            for (int r = 0; r < 4; ++r){
                *(bf16*)TFA(half*4 + r,      col) = __float2bfloat16(fmaxf(ac0[r], 0.f));
                *(bf16*)TFA(16 + half*4 + r, col) = __float2bfloat16(fmaxf(ac1[r], 0.f));
            }
        }
    }
    __syncthreads();

    {
        int col = w*16 + c15;
        float bias = b2[col];
        f32x4 ac0 = {bias,bias,bias,bias}, ac1 = ac0;
        #pragma unroll
        for (int S = 0; S < 8; ++S){
            uint4 bfv = packH[H_W2 + (w*8 + S)*64 + lane];
            uint4 a0 = *(const uint4*)TFA(c15,      S*32 + half*8);
            uint4 a1 = *(const uint4*)TFA(16 + c15, S*32 + half*8);
            ac0 = MFMA(a0, bfv, ac0); ac1 = MFMA(a1, bfv, ac1);
        }
        #pragma unroll
        for (int r = 0; r < 4; ++r){
            *(float*)XFA(half*4 + r,      col) += ac0[r];
            *(float*)XFA(16 + half*4 + r, col) += ac1[r];
        }
    }
    __syncthreads();

    {
        float4 v0 = *(const float4*)XFA(bb, g*8);
        float4 v1 = *(const float4*)XFA(bb, g*8 + 4);
        float vv[8] = {v0.x, v0.y, v0.z, v0.w, v1.x, v1.y, v1.z, v1.w};
        float s = 0.f, s2 = 0.f;
        #pragma unroll
        for (int j = 0; j < 8; ++j){ s += vv[j]; s2 += vv[j]*vv[j]; }
        #pragma unroll
        for (int msk = 1; msk < 8; msk <<= 1){ s += __shfl_xor(s, msk, 8); s2 += __shfl_xor(s2, msk, 8); }
        float mean = s * (1.f/64.f);
        float var  = s2 * (1.f/64.f) - mean*mean;
        float rstd = rsqrtf(var + 1e-5f);
        float xf[8];
        #pragma unroll
        for (int j = 0; j < 8; ++j){
            int c = g*8 + j;
            xf[j] = (vv[j] - mean) * rstd * ln2_g[c] + ln2_b[c];
        }
        uint4 u;
        u.x = pk2(xf[0], xf[1]); u.y = pk2(xf[2], xf[3]);
        u.z = pk2(xf[4], xf[5]); u.w = pk2(xf[6], xf[7]);
        *(uint4*)TBA(T0B, bb, g*8) = u;
    }
    __syncthreads();

    {
        int col = w*16 + c15;
        float bias = relu_b[col];
        f32x4 ac0 = {bias,bias,bias,bias}, ac1 = ac0;
        #pragma unroll
        for (int S = 0; S < 2; ++S){
            uint4 bfv = packH[H_RELU + (w*2 + S)*64 + lane];
            uint4 a0 = *(const uint4*)TBA(T0B, c15,      S*32 + half*8);
            uint4 a1 = *(const uint4*)TBA(T0B, 16 + c15, S*32 + half*8);
            ac0 = MFMA(a0, bfv, ac0); ac1 = MFMA(a1, bfv, ac1);
        }
        #pragma unroll
        for (int r = 0; r < 4; ++r){
            *(bf16*)TBA(XRB, half*4 + r,      col) = __float2bfloat16(ac0[r]);
            *(bf16*)TBA(XRB, 16 + half*4 + r, col) = __float2bfloat16(ac1[r]);
        }
    }
    __syncthreads();

    {
        int col = w*16 + c15;
        float bias = nd_b[col];
        f32x4 ac0 = {bias,bias,bias,bias}, ac1 = ac0;
        #pragma unroll
        for (int S = 0; S < 2; ++S){
            uint4 bfv = packH[H_ND + (w*2 + S)*64 + lane];
            uint4 a0 = *(const uint4*)TBA(XRB, c15,      S*32 + half*8);
            uint4 a1 = *(const uint4*)TBA(XRB, 16 + c15, S*32 + half*8);
            ac0 = MFMA(a0, bfv, ac0); ac1 = MFMA(a1, bfv, ac1);
        }
        #pragma unroll
        for (int r = 0; r < 4; ++r){
            *(bf16*)TBA(T1B, half*4 + r,      col) = __float2bfloat16(ac0[r]);
            *(bf16*)TBA(T1B, 16 + half*4 + r, col) = __float2bfloat16(ac1[r]);
        }
    }
    __syncthreads();

    {
        uint4 u = *(const uint4*)TBA(T1B, bb, g*8);
        float nf[8]; UNPK(u, nf);
        float p = 0.f;
        #pragma unroll
        for (int j = 0; j < 8; ++j) p = fmaf(nf[j], ldt_W[g*8 + j], p);
        #pragma unroll
        for (int msk = 1; msk < 8; msk <<= 1) p += __shfl_xor(p, msk, 8);
        if (g == 0){
            float dT = p + ldt_b[0];
            dTs[bb] = dT;
            out[(size_t)gb * 26] = dT;
        }
    }
    __syncthreads();

    {
        float dT = dTs[bb];
        for (int c8 = g; c8 < 12; c8 += 8){
            int cb = c8 * 8;
            unsigned pr[4];
            #pragma unroll
            for (int pj = 0; pj < 4; ++pj){
                int c0 = cb + 2*pj, c1 = c0 + 1;
                float v0 = (c0 == 0) ? dT :
                           (c0 <= 64 ? __bfloat162float(*(const bf16*)TBA(XRB, bb, c0-1)) : 0.f);
                float v1 = (c1 <= 64 ? __bfloat162float(*(const bf16*)TBA(XRB, bb, c1-1)) : 0.f);
                pr[pj] = pk2(v0, v1);
            }
            *(uint4*)TBA(T0B, bb, cb) = (uint4){pr[0], pr[1], pr[2], pr[3]};
        }
    }
    __syncthreads();

    {
        uint4 aS[3][2];
        #pragma unroll
        for (int S = 0; S < 3; ++S){
            aS[S][0] = *(const uint4*)TBA(T0B, c15,      S*32 + half*8);
            aS[S][1] = *(const uint4*)TBA(T0B, 16 + c15, S*32 + half*8);
        }
        int nbl[2]; int nnb = 1; nbl[0] = w;
        if (w == 0){ nbl[1] = 4; nnb = 2; }
        for (int q = 0; q < nnb; ++q){
            int nb = nbl[q];
            int col = nb*16 + c15;
            float bias = (col < 65) ? nz_b[col] : 0.f;
            f32x4 ac0 = {bias,bias,bias,bias}, ac1 = ac0;
            #pragma unroll
            for (int S = 0; S < 3; ++S){
                uint4 bfv = packH[H_NZ + (nb*3 + S)*64 + lane];
                ac0 = MFMA(aS[S][0], bfv, ac0); ac1 = MFMA(aS[S][1], bfv, ac1);
            }
            #pragma unroll
            for (int r = 0; r < 4; ++r){
                *(bf16*)TBA(T1B, half*4 + r,      col) = __float2bfloat16(ac0[r]);
                *(bf16*)TBA(T1B, 16 + half*4 + r, col) = __float2bfloat16(ac1[r]);
            }
        }
        if (t < 64){
            int row = t >> 1, seg = t & 1;
            *(uint4*)TBA(T1B, row, 80 + seg*8) = (uint4){0u,0u,0u,0u};
        }
    }
    __syncthreads();

    if (w < 2){
        uint4 aS[3][2];
        #pragma unroll
        for (int S = 0; S < 3; ++S){
            aS[S][0] = *(const uint4*)TBA(T1B, c15,      S*32 + half*8);
            aS[S][1] = *(const uint4*)TBA(T1B, 16 + c15, S*32 + half*8);
        }
        int nb = w;
        int col = nb*16 + c15;
        float bias = (col < 20) ? lz_b[col] : 0.f;
        f32x4 ac0 = {bias,bias,bias,bias}, ac1 = ac0;
        #pragma unroll
        for (int S = 0; S < 3; ++S){
            uint4 bfv = packH[H_LZ + (nb*3 + S)*64 + lane];
            ac0 = MFMA(aS[S][0], bfv, ac0); ac1 = MFMA(aS[S][1], bfv, ac1);
        }
        #pragma unroll
        for (int r = 0; r < 4; ++r){
            int r0 = half*4 + r, r1 = 16 + half*4 + r;
            *(bf16*)TBA(TQB, r0, col) = __float2bfloat16(ac0[r]);
            *(bf16*)TBA(TQB, r1, col) = __float2bfloat16(ac1[r]);
            if (col < 20){
                out[(size_t)(B0 + r0) * 26 + 1 + col] = ac0[r];
                out[(size_t)(B0 + r1) * 26 + 1 + col] = ac1[r];
            }
        }
    }
    __syncthreads();

    {
        float dT = dTs[bb];
        for (int c8 = g; c8 < 12; c8 += 8){
            int cb = c8 * 8;
            unsigned pr[4];
            #pragma unroll
            for (int pj = 0; pj < 4; ++pj){
                float vv[2];
                #pragma unroll
                for (int hh = 0; hh < 2; ++hh){
                    int c = cb + 2*pj + hh;
                    float v;
                    if (c < 20)       v = __bfloat162float(*(const bf16*)TBA(TQB, bb, c));
                    else if (c == 20) v = dT;
                    else if (c < 85)  v = __bfloat162float(*(const bf16*)TBA(XRB, bb, c - 21));
                    else              v = 0.f;
                    vv[hh] = v;
                }
                pr[pj] = pk2(vv[0], vv[1]);
            }
            *(uint4*)TBA(T0B, bb, cb) = (uint4){pr[0], pr[1], pr[2], pr[3]};
        }
    }
    __syncthreads();

    {
        uint4 aS[3][2];
        #pragma unroll
        for (int S = 0; S < 3; ++S){
            aS[S][0] = *(const uint4*)TBA(T0B, c15,      S*32 + half*8);
            aS[S][1] = *(const uint4*)TBA(T0B, 16 + c15, S*32 + half*8);
        }
        int nbl[2]; int nnb = 1; nbl[0] = w;
        if (w < 2){ nbl[1] = 4 + w; nnb = 2; }
        for (int q = 0; q < nnb; ++q){
            int nb = nbl[q];
            int col = nb*16 + c15;
            float bias = (col < 85) ? na0_b[col] : 0.f;
            f32x4 ac0 = {bias,bias,bias,bias}, ac1 = ac0;
            #pragma unroll
            for (int S = 0; S < 3; ++S){
                uint4 bfv = packH[H_NA0 + (nb*3 + S)*64 + lane];
                ac0 = MFMA(aS[S][0], bfv, ac0); ac1 = MFMA(aS[S][1], bfv, ac1);
            }
            #pragma unroll
            for (int r = 0; r < 4; ++r){
                *(bf16*)TBA(T1B, half*4 + r,      col) = __float2bfloat16(ac0[r]);
                *(bf16*)TBA(T1B, 16 + half*4 + r, col) = __float2bfloat16(ac1[r]);
            }
        }
    }
    __syncthreads();

    {
        uint4 aS[3][2];
        #pragma unroll
        for (int S = 0; S < 3; ++S){
            aS[S][0] = *(const uint4*)TBA(T1B, c15,      S*32 + half*8);
            aS[S][1] = *(const uint4*)TBA(T1B, 16 + c15, S*32 + half*8);
        }
        int nbl[2]; int nnb = 1; nbl[0] = w;
        if (w < 2){ nbl[1] = 4 + w; nnb = 2; }
        for (int q = 0; q < nnb; ++q){
            int nb = nbl[q];
            int col = nb*16 + c15;
            float bias = (col < 85) ? na1_b[col] : 0.f;
            f32x4 ac0 = {bias,bias,bias,bias}, ac1 = ac0;
            #pragma unroll
            for (int S = 0; S < 3; ++S){
                uint4 bfv = packH[H_NA1 + (nb*3 + S)*64 + lane];
                ac0 = MFMA(aS[S][0], bfv, ac0); ac1 = MFMA(aS[S][1], bfv, ac1);
            }
            #pragma unroll
            for (int r = 0; r < 4; ++r){
                *(bf16*)TBA(T0B, half*4 + r,      col) = __float2bfloat16(ac0[r]);
                *(bf16*)TBA(T0B, 16 + half*4 + r, col) = __float2bfloat16(ac1[r]);
            }
        }
    }
    __syncthreads();

    if (w == 0){
        int col = c15;
        float bias = (col < 5) ? la_b[col] : 0.f;
        f32x4 ac0 = {bias,bias,bias,bias}, ac1 = ac0;
        #pragma unroll
        for (int S = 0; S < 3; ++S){
            uint4 bfv = packH[H_LA + S*64 + lane];
            uint4 a0 = *(const uint4*)TBA(T0B, c15,      S*32 + half*8);
            uint4 a1 = *(const uint4*)TBA(T0B, 16 + c15, S*32 + half*8);
            ac0 = MFMA(a0, bfv, ac0); ac1 = MFMA(a1, bfv, ac1);
        }
        if (col < 5){
            #pragma unroll
            for (int r = 0; r < 4; ++r){
                out[(size_t)(B0 + half*4 + r) * 26 + 21 + col]      = ac0[r];
                out[(size_t)(B0 + 16 + half*4 + r) * 26 + 21 + col] = ac1[r];
            }
        }
    }
}

extern "C" void kernel_launch(void* const* d_in, const int* in_sizes, int n_in,
                              void* d_out, int out_size, void* d_ws, size_t ws_size,
                              hipStream_t stream)
{
    const float* X        = (const float*)d_in[0];
    const float* emb_act  = (const float*)d_in[1];
    const float* emb_zone = (const float*)d_in[2];
    const float* lin0_W   = (const float*)d_in[3];
    const float* lin0_b   = (const float*)d_in[4];
    const float* gat_W    = (const float*)d_in[5];
    const float* gat_b    = (const float*)d_in[6];
    const float* gat_a    = (const float*)d_in[7];
    const float* gl0_W    = (const float*)d_in[8];
    const float* gl0_b    = (const float*)d_in[9];
    const float* gl1_W    = (const float*)d_in[10];
    const float* gl1_b    = (const float*)d_in[11];
    const float* gl2_W    = (const float*)d_in[12];
    const float* gl2_b    = (const float*)d_in[13];
    const float* Wqkv     = (const float*)d_in[14];
    const float* bqkv     = (const float*)d_in[15];
    const float* Wo       = (const float*)d_in[16];
    const float* bo       = (const float*)d_in[17];
    const float* ln1_g    = (const float*)d_in[18];
    const float* ln1_b    = (const float*)d_in[19];
    const float* W1       = (const float*)d_in[20];
    const float* b1       = (const float*)d_in[21];
    const float* W2       = (const float*)d_in[22];
    const float* b2       = (const float*)d_in[23];
    const float* ln2_g    = (const float*)d_in[24];
    const float* ln2_b    = (const float*)d_in[25];
    const float* relu_W   = (const float*)d_in[26];
    const float* relu_b   = (const float*)d_in[27];
    const float* nd_W     = (const float*)d_in[28];
    const float* nd_b     = (const float*)d_in[29];
    const float* ldt_W    = (const float*)d_in[30];
    const float* ldt_b    = (const float*)d_in[31];
    const float* nz_W     = (const float*)d_in[32];
    const float* nz_b     = (const float*)d_in[33];
    const float* lz_W     = (const float*)d_in[34];
    const float* lz_b     = (const float*)d_in[35];
    const float* na0_W    = (const float*)d_in[36];
    const float* na0_b    = (const float*)d_in[37];
    const float* na1_W    = (const float*)d_in[38];
    const float* na1_b    = (const float*)d_in[39];
    const float* la_W     = (const float*)d_in[40];
    const float* la_b     = (const float*)d_in[41];

    char* wsb = (char*)d_ws;
    bf16*  kv       = (bf16*)wsb;
    float* src_last = (float*)(wsb + (size_t)NTOK * 128 * sizeof(bf16));
    uint4* packW    = (uint4*)(wsb + (size_t)NTOK * 128 * sizeof(bf16) + (size_t)B_ * 64 * sizeof(float));
    uint4* packH    = packW + PK_TOT;

    k_pack_all<<<(PK_TOT + H_TOT + 255)/256, 256, 0, stream>>>(
        gl0_W, gl1_W, gl2_W, Wqkv, Wo, W1, W2, relu_W, nd_W, nz_W, lz_W,
        na0_W, na1_W, la_W, packW, packH);

    k_token<<<NTOK/TOKB, TPB, 0, stream>>>(X, emb_act, emb_zone, lin0_W, lin0_b,
        gat_W, gat_b, gat_a, gl0_b, gl1_b, gl2_b, bqkv, packW, kv, src_last);

    k_head2<<<B_/32, 256, 0, stream>>>(kv, src_last, packH, bqkv, bo,
        ln1_g, ln1_b, b1, b2, ln2_g, ln2_b, relu_b, nd_b, ldt_W, ldt_b,
        nz_b, lz_b, na0_b, na1_b, la_b, (float*)d_out);
}

// Round 10
// 71.133 us; speedup vs baseline: 2.5908x; 1.0464x over previous
//
#include <hip/hip_runtime.h>
#include <hip/hip_bf16.h>

typedef __hip_bfloat16 bf16;
typedef float f32x4 __attribute__((ext_vector_type(4)));
typedef short s16x8 __attribute__((ext_vector_type(8)));

#define B_    2048
#define S_    40
#define NTOK  (B_*S_)
#define TPB   256
#define TOKB  64

// ---- k_token LDS layout (dwords). A1 aliases FF (FF dead after phase 1).
#define FF_OFF    0
#define A1_OFFD   0
#define A0_OFFD   3520
#define PE_OFFD   7616
#define IA_OFFD   7680
#define HD_OFFD   7744
#define LDS_DW    8128     // 32512 B

#define A0B (A0_OFFD*4)
#define A1B (A1_OFFD*4)

// ---- packW (token) fragment offsets (uint4 units)
#define PK_GL0 0
#define PK_GL1 1024
#define PK_GL2 1536
#define PK_KV  1664
#define PK_TOT 2688

// ---- packH (head) fragment offsets (uint4 units)
#define H_WQ   0
#define H_WO   512
#define H_W1   1024
#define H_W2   3072
#define H_RELU 5120
#define H_ND   5632
#define H_NZ   6144
#define H_LZ   7104
#define H_NA0  7488
#define H_NA1  8640
#define H_LA   9792
#define H_TOT  9984

__device__ inline unsigned pk2(float a, float b){
    __hip_bfloat16 ha = __float2bfloat16(a), hb = __float2bfloat16(b);
    unsigned short ua = *reinterpret_cast<unsigned short*>(&ha);
    unsigned short ub = *reinterpret_cast<unsigned short*>(&hb);
    return (unsigned)ua | ((unsigned)ub << 16);
}
__device__ inline float blo(unsigned u){ return __uint_as_float(u << 16); }
__device__ inline float bhi(unsigned u){ return __uint_as_float(u & 0xffff0000u); }

__device__ inline float fexp2(float x){
#if __has_builtin(__builtin_amdgcn_exp2f)
    return __builtin_amdgcn_exp2f(x);
#else
    return exp2f(x);
#endif
}

__device__ inline f32x4 MFMA(uint4 a, uint4 b, f32x4 c){
    union { uint4 q; s16x8 s; } A, Bv;
    A.q = a; Bv.q = b;
    return __builtin_amdgcn_mfma_f32_16x16x32_bf16(A.s, Bv.s, c, 0, 0, 0);
}

// load ff row j (5 bf16 at bf16-index 5j) from contiguous packing
__device__ inline void ldff(const unsigned* L, unsigned tb, int j, float f[5]){
    int k = (5*j) >> 1;
    unsigned u0 = L[tb + k], u1 = L[tb + k + 1], u2 = L[tb + k + 2];
    if ((j & 1) == 0){
        f[0]=blo(u0); f[1]=bhi(u0); f[2]=blo(u1); f[3]=bhi(u1); f[4]=blo(u2);
    } else {
        f[0]=bhi(u0); f[1]=blo(u1); f[2]=bhi(u1); f[3]=blo(u2); f[4]=bhi(u2);
    }
}

__device__ inline uint4 packB(const float* W, int ld, int K, int N, int nb, int S, int lane){
    int half = lane >> 4, c15 = lane & 15;
    int col = nb*16 + c15;
    unsigned pr[4];
    #pragma unroll
    for (int jj = 0; jj < 4; ++jj){
        int k0 = S*32 + half*8 + 2*jj;
        float v0 = (k0   < K && col < N) ? W[(size_t)k0*ld + col]     : 0.f;
        float v1 = (k0+1 < K && col < N) ? W[(size_t)(k0+1)*ld + col] : 0.f;
        pr[jj] = pk2(v0, v1);
    }
    return (uint4){pr[0], pr[1], pr[2], pr[3]};
}

// ---------------- Kernel 0: pre-pack ALL weight fragments ----------------
__global__ __launch_bounds__(256) void k_pack_all(
    const float* __restrict__ gl0_W, const float* __restrict__ gl1_W,
    const float* __restrict__ gl2_W, const float* __restrict__ Wqkv,
    const float* __restrict__ Wo,    const float* __restrict__ W1,
    const float* __restrict__ W2,    const float* __restrict__ relu_W,
    const float* __restrict__ nd_W,  const float* __restrict__ nz_W,
    const float* __restrict__ lz_W,  const float* __restrict__ na0_W,
    const float* __restrict__ na1_W, const float* __restrict__ la_W,
    uint4* __restrict__ packW, uint4* __restrict__ packH)
{
    int f = blockIdx.x * 256 + threadIdx.x;
    if (f < PK_TOT){
        unsigned pr[4];
        if (f < PK_GL1){
            int w = f >> 8, r = f & 255, S = r >> 6, lane = r & 63;
            int half = lane >> 4, c15 = lane & 15, col = w * 16 + c15;
            #pragma unroll
            for (int jj = 0; jj < 4; ++jj){
                int k0 = S*32 + half*8 + 2*jj;
                float v0 = (k0   < 110) ? gl0_W[k0*64 + col]     : 0.f;
                float v1 = (k0+1 < 110) ? gl0_W[(k0+1)*64 + col] : 0.f;
                pr[jj] = pk2(v0, v1);
            }
        } else if (f < PK_GL2){
            int g = f - PK_GL1, w = g >> 7, r = g & 127, S = r >> 6, lane = r & 63;
            int half = lane >> 4, c15 = lane & 15, col = w * 16 + c15;
            #pragma unroll
            for (int jj = 0; jj < 4; ++jj){
                int k0 = S*32 + half*8 + 2*jj;
                pr[jj] = pk2(gl1_W[k0*64 + col], gl1_W[(k0+1)*64 + col]);
            }
        } else if (f < PK_KV){
            int g = f - PK_GL2, S = g >> 6, lane = g & 63;
            int half = lane >> 4, c15 = lane & 15;
            #pragma unroll
            for (int jj = 0; jj < 4; ++jj){
                int k0 = S*32 + half*8 + 2*jj;
                pr[jj] = pk2(gl2_W[k0*16 + c15], gl2_W[(k0+1)*16 + c15]);
            }
        } else {
            int g = f - PK_KV, w = g >> 8, r = g & 255, cf = r >> 7, r2 = r & 127;
            int S = r2 >> 6, lane = r2 & 63;
            int half = lane >> 4, c15 = lane & 15, col = 64 + w*32 + cf*16 + c15;
            #pragma unroll
            for (int jj = 0; jj < 4; ++jj){
                int k0 = S*32 + half*8 + 2*jj;
                pr[jj] = pk2(Wqkv[k0*192 + col], Wqkv[(k0+1)*192 + col]);
            }
        }
        packW[f] = (uint4){pr[0], pr[1], pr[2], pr[3]};
        return;
    }
    int f2 = f - PK_TOT;
    if (f2 >= H_TOT) return;
    const float* W; int ld, K, N, St, base;
    if      (f2 < H_WO ){ W=Wqkv;   ld=192; K=64;  N=64;  St=2; base=H_WQ;  }
    else if (f2 < H_W1 ){ W=Wo;     ld=64;  K=64;  N=64;  St=2; base=H_WO;  }
    else if (f2 < H_W2 ){ W=W1;     ld=256; K=64;  N=256; St=2; base=H_W1;  }
    else if (f2 < H_RELU){W=W2;     ld=64;  K=256; N=64;  St=8; base=H_W2;  }
    else if (f2 < H_ND ){ W=relu_W; ld=64;  K=64;  N=64;  St=2; base=H_RELU;}
    else if (f2 < H_NZ ){ W=nd_W;   ld=64;  K=64;  N=64;  St=2; base=H_ND;  }
    else if (f2 < H_LZ ){ W=nz_W;   ld=65;  K=65;  N=65;  St=3; base=H_NZ;  }
    else if (f2 < H_NA0){ W=lz_W;   ld=20;  K=65;  N=20;  St=3; base=H_LZ;  }
    else if (f2 < H_NA1){ W=na0_W;  ld=85;  K=85;  N=85;  St=3; base=H_NA0; }
    else if (f2 < H_LA ){ W=na1_W;  ld=85;  K=85;  N=85;  St=3; base=H_NA1; }
    else               { W=la_W;   ld=5;   K=85;  N=5;   St=3; base=H_LA;  }
    int loc = f2 - base;
    int nb = loc / (St*64);
    int rem = loc - nb*St*64;
    packH[f2] = packB(W, ld, K, N, nb, rem >> 6, rem & 63);
}

// ---------------- Kernel 1: MFMA featurizer (unchanged from R9) ----------------
__global__ __launch_bounds__(TPB) void k_token(
    const float* __restrict__ X,
    const float* __restrict__ emb_act,
    const float* __restrict__ emb_zone,
    const float* __restrict__ lin0_W, const float* __restrict__ lin0_b,
    const float* __restrict__ gat_W,  const float* __restrict__ gat_b,
    const float* __restrict__ gat_a,
    const float* __restrict__ gl0_b,  const float* __restrict__ gl1_b,
    const float* __restrict__ gl2_b,  const float* __restrict__ bqkv,
    const uint4* __restrict__ packW,
    bf16* __restrict__ kv, float* __restrict__ src_last)
{
    __shared__ unsigned L[LDS_DW];
    char* Lb = (char*)L;

    const int t    = threadIdx.x;
    const int w    = t >> 6;
    const int lane = t & 63;
    const int half = (lane >> 4);
    const int c15  = lane & 15;
    const int blk0 = blockIdx.x * TOKB;
    const int swzc = (c15 & 7) << 4;

    for (int task = t; task < TOKB * 11; task += TPB){
        int tt = task / 11;
        int p  = task - tt * 11;
        const float2* xp = (const float2*)(X + (size_t)(blk0 + tt) * 118 + 8 + 10 * p);
        float2 a0 = xp[0], a1 = xp[1], a2 = xp[2], a3 = xp[3], a4 = xp[4];
        unsigned* dst = &L[FF_OFF + tt * 55 + 5 * p];
        dst[0] = pk2(a0.x, a0.y);
        dst[1] = pk2(a1.x, a1.y);
        dst[2] = pk2(a2.x, a2.y);
        dst[3] = pk2(a3.x, a3.y);
        dst[4] = pk2(a4.x, a4.y);
    }
    for (int idx = t; idx < 64 * 9; idx += TPB){
        int row = idx / 9, p = idx - row * 9;
        *(unsigned*)(Lb + A0B + row * 256 + ((220 + 4*p) ^ ((row & 7) << 4))) = 0u;
    }
    if (t < TOKB){
        int tok = blk0 + t;
        const float2* xp = (const float2*)(X + (size_t)tok * 118);
        float2 v0 = xp[0], v1 = xp[1], v2 = xp[2], v3 = xp[3];
        int b = tok / 40, s = tok - b * 40;
        float expo = (2.0f * (float)s) / 40.0f;
        float inv100 = fexp2(-expo * 6.6438561897747395f);
        float ang = (float)b * inv100;
        float pe = ((s & 1) == 0) ? __sinf(ang) : __cosf(ang);
        ((float*)&L[PE_OFFD])[t] = pe;
        L[IA_OFFD + t] = (((unsigned)(int)v0.x) << 16) | ((unsigned)(int)v0.y & 0xffffu);
        float* hdL = (float*)&L[HD_OFFD + t * 6];
        hdL[0] = v1.x; hdL[1] = v1.y; hdL[2] = v2.x;
        hdL[3] = v2.y; hdL[4] = v3.x; hdL[5] = v3.y;
    }
    __syncthreads();

    {
        const float LOG2E = 1.4426950408889634f;
        const unsigned tb = FF_OFF + lane * 55;
        float va1[5], va2[5];
        float cc1 = 0.f, cc2 = 0.f;
        #pragma unroll
        for (int e = 0; e < 5; ++e){
            float u1 = 0.f, u2 = 0.f;
            #pragma unroll
            for (int d = 0; d < 5; ++d){
                u1 += gat_W[e*5+d] * gat_a[d];
                u2 += gat_W[e*5+d] * gat_a[5+d];
            }
            va1[e] = u1 * LOG2E; va2[e] = u2 * LOG2E;
        }
        #pragma unroll
        for (int d = 0; d < 5; ++d){ cc1 += gat_b[d]*gat_a[d]; cc2 += gat_b[d]*gat_a[5+d]; }
        cc1 *= LOG2E; cc2 *= LOG2E;

        float m2 = -1e30f;
        #pragma unroll
        for (int j = 0; j < 22; ++j){
            float f[5]; ldff(L, tb, j, f);
            float s2j = cc2 + f[0]*va2[0] + f[1]*va2[1] + f[2]*va2[2] + f[3]*va2[3] + f[4]*va2[4];
            m2 = fmaxf(m2, s2j);
        }

        const int wbase = w * 6;
        float s1own[6], negmi[6], Z[6], ffp[6][5];
        #pragma unroll
        for (int ii = 0; ii < 6; ++ii){
            int i = wbase + ii; if (i > 21) i = 21;
            float f[5]; ldff(L, tb, i, f);
            float s1 = cc1 + f[0]*va1[0] + f[1]*va1[1] + f[2]*va1[2] + f[3]*va1[3] + f[4]*va1[4];
            s1own[ii] = s1;
            float em = s1 + m2;
            negmi[ii] = -fmaxf(em, 0.2f * em);
            Z[ii] = 0.f;
            #pragma unroll
            for (int e = 0; e < 5; ++e) ffp[ii][e] = 0.f;
        }

        #pragma unroll
        for (int j = 0; j < 22; ++j){
            float f[5]; ldff(L, tb, j, f);
            float s2j = cc2 + f[0]*va2[0] + f[1]*va2[1] + f[2]*va2[2] + f[3]*va2[3] + f[4]*va2[4];
            #pragma unroll
            for (int ii = 0; ii < 6; ++ii){
                float e2 = s1own[ii] + s2j;
                float a  = e2 + negmi[ii];
                float bq = fmaf(0.2f, e2, negmi[ii]);
                float wg = fexp2(fmaxf(a, bq));
                Z[ii] += wg;
                ffp[ii][0] = fmaf(wg, f[0], ffp[ii][0]);
                ffp[ii][1] = fmaf(wg, f[1], ffp[ii][1]);
                ffp[ii][2] = fmaf(wg, f[2], ffp[ii][2]);
                ffp[ii][3] = fmaf(wg, f[3], ffp[ii][3]);
                ffp[ii][4] = fmaf(wg, f[4], ffp[ii][4]);
            }
        }

        const int rswz = (lane & 7) << 4;
        #pragma unroll
        for (int ii = 0; ii < 6; ++ii){
            int i = wbase + ii;
            if (i < 22){
                float rz = 1.f / Z[ii];
                #pragma unroll
                for (int d = 0; d < 5; ++d){
                    float u = 0.f;
                    #pragma unroll
                    for (int e = 0; e < 5; ++e) u += ffp[ii][e] * gat_W[e*5+d];
                    float h = u * rz + gat_b[d];
                    *(bf16*)(Lb + A0B + lane*256 + ((10*i + 2*d) ^ rswz)) = __float2bfloat16(h);
                }
            }
        }
    }
    __syncthreads();

    {
        uint4 bfr[4];
        #pragma unroll
        for (int S = 0; S < 4; ++S) bfr[S] = packW[PK_GL0 + (w*4 + S)*64 + lane];
        const int col = w * 16 + c15;
        float bias = gl0_b[col];
        f32x4 ac0 = {bias,bias,bias,bias}, ac1 = ac0, ac2 = ac0, ac3 = ac0;
        #pragma unroll
        for (int S = 0; S < 4; ++S){
            int koff = S*64 + half*16;
            uint4 a0 = *(const uint4*)(Lb + A0B + (0*16 + c15)*256 + (koff ^ swzc));
            uint4 a1 = *(const uint4*)(Lb + A0B + (1*16 + c15)*256 + (koff ^ swzc));
            uint4 a2 = *(const uint4*)(Lb + A0B + (2*16 + c15)*256 + (koff ^ swzc));
            uint4 a3 = *(const uint4*)(Lb + A0B + (3*16 + c15)*256 + (koff ^ swzc));
            ac0 = MFMA(a0, bfr[S], ac0);
            ac1 = MFMA(a1, bfr[S], ac1);
            ac2 = MFMA(a2, bfr[S], ac2);
            ac3 = MFMA(a3, bfr[S], ac3);
        }
        const int off = col * 2;
        #pragma unroll
        for (int r = 0; r < 4; ++r){
            int row0 = 0*16 + half*4 + r;
            int row1 = 1*16 + half*4 + r;
            int row2 = 2*16 + half*4 + r;
            int row3 = 3*16 + half*4 + r;
            *(bf16*)(Lb + A1B + row0*128 + (off ^ ((row0 & 7) << 4))) = __float2bfloat16(fmaxf(ac0[r], 0.f));
            *(bf16*)(Lb + A1B + row1*128 + (off ^ ((row1 & 7) << 4))) = __float2bfloat16(fmaxf(ac1[r], 0.f));
            *(bf16*)(Lb + A1B + row2*128 + (off ^ ((row2 & 7) << 4))) = __float2bfloat16(fmaxf(ac2[r], 0.f));
            *(bf16*)(Lb + A1B + row3*128 + (off ^ ((row3 & 7) << 4))) = __float2bfloat16(fmaxf(ac3[r], 0.f));
        }
    }
    __syncthreads();

    {
        uint4 bfr[2];
        #pragma unroll
        for (int S = 0; S < 2; ++S) bfr[S] = packW[PK_GL1 + (w*2 + S)*64 + lane];
        const int col = w * 16 + c15;
        float bias = gl1_b[col];
        f32x4 ac0 = {bias,bias,bias,bias}, ac1 = ac0, ac2 = ac0, ac3 = ac0;
        #pragma unroll
        for (int S = 0; S < 2; ++S){
            int koff = S*64 + half*16;
            uint4 a0 = *(const uint4*)(Lb + A1B + (0*16 + c15)*128 + (koff ^ swzc));
            uint4 a1 = *(const uint4*)(Lb + A1B + (1*16 + c15)*128 + (koff ^ swzc));
            uint4 a2 = *(const uint4*)(Lb + A1B + (2*16 + c15)*128 + (koff ^ swzc));
            uint4 a3 = *(const uint4*)(Lb + A1B + (3*16 + c15)*128 + (koff ^ swzc));
            ac0 = MFMA(a0, bfr[S], ac0);
            ac1 = MFMA(a1, bfr[S], ac1);
            ac2 = MFMA(a2, bfr[S], ac2);
            ac3 = MFMA(a3, bfr[S], ac3);
        }
        const int off = col * 2;
        #pragma unroll
        for (int r = 0; r < 4; ++r){
            int row0 = 0*16 + half*4 + r;
            int row1 = 1*16 + half*4 + r;
            int row2 = 2*16 + half*4 + r;
            int row3 = 3*16 + half*4 + r;
            *(bf16*)(Lb + A0B + row0*128 + (off ^ ((row0 & 7) << 4))) = __float2bfloat16(fmaxf(ac0[r], 0.f));
            *(bf16*)(Lb + A0B + row1*128 + (off ^ ((row1 & 7) << 4))) = __float2bfloat16(fmaxf(ac1[r], 0.f));
            *(bf16*)(Lb + A0B + row2*128 + (off ^ ((row2 & 7) << 4))) = __float2bfloat16(fmaxf(ac2[r], 0.f));
            *(bf16*)(Lb + A0B + row3*128 + (off ^ ((row3 & 7) << 4))) = __float2bfloat16(fmaxf(ac3[r], 0.f));
        }
    }
    __syncthreads();

    {
        uint4 bfr[2];
        #pragma unroll
        for (int S = 0; S < 2; ++S) bfr[S] = packW[PK_GL2 + S*64 + lane];
        float bias = gl2_b[c15];
        f32x4 ac = {bias,bias,bias,bias};
        #pragma unroll
        for (int S = 0; S < 2; ++S){
            int koff = S*64 + half*16;
            uint4 a = *(const uint4*)(Lb + A0B + (w*16 + c15)*128 + (koff ^ swzc));
            ac = MFMA(a, bfr[S], ac);
        }
        const float* pef = (const float*)&L[PE_OFFD];
        const int off = (48 + c15) * 2;
        #pragma unroll
        for (int r = 0; r < 4; ++r){
            int row = w*16 + half*4 + r;
            float v = fmaxf(ac[r], 0.f) + pef[row];
            *(bf16*)(Lb + A1B + row*128 + (off ^ ((row & 7) << 4))) = __float2bfloat16(v);
        }

        float pe = pef[lane];
        unsigned iaz = L[IA_OFFD + lane];
        int ia = (int)(iaz >> 16), iz = (int)(iaz & 0xffffu);
        const float* hdL = (const float*)&L[HD_OFFD + lane * 6];
        const int tswz = (lane & 7) << 4;
        #pragma unroll
        for (int pp = 0; pp < 6; ++pp){
            int p = w * 6 + pp;
            int c0 = 2 * p;
            float v0, v1;
            if (p < 8)        { v0 = emb_act[ia*16 + c0];        v1 = emb_act[ia*16 + c0 + 1]; }
            else if (p < 16)  { v0 = emb_zone[iz*16 + c0 - 16];  v1 = emb_zone[iz*16 + c0 - 15]; }
            else {
                int cc = c0 - 32;
                float o0 = lin0_b[cc], o1 = lin0_b[cc+1];
                #pragma unroll
                for (int e = 0; e < 6; ++e){
                    float f = hdL[e];
                    o0 = fmaf(f, lin0_W[e*16 + cc], o0);
                    o1 = fmaf(f, lin0_W[e*16 + cc + 1], o1);
                }
                v0 = o0; v1 = o1;
            }
            *(unsigned*)(Lb + A1B + lane*128 + ((4*p) ^ tswz)) = pk2(v0 + pe, v1 + pe);
        }
    }
    __syncthreads();

    {
        int r0 = 39 - (blk0 % 40);
        if (t < 128){
            int tok = r0 + 40 * (t >> 6);
            if (tok < 64){
                int col = t & 63;
                bf16 hv = *(const bf16*)(Lb + A1B + tok*128 + ((col*2) ^ ((tok & 7) << 4)));
                src_last[(size_t)((blk0 + tok) / 40) * 64 + col] = __bfloat162float(hv);
            }
        }

        uint4 bfk[2][2];
        #pragma unroll
        for (int cf = 0; cf < 2; ++cf)
            #pragma unroll
            for (int S = 0; S < 2; ++S)
                bfk[cf][S] = packW[PK_KV + ((w*2 + cf)*2 + S)*64 + lane];

        float b0v = bqkv[64 + w*32 + c15];
        float b1v = bqkv[64 + w*32 + 16 + c15];
        f32x4 acc[4][2];
        #pragma unroll
        for (int R = 0; R < 4; ++R){
            acc[R][0] = (f32x4){b0v, b0v, b0v, b0v};
            acc[R][1] = (f32x4){b1v, b1v, b1v, b1v};
        }
        #pragma unroll
        for (int S = 0; S < 2; ++S){
            int koff = S*64 + half*16;
            #pragma unroll
            for (int R = 0; R < 4; ++R){
                uint4 a = *(const uint4*)(Lb + A1B + (R*16 + c15)*128 + (koff ^ swzc));
                acc[R][0] = MFMA(a, bfk[0][S], acc[R][0]);
                acc[R][1] = MFMA(a, bfk[1][S], acc[R][1]);
            }
        }
        #pragma unroll
        for (int R = 0; R < 4; ++R){
            #pragma unroll
            for (int cf = 0; cf < 2; ++cf){
                int lcol = w*32 + cf*16 + c15;
                int off = lcol * 2;
                #pragma unroll
                for (int r = 0; r < 4; ++r){
                    int row = R*16 + half*4 + r;
                    *(bf16*)(Lb + A0B + row*256 + (off ^ ((row & 7) << 4))) = __float2bfloat16(acc[R][cf][r]);
                }
            }
        }
    }
    __syncthreads();

    {
        int row = t >> 2;
        int q = t & 3;
        #pragma unroll
        for (int c = 0; c < 4; ++c){
            int chunk = q*4 + c;
            uint4 d = *(const uint4*)(Lb + A0B + row*256 + ((chunk*16) ^ ((row & 7) << 4)));
            *((uint4*)(kv + (size_t)(blk0 + row) * 128 + chunk * 8)) = d;
        }
    }
}

// ---------------- Kernel 2: MFMA head (16 batches/block, 128 blocks) ----------------
#define T0B 0
#define T1B 4096
#define TQB 8192
#define XRB 12288
#define XFB 16384
#define TFB 20480
#define DTS 28672

#define TBA(base, row, col) (Lb + (base) + (row)*256 + ((((col)*2)) ^ (((row)&7)<<4)))
#define TFA(row, col)       (Lb + TFB   + (row)*512 + ((((col)*2)) ^ (((row)&7)<<4)))
#define XFA(row, col)       (Lb + XFB   + (row)*256 + ((((col)*4)) ^ (((row)&7)<<4)))

#define UNPK(u, arr) { arr[0]=blo(u.x); arr[1]=bhi(u.x); arr[2]=blo(u.y); arr[3]=bhi(u.y); \
                       arr[4]=blo(u.z); arr[5]=bhi(u.z); arr[6]=blo(u.w); arr[7]=bhi(u.w); }

__global__ __launch_bounds__(256) void k_head2(
    const bf16* __restrict__ kv, const float* __restrict__ src_last,
    const uint4* __restrict__ packH,
    const float* __restrict__ bqkv,  const float* __restrict__ bo,
    const float* __restrict__ ln1_g, const float* __restrict__ ln1_b,
    const float* __restrict__ b1,    const float* __restrict__ b2,
    const float* __restrict__ ln2_g, const float* __restrict__ ln2_b,
    const float* __restrict__ relu_b, const float* __restrict__ nd_b,
    const float* __restrict__ ldt_W, const float* __restrict__ ldt_b,
    const float* __restrict__ nz_b,  const float* __restrict__ lz_b,
    const float* __restrict__ na0_b, const float* __restrict__ na1_b,
    const float* __restrict__ la_b,
    float* __restrict__ out)
{
    __shared__ uint4 Lsh[1796];   // 28736 B
    char* Lb = (char*)Lsh;
    float* dTs = (float*)(Lb + DTS);

    const int t    = threadIdx.x;
    const int w    = t >> 6;
    const int lane = t & 63;
    const int half = lane >> 4;
    const int c15  = lane & 15;
    const int B0   = blockIdx.x * 16;
    const int bb   = t >> 4;        // 0..15 (row-parallel phases)
    const int g    = t & 15;
    const int gb   = B0 + bb;

    // ---- P0: load src rows -> XF (f32) + T0 (bf16); 4 cols/thread
    {
        float4 v = *(const float4*)(src_last + (size_t)gb * 64 + g * 4);
        *(float4*)XFA(bb, g*4) = v;
        uint2 u;
        u.x = pk2(v.x, v.y); u.y = pk2(v.z, v.w);
        *(uint2*)TBA(T0B, bb, g*4) = u;
    }
    __syncthreads();

    // ---- P1: q = (src@Wq + bq)/sqrt8 -> TQ
    {
        int col = w*16 + c15;
        float bias = bqkv[col];
        f32x4 ac0 = {bias,bias,bias,bias};
        #pragma unroll
        for (int S = 0; S < 2; ++S){
            uint4 bfv = packH[H_WQ + (w*2 + S)*64 + lane];
            uint4 a0 = *(const uint4*)TBA(T0B, c15, S*32 + half*8);
            ac0 = MFMA(a0, bfv, ac0);
        }
        #pragma unroll
        for (int r = 0; r < 4; ++r)
            *(bf16*)TBA(TQB, half*4 + r, col) = __float2bfloat16(ac0[r] * 0.35355339059327373f);
    }
    __syncthreads();

    // ---- P2: attention, one (batch, head) pair per thread -> T1
    if (t < 128){
        int pb = t >> 3, h = t & 7;
        int gpb = B0 + pb;
        uint4 qu = *(const uint4*)TBA(TQB, pb, h*8);
        float qh[8]; UNPK(qu, qh);
        const uint4* kp = (const uint4*)(kv + (size_t)gpb * 40 * 128 + h*8);
        const uint4* vp = (const uint4*)(kv + (size_t)gpb * 40 * 128 + 64 + h*8);
        float sc[40];
        float m = -1e30f;
        #pragma unroll 4
        for (int j = 0; j < 40; ++j){
            uint4 ku = kp[j*16];
            float kf[8]; UNPK(ku, kf);
            float a = qh[0]*kf[0] + qh[1]*kf[1] + qh[2]*kf[2] + qh[3]*kf[3]
                    + qh[4]*kf[4] + qh[5]*kf[5] + qh[6]*kf[6] + qh[7]*kf[7];
            sc[j] = a; m = fmaxf(m, a);
        }
        float Z = 0.f;
        float o[8] = {0.f,0.f,0.f,0.f,0.f,0.f,0.f,0.f};
        #pragma unroll 4
        for (int j = 0; j < 40; ++j){
            float wj = __expf(sc[j] - m);
            Z += wj;
            uint4 vu = vp[j*16];
            float vf[8]; UNPK(vu, vf);
            #pragma unroll
            for (int d = 0; d < 8; ++d) o[d] = fmaf(wj, vf[d], o[d]);
        }
        float rz = 1.f / Z;
        uint4 u;
        u.x = pk2(o[0]*rz, o[1]*rz); u.y = pk2(o[2]*rz, o[3]*rz);
        u.z = pk2(o[4]*rz, o[5]*rz); u.w = pk2(o[6]*rz, o[7]*rz);
        *(uint4*)TBA(T1B, pb, h*8) = u;
    }
    __syncthreads();

    // ---- P3: XF += T1@Wo + bo
    {
        int col = w*16 + c15;
        float bias = bo[col];
        f32x4 ac0 = {bias,bias,bias,bias};
        #pragma unroll
        for (int S = 0; S < 2; ++S){
            uint4 bfv = packH[H_WO + (w*2 + S)*64 + lane];
            uint4 a0 = *(const uint4*)TBA(T1B, c15, S*32 + half*8);
            ac0 = MFMA(a0, bfv, ac0);
        }
        #pragma unroll
        for (int r = 0; r < 4; ++r)
            *(float*)XFA(half*4 + r, col) += ac0[r];
    }
    __syncthreads();

    // ---- P4: LN1 -> T0 (bf16) + XF (f32); 4 cols/thread, reduce width 16
    {
        float4 v = *(const float4*)XFA(bb, g*4);
        float vv[4] = {v.x, v.y, v.z, v.w};
        float s = 0.f, s2 = 0.f;
        #pragma unroll
        for (int j = 0; j < 4; ++j){ s += vv[j]; s2 += vv[j]*vv[j]; }
        #pragma unroll
        for (int msk = 1; msk < 16; msk <<= 1){ s += __shfl_xor(s, msk, 16); s2 += __shfl_xor(s2, msk, 16); }
        float mean = s * (1.f/64.f);
        float var  = s2 * (1.f/64.f) - mean*mean;
        float rstd = rsqrtf(var + 1e-5f);
        float xf[4];
        #pragma unroll
        for (int j = 0; j < 4; ++j){
            int c = g*4 + j;
            xf[j] = (vv[j] - mean) * rstd * ln1_g[c] + ln1_b[c];
        }
        uint2 u;
        u.x = pk2(xf[0], xf[1]); u.y = pk2(xf[2], xf[3]);
        *(uint2*)TBA(T0B, bb, g*4) = u;
        *(float4*)XFA(bb, g*4) = (float4){xf[0], xf[1], xf[2], xf[3]};
    }
    __syncthreads();

    // ---- P5: f1 = relu(x1@W1 + b1) -> TF [16][256]
    {
        uint4 aS[2];
        #pragma unroll
        for (int S = 0; S < 2; ++S)
            aS[S] = *(const uint4*)TBA(T0B, c15, S*32 + half*8);
        #pragma unroll
        for (int k = 0; k < 4; ++k){
            int nb = k*4 + w;
            int col = nb*16 + c15;
            float bias = b1[col];
            f32x4 ac0 = {bias,bias,bias,bias};
            #pragma unroll
            for (int S = 0; S < 2; ++S){
                uint4 bfv = packH[H_W1 + (nb*2 + S)*64 + lane];
                ac0 = MFMA(aS[S], bfv, ac0);
            }
            #pragma unroll
            for (int r = 0; r < 4; ++r)
                *(bf16*)TFA(half*4 + r, col) = __float2bfloat16(fmaxf(ac0[r], 0.f));
        }
    }
    __syncthreads();

    // ---- P6: XF += f1@W2 + b2
    {
        int col = w*16 + c15;
        float bias = b2[col];
        f32x4 ac0 = {bias,bias,bias,bias};
        #pragma unroll
        for (int S = 0; S < 8; ++S){
            uint4 bfv = packH[H_W2 + (w*8 + S)*64 + lane];
            uint4 a0 = *(const uint4*)TFA(c15, S*32 + half*8);
            ac0 = MFMA(a0, bfv, ac0);
        }
        #pragma unroll
        for (int r = 0; r < 4; ++r)
            *(float*)XFA(half*4 + r, col) += ac0[r];
    }
    __syncthreads();

    // ---- P7: LN2 -> T0
    {
        float4 v = *(const float4*)XFA(bb, g*4);
        float vv[4] = {v.x, v.y, v.z, v.w};
        float s = 0.f, s2 = 0.f;
        #pragma unroll
        for (int j = 0; j < 4; ++j){ s += vv[j]; s2 += vv[j]*vv[j]; }
        #pragma unroll
        for (int msk = 1; msk < 16; msk <<= 1){ s += __shfl_xor(s, msk, 16); s2 += __shfl_xor(s2, msk, 16); }
        float mean = s * (1.f/64.f);
        float var  = s2 * (1.f/64.f) - mean*mean;
        float rstd = rsqrtf(var + 1e-5f);
        float xf[4];
        #pragma unroll
        for (int j = 0; j < 4; ++j){
            int c = g*4 + j;
            xf[j] = (vv[j] - mean) * rstd * ln2_g[c] + ln2_b[c];
        }
        uint2 u;
        u.x = pk2(xf[0], xf[1]); u.y = pk2(xf[2], xf[3]);
        *(uint2*)TBA(T0B, bb, g*4) = u;
    }
    __syncthreads();

    // ---- P8: xr = x2@relu_W + relu_b -> XR
    {
        int col = w*16 + c15;
        float bias = relu_b[col];
        f32x4 ac0 = {bias,bias,bias,bias};
        #pragma unroll
        for (int S = 0; S < 2; ++S){
            uint4 bfv = packH[H_RELU + (w*2 + S)*64 + lane];
            uint4 a0 = *(const uint4*)TBA(T0B, c15, S*32 + half*8);
            ac0 = MFMA(a0, bfv, ac0);
        }
        #pragma unroll
        for (int r = 0; r < 4; ++r)
            *(bf16*)TBA(XRB, half*4 + r, col) = __float2bfloat16(ac0[r]);
    }
    __syncthreads();

    // ---- P9: nd = xr@nd_W + nd_b -> T1
    {
        int col = w*16 + c15;
        float bias = nd_b[col];
        f32x4 ac0 = {bias,bias,bias,bias};
        #pragma unroll
        for (int S = 0; S < 2; ++S){
            uint4 bfv = packH[H_ND + (w*2 + S)*64 + lane];
            uint4 a0 = *(const uint4*)TBA(XRB, c15, S*32 + half*8);
            ac0 = MFMA(a0, bfv, ac0);
        }
        #pragma unroll
        for (int r = 0; r < 4; ++r)
            *(bf16*)TBA(T1B, half*4 + r, col) = __float2bfloat16(ac0[r]);
    }
    __syncthreads();

    // ---- P10: dT = nd@ldt_W + ldt_b
    {
        uint2 u = *(const uint2*)TBA(T1B, bb, g*4);
        float nf[4] = {blo(u.x), bhi(u.x), blo(u.y), bhi(u.y)};
        float p = 0.f;
        #pragma unroll
        for (int j = 0; j < 4; ++j) p = fmaf(nf[j], ldt_W[g*4 + j], p);
        #pragma unroll
        for (int msk = 1; msk < 16; msk <<= 1) p += __shfl_xor(p, msk, 16);
        if (g == 0){
            float dT = p + ldt_b[0];
            dTs[bb] = dT;
            out[(size_t)gb * 26] = dT;
        }
    }
    __syncthreads();

    // ---- P10b: build NZ A-tile [dT, xr, 0-pad] -> T0 (96 cols)
    if (g < 12){
        float dT = dTs[bb];
        int cb = g * 8;
        unsigned pr[4];
        #pragma unroll
        for (int pj = 0; pj < 4; ++pj){
            int c0 = cb + 2*pj, c1 = c0 + 1;
            float v0 = (c0 == 0) ? dT :
                       (c0 <= 64 ? __bfloat162float(*(const bf16*)TBA(XRB, bb, c0-1)) : 0.f);
            float v1 = (c1 <= 64 ? __bfloat162float(*(const bf16*)TBA(XRB, bb, c1-1)) : 0.f);
            pr[pj] = pk2(v0, v1);
        }
        *(uint4*)TBA(T0B, bb, cb) = (uint4){pr[0], pr[1], pr[2], pr[3]};
    }
    __syncthreads();

    // ---- P11: m65 = nza@nz_W + nz_b -> T1 (cols 0..79; zero 80..95)
    {
        uint4 aS[3];
        #pragma unroll
        for (int S = 0; S < 3; ++S)
            aS[S] = *(const uint4*)TBA(T0B, c15, S*32 + half*8);
        int nbl[2]; int nnb = 1; nbl[0] = w;
        if (w == 0){ nbl[1] = 4; nnb = 2; }
        for (int q = 0; q < nnb; ++q){
            int nb = nbl[q];
            int col = nb*16 + c15;
            float bias = (col < 65) ? nz_b[col] : 0.f;
            f32x4 ac0 = {bias,bias,bias,bias};
            #pragma unroll
            for (int S = 0; S < 3; ++S){
                uint4 bfv = packH[H_NZ + (nb*3 + S)*64 + lane];
                ac0 = MFMA(aS[S], bfv, ac0);
            }
            #pragma unroll
            for (int r = 0; r < 4; ++r)
                *(bf16*)TBA(T1B, half*4 + r, col) = __float2bfloat16(ac0[r]);
        }
        if (t < 32){
            int row = t >> 1, seg = t & 1;
            *(uint4*)TBA(T1B, row, 80 + seg*8) = (uint4){0u,0u,0u,0u};
        }
    }
    __syncthreads();

    // ---- P12: mz = m65@lz_W + lz_b -> TQ (bf16) + out[:,1..20]
    if (w < 2){
        uint4 aS[3];
        #pragma unroll
        for (int S = 0; S < 3; ++S)
            aS[S] = *(const uint4*)TBA(T1B, c15, S*32 + half*8);
        int nb = w;
        int col = nb*16 + c15;
        float bias = (col < 20) ? lz_b[col] : 0.f;
        f32x4 ac0 = {bias,bias,bias,bias};
        #pragma unroll
        for (int S = 0; S < 3; ++S){
            uint4 bfv = packH[H_LZ + (nb*3 + S)*64 + lane];
            ac0 = MFMA(aS[S], bfv, ac0);
        }
        #pragma unroll
        for (int r = 0; r < 4; ++r){
            int r0 = half*4 + r;
            *(bf16*)TBA(TQB, r0, col) = __float2bfloat16(ac0[r]);
            if (col < 20)
                out[(size_t)(B0 + r0) * 26 + 1 + col] = ac0[r];
        }
    }
    __syncthreads();

    // ---- P13: build FA tile [mz(20), dT, xr(64), 0-pad] -> T0 (96 cols)
    if (g < 12){
        float dT = dTs[bb];
        int cb = g * 8;
        unsigned pr[4];
        #pragma unroll
        for (int pj = 0; pj < 4; ++pj){
            float vv[2];
            #pragma unroll
            for (int hh = 0; hh < 2; ++hh){
                int c = cb + 2*pj + hh;
                float v;
                if (c < 20)       v = __bfloat162float(*(const bf16*)TBA(TQB, bb, c));
                else if (c == 20) v = dT;
                else if (c < 85)  v = __bfloat162float(*(const bf16*)TBA(XRB, bb, c - 21));
                else              v = 0.f;
                vv[hh] = v;
            }
            pr[pj] = pk2(vv[0], vv[1]);
        }
        *(uint4*)TBA(T0B, bb, cb) = (uint4){pr[0], pr[1], pr[2], pr[3]};
    }
    __syncthreads();

    // ---- P14: ma1 = fa@na0_W + na0_b -> T1 (96 cols)
    {
        uint4 aS[3];
        #pragma unroll
        for (int S = 0; S < 3; ++S)
            aS[S] = *(const uint4*)TBA(T0B, c15, S*32 + half*8);
        int nbl[2]; int nnb = 1; nbl[0] = w;
        if (w < 2){ nbl[1] = 4 + w; nnb = 2; }
        for (int q = 0; q < nnb; ++q){
            int nb = nbl[q];
            int col = nb*16 + c15;
            float bias = (col < 85) ? na0_b[col] : 0.f;
            f32x4 ac0 = {bias,bias,bias,bias};
            #pragma unroll
            for (int S = 0; S < 3; ++S){
                uint4 bfv = packH[H_NA0 + (nb*3 + S)*64 + lane];
                ac0 = MFMA(aS[S], bfv, ac0);
            }
            #pragma unroll
            for (int r = 0; r < 4; ++r)
                *(bf16*)TBA(T1B, half*4 + r, col) = __float2bfloat16(ac0[r]);
        }
    }
    __syncthreads();

    // ---- P15: ma2 = ma1@na1_W + na1_b -> T0 (96 cols)
    {
        uint4 aS[3];
        #pragma unroll
        for (int S = 0; S < 3; ++S)
            aS[S] = *(const uint4*)TBA(T1B, c15, S*32 + half*8);
        int nbl[2]; int nnb = 1; nbl[0] = w;
        if (w < 2){ nbl[1] = 4 + w; nnb = 2; }
        for (int q = 0; q < nnb; ++q){
            int nb = nbl[q];
            int col = nb*16 + c15;
            float bias = (col < 85) ? na1_b[col] : 0.f;
            f32x4 ac0 = {bias,bias,bias,bias};
            #pragma unroll
            for (int S = 0; S < 3; ++S){
                uint4 bfv = packH[H_NA1 + (nb*3 + S)*64 + lane];
                ac0 = MFMA(aS[S], bfv, ac0);
            }
            #pragma unroll
            for (int r = 0; r < 4; ++r)
                *(bf16*)TBA(T0B, half*4 + r, col) = __float2bfloat16(ac0[r]);
        }
    }
    __syncthreads();

    // ---- P16: ma = ma2@la_W + la_b -> out[:,21..25]
    if (w == 0){
        int col = c15;
        float bias = (col < 5) ? la_b[col] : 0.f;
        f32x4 ac0 = {bias,bias,bias,bias};
        #pragma unroll
        for (int S = 0; S < 3; ++S){
            uint4 bfv = packH[H_LA + S*64 + lane];
            uint4 a0 = *(const uint4*)TBA(T0B, c15, S*32 + half*8);
            ac0 = MFMA(a0, bfv, ac0);
        }
        if (col < 5){
            #pragma unroll
            for (int r = 0; r < 4; ++r)
                out[(size_t)(B0 + half*4 + r) * 26 + 21 + col] = ac0[r];
        }
    }
}

extern "C" void kernel_launch(void* const* d_in, const int* in_sizes, int n_in,
                              void* d_out, int out_size, void* d_ws, size_t ws_size,
                              hipStream_t stream)
{
    const float* X        = (const float*)d_in[0];
    const float* emb_act  = (const float*)d_in[1];
    const float* emb_zone = (const float*)d_in[2];
    const float* lin0_W   = (const float*)d_in[3];
    const float* lin0_b   = (const float*)d_in[4];
    const float* gat_W    = (const float*)d_in[5];
    const float* gat_b    = (const float*)d_in[6];
    const float* gat_a    = (const float*)d_in[7];
    const float* gl0_W    = (const float*)d_in[8];
    const float* gl0_b    = (const float*)d_in[9];
    const float* gl1_W    = (const float*)d_in[10];
    const float* gl1_b    = (const float*)d_in[11];
    const float* gl2_W    = (const float*)d_in[12];
    const float* gl2_b    = (const float*)d_in[13];
    const float* Wqkv     = (const float*)d_in[14];
    const float* bqkv     = (const float*)d_in[15];
    const float* Wo       = (const float*)d_in[16];
    const float* bo       = (const float*)d_in[17];
    const float* ln1_g    = (const float*)d_in[18];
    const float* ln1_b    = (const float*)d_in[19];
    const float* W1       = (const float*)d_in[20];
    const float* b1       = (const float*)d_in[21];
    const float* W2       = (const float*)d_in[22];
    const float* b2       = (const float*)d_in[23];
    const float* ln2_g    = (const float*)d_in[24];
    const float* ln2_b    = (const float*)d_in[25];
    const float* relu_W   = (const float*)d_in[26];
    const float* relu_b   = (const float*)d_in[27];
    const float* nd_W     = (const float*)d_in[28];
    const float* nd_b     = (const float*)d_in[29];
    const float* ldt_W    = (const float*)d_in[30];
    const float* ldt_b    = (const float*)d_in[31];
    const float* nz_W     = (const float*)d_in[32];
    const float* nz_b     = (const float*)d_in[33];
    const float* lz_W     = (const float*)d_in[34];
    const float* lz_b     = (const float*)d_in[35];
    const float* na0_W    = (const float*)d_in[36];
    const float* na0_b    = (const float*)d_in[37];
    const float* na1_W    = (const float*)d_in[38];
    const float* na1_b    = (const float*)d_in[39];
    const float* la_W     = (const float*)d_in[40];
    const float* la_b     = (const float*)d_in[41];

    char* wsb = (char*)d_ws;
    bf16*  kv       = (bf16*)wsb;
    float* src_last = (float*)(wsb + (size_t)NTOK * 128 * sizeof(bf16));
    uint4* packW    = (uint4*)(wsb + (size_t)NTOK * 128 * sizeof(bf16) + (size_t)B_ * 64 * sizeof(float));
    uint4* packH    = packW + PK_TOT;

    k_pack_all<<<(PK_TOT + H_TOT + 255)/256, 256, 0, stream>>>(
        gl0_W, gl1_W, gl2_W, Wqkv, Wo, W1, W2, relu_W, nd_W, nz_W, lz_W,
        na0_W, na1_W, la_W, packW, packH);

    k_token<<<NTOK/TOKB, TPB, 0, stream>>>(X, emb_act, emb_zone, lin0_W, lin0_b,
        gat_W, gat_b, gat_a, gl0_b, gl1_b, gl2_b, bqkv, packW, kv, src_last);

    k_head2<<<B_/16, 256, 0, stream>>>(kv, src_last, packH, bqkv, bo,
        ln1_g, ln1_b, b1, b2, ln2_g, ln2_b, relu_b, nd_b, ldt_W, ldt_b,
        nz_b, lz_b, na0_b, na1_b, la_b, (float*)d_out);
}

// Round 11
// 70.284 us; speedup vs baseline: 2.6221x; 1.0121x over previous
//
#include <hip/hip_runtime.h>
#include <hip/hip_bf16.h>

typedef __hip_bfloat16 bf16;
typedef float f32x4 __attribute__((ext_vector_type(4)));
typedef short s16x8 __attribute__((ext_vector_type(8)));

#define B_    2048
#define S_    40
#define NTOK  (B_*S_)
#define TPB   256
#define TOKB  64

// ---- k_token LDS layout (dwords). A1 aliases FF (FF dead after phase 1).
#define FF_OFF    0
#define A1_OFFD   0
#define A0_OFFD   3520
#define PE_OFFD   7616
#define IA_OFFD   7680
#define HD_OFFD   7744
#define LDS_DW    8128     // 32512 B

#define A0B (A0_OFFD*4)
#define A1B (A1_OFFD*4)

// ---- packW (token) fragment offsets (uint4 units)
#define PK_GL0 0
#define PK_GL1 1024
#define PK_GL2 1536
#define PK_KV  1664
#define PK_TOT 2688

// ---- packH (head) fragment offsets (uint4 units)
#define H_WQ   0
#define H_WO   512
#define H_W1   1024
#define H_W2   3072
#define H_RELU 5120
#define H_ND   5632
#define H_NZ   6144
#define H_LZ   7104
#define H_NA0  7488
#define H_NA1  8640
#define H_LA   9792
#define H_TOT  9984

__device__ inline unsigned pk2(float a, float b){
    __hip_bfloat16 ha = __float2bfloat16(a), hb = __float2bfloat16(b);
    unsigned short ua = *reinterpret_cast<unsigned short*>(&ha);
    unsigned short ub = *reinterpret_cast<unsigned short*>(&hb);
    return (unsigned)ua | ((unsigned)ub << 16);
}
__device__ inline float blo(unsigned u){ return __uint_as_float(u << 16); }
__device__ inline float bhi(unsigned u){ return __uint_as_float(u & 0xffff0000u); }

__device__ inline float fexp2(float x){
#if __has_builtin(__builtin_amdgcn_exp2f)
    return __builtin_amdgcn_exp2f(x);
#else
    return exp2f(x);
#endif
}

__device__ inline f32x4 MFMA(uint4 a, uint4 b, f32x4 c){
    union { uint4 q; s16x8 s; } A, Bv;
    A.q = a; Bv.q = b;
    return __builtin_amdgcn_mfma_f32_16x16x32_bf16(A.s, Bv.s, c, 0, 0, 0);
}

// load ff row j (5 bf16 at bf16-index 5j) from contiguous packing
__device__ inline void ldff(const unsigned* L, unsigned tb, int j, float f[5]){
    int k = (5*j) >> 1;
    unsigned u0 = L[tb + k], u1 = L[tb + k + 1], u2 = L[tb + k + 2];
    if ((j & 1) == 0){
        f[0]=blo(u0); f[1]=bhi(u0); f[2]=blo(u1); f[3]=bhi(u1); f[4]=blo(u2);
    } else {
        f[0]=bhi(u0); f[1]=blo(u1); f[2]=bhi(u1); f[3]=blo(u2); f[4]=bhi(u2);
    }
}

__device__ inline uint4 packB(const float* W, int ld, int K, int N, int nb, int S, int lane){
    int half = lane >> 4, c15 = lane & 15;
    int col = nb*16 + c15;
    unsigned pr[4];
    #pragma unroll
    for (int jj = 0; jj < 4; ++jj){
        int k0 = S*32 + half*8 + 2*jj;
        float v0 = (k0   < K && col < N) ? W[(size_t)k0*ld + col]     : 0.f;
        float v1 = (k0+1 < K && col < N) ? W[(size_t)(k0+1)*ld + col] : 0.f;
        pr[jj] = pk2(v0, v1);
    }
    return (uint4){pr[0], pr[1], pr[2], pr[3]};
}

// ---------------- Kernel 0: pre-pack ALL weight fragments ----------------
__global__ __launch_bounds__(256) void k_pack_all(
    const float* __restrict__ gl0_W, const float* __restrict__ gl1_W,
    const float* __restrict__ gl2_W, const float* __restrict__ Wqkv,
    const float* __restrict__ Wo,    const float* __restrict__ W1,
    const float* __restrict__ W2,    const float* __restrict__ relu_W,
    const float* __restrict__ nd_W,  const float* __restrict__ nz_W,
    const float* __restrict__ lz_W,  const float* __restrict__ na0_W,
    const float* __restrict__ na1_W, const float* __restrict__ la_W,
    uint4* __restrict__ packW, uint4* __restrict__ packH)
{
    int f = blockIdx.x * 256 + threadIdx.x;
    if (f < PK_TOT){
        unsigned pr[4];
        if (f < PK_GL1){
            int w = f >> 8, r = f & 255, S = r >> 6, lane = r & 63;
            int half = lane >> 4, c15 = lane & 15, col = w * 16 + c15;
            #pragma unroll
            for (int jj = 0; jj < 4; ++jj){
                int k0 = S*32 + half*8 + 2*jj;
                float v0 = (k0   < 110) ? gl0_W[k0*64 + col]     : 0.f;
                float v1 = (k0+1 < 110) ? gl0_W[(k0+1)*64 + col] : 0.f;
                pr[jj] = pk2(v0, v1);
            }
        } else if (f < PK_GL2){
            int g = f - PK_GL1, w = g >> 7, r = g & 127, S = r >> 6, lane = r & 63;
            int half = lane >> 4, c15 = lane & 15, col = w * 16 + c15;
            #pragma unroll
            for (int jj = 0; jj < 4; ++jj){
                int k0 = S*32 + half*8 + 2*jj;
                pr[jj] = pk2(gl1_W[k0*64 + col], gl1_W[(k0+1)*64 + col]);
            }
        } else if (f < PK_KV){
            int g = f - PK_GL2, S = g >> 6, lane = g & 63;
            int half = lane >> 4, c15 = lane & 15;
            #pragma unroll
            for (int jj = 0; jj < 4; ++jj){
                int k0 = S*32 + half*8 + 2*jj;
                pr[jj] = pk2(gl2_W[k0*16 + c15], gl2_W[(k0+1)*16 + c15]);
            }
        } else {
            int g = f - PK_KV, w = g >> 8, r = g & 255, cf = r >> 7, r2 = r & 127;
            int S = r2 >> 6, lane = r2 & 63;
            int half = lane >> 4, c15 = lane & 15, col = 64 + w*32 + cf*16 + c15;
            #pragma unroll
            for (int jj = 0; jj < 4; ++jj){
                int k0 = S*32 + half*8 + 2*jj;
                pr[jj] = pk2(Wqkv[k0*192 + col], Wqkv[(k0+1)*192 + col]);
            }
        }
        packW[f] = (uint4){pr[0], pr[1], pr[2], pr[3]};
        return;
    }
    int f2 = f - PK_TOT;
    if (f2 >= H_TOT) return;
    const float* W; int ld, K, N, St, base;
    if      (f2 < H_WO ){ W=Wqkv;   ld=192; K=64;  N=64;  St=2; base=H_WQ;  }
    else if (f2 < H_W1 ){ W=Wo;     ld=64;  K=64;  N=64;  St=2; base=H_WO;  }
    else if (f2 < H_W2 ){ W=W1;     ld=256; K=64;  N=256; St=2; base=H_W1;  }
    else if (f2 < H_RELU){W=W2;     ld=64;  K=256; N=64;  St=8; base=H_W2;  }
    else if (f2 < H_ND ){ W=relu_W; ld=64;  K=64;  N=64;  St=2; base=H_RELU;}
    else if (f2 < H_NZ ){ W=nd_W;   ld=64;  K=64;  N=64;  St=2; base=H_ND;  }
    else if (f2 < H_LZ ){ W=nz_W;   ld=65;  K=65;  N=65;  St=3; base=H_NZ;  }
    else if (f2 < H_NA0){ W=lz_W;   ld=20;  K=65;  N=20;  St=3; base=H_LZ;  }
    else if (f2 < H_NA1){ W=na0_W;  ld=85;  K=85;  N=85;  St=3; base=H_NA0; }
    else if (f2 < H_LA ){ W=na1_W;  ld=85;  K=85;  N=85;  St=3; base=H_NA1; }
    else               { W=la_W;   ld=5;   K=85;  N=5;   St=3; base=H_LA;  }
    int loc = f2 - base;
    int nb = loc / (St*64);
    int rem = loc - nb*St*64;
    packH[f2] = packB(W, ld, K, N, nb, rem >> 6, rem & 63);
}

// ---------------- Kernel 1: MFMA featurizer ----------------
__global__ __launch_bounds__(TPB) void k_token(
    const float* __restrict__ X,
    const float* __restrict__ emb_act,
    const float* __restrict__ emb_zone,
    const float* __restrict__ lin0_W, const float* __restrict__ lin0_b,
    const float* __restrict__ gat_W,  const float* __restrict__ gat_b,
    const float* __restrict__ gat_a,
    const float* __restrict__ gl0_b,  const float* __restrict__ gl1_b,
    const float* __restrict__ gl2_b,  const float* __restrict__ bqkv,
    const uint4* __restrict__ packW,
    bf16* __restrict__ kv, float* __restrict__ src_last)
{
    __shared__ unsigned L[LDS_DW];
    char* Lb = (char*)L;

    const int t    = threadIdx.x;
    const int w    = t >> 6;
    const int lane = t & 63;
    const int half = (lane >> 4);
    const int c15  = lane & 15;
    const int blk0 = blockIdx.x * TOKB;
    const int swzc = (c15 & 7) << 4;

    // ---------- phase 0 ----------
    for (int task = t; task < TOKB * 11; task += TPB){
        int tt = task / 11;
        int p  = task - tt * 11;
        const float2* xp = (const float2*)(X + (size_t)(blk0 + tt) * 118 + 8 + 10 * p);
        float2 a0 = xp[0], a1 = xp[1], a2 = xp[2], a3 = xp[3], a4 = xp[4];
        unsigned* dst = &L[FF_OFF + tt * 55 + 5 * p];
        dst[0] = pk2(a0.x, a0.y);
        dst[1] = pk2(a1.x, a1.y);
        dst[2] = pk2(a2.x, a2.y);
        dst[3] = pk2(a3.x, a3.y);
        dst[4] = pk2(a4.x, a4.y);
    }
    for (int idx = t; idx < 64 * 9; idx += TPB){
        int row = idx / 9, p = idx - row * 9;
        *(unsigned*)(Lb + A0B + row * 256 + ((220 + 4*p) ^ ((row & 7) << 4))) = 0u;
    }
    if (t < TOKB){
        int tok = blk0 + t;
        const float2* xp = (const float2*)(X + (size_t)tok * 118);
        float2 v0 = xp[0], v1 = xp[1], v2 = xp[2], v3 = xp[3];
        int b = tok / 40, s = tok - b * 40;
        float expo = (2.0f * (float)s) / 40.0f;
        float inv100 = fexp2(-expo * 6.6438561897747395f);
        float ang = (float)b * inv100;
        float pe = ((s & 1) == 0) ? __sinf(ang) : __cosf(ang);
        ((float*)&L[PE_OFFD])[t] = pe;
        L[IA_OFFD + t] = (((unsigned)(int)v0.x) << 16) | ((unsigned)(int)v0.y & 0xffffu);
        float* hdL = (float*)&L[HD_OFFD + t * 6];
        hdL[0] = v1.x; hdL[1] = v1.y; hdL[2] = v2.x;
        hdL[3] = v2.y; hdL[4] = v3.x; hdL[5] = v3.y;
    }
    __syncthreads();

    // ---------- phase 1: GAT (no max-subtraction; logits are O(1), exp-safe) ----------
    {
        const float LOG2E = 1.4426950408889634f;
        const unsigned tb = FF_OFF + lane * 55;
        float va1[5], va2[5];
        float cc1 = 0.f, cc2 = 0.f;
        #pragma unroll
        for (int e = 0; e < 5; ++e){
            float u1 = 0.f, u2 = 0.f;
            #pragma unroll
            for (int d = 0; d < 5; ++d){
                u1 += gat_W[e*5+d] * gat_a[d];
                u2 += gat_W[e*5+d] * gat_a[5+d];
            }
            va1[e] = u1 * LOG2E; va2[e] = u2 * LOG2E;
        }
        #pragma unroll
        for (int d = 0; d < 5; ++d){ cc1 += gat_b[d]*gat_a[d]; cc2 += gat_b[d]*gat_a[5+d]; }
        cc1 *= LOG2E; cc2 *= LOG2E;

        const int wbase = w * 6;
        float s1own[6], Z[6], ffp[6][5];
        #pragma unroll
        for (int ii = 0; ii < 6; ++ii){
            int i = wbase + ii; if (i > 21) i = 21;
            float f[5]; ldff(L, tb, i, f);
            s1own[ii] = cc1 + f[0]*va1[0] + f[1]*va1[1] + f[2]*va1[2] + f[3]*va1[3] + f[4]*va1[4];
            Z[ii] = 0.f;
            #pragma unroll
            for (int e = 0; e < 5; ++e) ffp[ii][e] = 0.f;
        }

        #pragma unroll
        for (int j = 0; j < 22; ++j){
            float f[5]; ldff(L, tb, j, f);
            float s2j = cc2 + f[0]*va2[0] + f[1]*va2[1] + f[2]*va2[2] + f[3]*va2[3] + f[4]*va2[4];
            #pragma unroll
            for (int ii = 0; ii < 6; ++ii){
                float e2 = s1own[ii] + s2j;
                float lr = fmaxf(e2, 0.2f * e2);   // leaky_relu (in log2 domain)
                float wg = fexp2(lr);
                Z[ii] += wg;
                ffp[ii][0] = fmaf(wg, f[0], ffp[ii][0]);
                ffp[ii][1] = fmaf(wg, f[1], ffp[ii][1]);
                ffp[ii][2] = fmaf(wg, f[2], ffp[ii][2]);
                ffp[ii][3] = fmaf(wg, f[3], ffp[ii][3]);
                ffp[ii][4] = fmaf(wg, f[4], ffp[ii][4]);
            }
        }

        const int rswz = (lane & 7) << 4;
        #pragma unroll
        for (int ii = 0; ii < 6; ++ii){
            int i = wbase + ii;
            if (i < 22){
                float rz = 1.f / Z[ii];
                #pragma unroll
                for (int d = 0; d < 5; ++d){
                    float u = 0.f;
                    #pragma unroll
                    for (int e = 0; e < 5; ++e) u += ffp[ii][e] * gat_W[e*5+d];
                    float h = u * rz + gat_b[d];
                    *(bf16*)(Lb + A0B + lane*256 + ((10*i + 2*d) ^ rswz)) = __float2bfloat16(h);
                }
            }
        }
    }
    __syncthreads();

    // ---------- phase 2: gl0 MFMA (K=128) -> A1 ----------
    {
        uint4 bfr[4];
        #pragma unroll
        for (int S = 0; S < 4; ++S) bfr[S] = packW[PK_GL0 + (w*4 + S)*64 + lane];
        const int col = w * 16 + c15;
        float bias = gl0_b[col];
        f32x4 ac0 = {bias,bias,bias,bias}, ac1 = ac0, ac2 = ac0, ac3 = ac0;
        #pragma unroll
        for (int S = 0; S < 4; ++S){
            int koff = S*64 + half*16;
            uint4 a0 = *(const uint4*)(Lb + A0B + (0*16 + c15)*256 + (koff ^ swzc));
            uint4 a1 = *(const uint4*)(Lb + A0B + (1*16 + c15)*256 + (koff ^ swzc));
            uint4 a2 = *(const uint4*)(Lb + A0B + (2*16 + c15)*256 + (koff ^ swzc));
            uint4 a3 = *(const uint4*)(Lb + A0B + (3*16 + c15)*256 + (koff ^ swzc));
            ac0 = MFMA(a0, bfr[S], ac0);
            ac1 = MFMA(a1, bfr[S], ac1);
            ac2 = MFMA(a2, bfr[S], ac2);
            ac3 = MFMA(a3, bfr[S], ac3);
        }
        const int off = col * 2;
        #pragma unroll
        for (int r = 0; r < 4; ++r){
            int row0 = 0*16 + half*4 + r;
            int row1 = 1*16 + half*4 + r;
            int row2 = 2*16 + half*4 + r;
            int row3 = 3*16 + half*4 + r;
            *(bf16*)(Lb + A1B + row0*128 + (off ^ ((row0 & 7) << 4))) = __float2bfloat16(fmaxf(ac0[r], 0.f));
            *(bf16*)(Lb + A1B + row1*128 + (off ^ ((row1 & 7) << 4))) = __float2bfloat16(fmaxf(ac1[r], 0.f));
            *(bf16*)(Lb + A1B + row2*128 + (off ^ ((row2 & 7) << 4))) = __float2bfloat16(fmaxf(ac2[r], 0.f));
            *(bf16*)(Lb + A1B + row3*128 + (off ^ ((row3 & 7) << 4))) = __float2bfloat16(fmaxf(ac3[r], 0.f));
        }
    }
    __syncthreads();

    // ---------- phase 3: gl1 MFMA (A1 -> A0, stride 128B) ----------
    {
        uint4 bfr[2];
        #pragma unroll
        for (int S = 0; S < 2; ++S) bfr[S] = packW[PK_GL1 + (w*2 + S)*64 + lane];
        const int col = w * 16 + c15;
        float bias = gl1_b[col];
        f32x4 ac0 = {bias,bias,bias,bias}, ac1 = ac0, ac2 = ac0, ac3 = ac0;
        #pragma unroll
        for (int S = 0; S < 2; ++S){
            int koff = S*64 + half*16;
            uint4 a0 = *(const uint4*)(Lb + A1B + (0*16 + c15)*128 + (koff ^ swzc));
            uint4 a1 = *(const uint4*)(Lb + A1B + (1*16 + c15)*128 + (koff ^ swzc));
            uint4 a2 = *(const uint4*)(Lb + A1B + (2*16 + c15)*128 + (koff ^ swzc));
            uint4 a3 = *(const uint4*)(Lb + A1B + (3*16 + c15)*128 + (koff ^ swzc));
            ac0 = MFMA(a0, bfr[S], ac0);
            ac1 = MFMA(a1, bfr[S], ac1);
            ac2 = MFMA(a2, bfr[S], ac2);
            ac3 = MFMA(a3, bfr[S], ac3);
        }
        const int off = col * 2;
        #pragma unroll
        for (int r = 0; r < 4; ++r){
            int row0 = 0*16 + half*4 + r;
            int row1 = 1*16 + half*4 + r;
            int row2 = 2*16 + half*4 + r;
            int row3 = 3*16 + half*4 + r;
            *(bf16*)(Lb + A0B + row0*128 + (off ^ ((row0 & 7) << 4))) = __float2bfloat16(fmaxf(ac0[r], 0.f));
            *(bf16*)(Lb + A0B + row1*128 + (off ^ ((row1 & 7) << 4))) = __float2bfloat16(fmaxf(ac1[r], 0.f));
            *(bf16*)(Lb + A0B + row2*128 + (off ^ ((row2 & 7) << 4))) = __float2bfloat16(fmaxf(ac2[r], 0.f));
            *(bf16*)(Lb + A0B + row3*128 + (off ^ ((row3 & 7) << 4))) = __float2bfloat16(fmaxf(ac3[r], 0.f));
        }
    }
    __syncthreads();

    // ---------- phase 4: gl2 MFMA + src build into A1 ----------
    {
        uint4 bfr[2];
        #pragma unroll
        for (int S = 0; S < 2; ++S) bfr[S] = packW[PK_GL2 + S*64 + lane];
        float bias = gl2_b[c15];
        f32x4 ac = {bias,bias,bias,bias};
        #pragma unroll
        for (int S = 0; S < 2; ++S){
            int koff = S*64 + half*16;
            uint4 a = *(const uint4*)(Lb + A0B + (w*16 + c15)*128 + (koff ^ swzc));
            ac = MFMA(a, bfr[S], ac);
        }
        const float* pef = (const float*)&L[PE_OFFD];
        const int off = (48 + c15) * 2;
        #pragma unroll
        for (int r = 0; r < 4; ++r){
            int row = w*16 + half*4 + r;
            float v = fmaxf(ac[r], 0.f) + pef[row];
            *(bf16*)(Lb + A1B + row*128 + (off ^ ((row & 7) << 4))) = __float2bfloat16(v);
        }

        float pe = pef[lane];
        unsigned iaz = L[IA_OFFD + lane];
        int ia = (int)(iaz >> 16), iz = (int)(iaz & 0xffffu);
        const float* hdL = (const float*)&L[HD_OFFD + lane * 6];
        const int tswz = (lane & 7) << 4;
        #pragma unroll
        for (int pp = 0; pp < 6; ++pp){
            int p = w * 6 + pp;
            int c0 = 2 * p;
            float v0, v1;
            if (p < 8)        { v0 = emb_act[ia*16 + c0];        v1 = emb_act[ia*16 + c0 + 1]; }
            else if (p < 16)  { v0 = emb_zone[iz*16 + c0 - 16];  v1 = emb_zone[iz*16 + c0 - 15]; }
            else {
                int cc = c0 - 32;
                float o0 = lin0_b[cc], o1 = lin0_b[cc+1];
                #pragma unroll
                for (int e = 0; e < 6; ++e){
                    float f = hdL[e];
                    o0 = fmaf(f, lin0_W[e*16 + cc], o0);
                    o1 = fmaf(f, lin0_W[e*16 + cc + 1], o1);
                }
                v0 = o0; v1 = o1;
            }
            *(unsigned*)(Lb + A1B + lane*128 + ((4*p) ^ tswz)) = pk2(v0 + pe, v1 + pe);
        }
    }
    __syncthreads();

    // ---------- phase 5: src_last + KV MFMA ----------
    {
        int r0 = 39 - (blk0 % 40);
        if (t < 128){
            int tok = r0 + 40 * (t >> 6);
            if (tok < 64){
                int col = t & 63;
                bf16 hv = *(const bf16*)(Lb + A1B + tok*128 + ((col*2) ^ ((tok & 7) << 4)));
                src_last[(size_t)((blk0 + tok) / 40) * 64 + col] = __bfloat162float(hv);
            }
        }

        uint4 bfk[2][2];
        #pragma unroll
        for (int cf = 0; cf < 2; ++cf)
            #pragma unroll
            for (int S = 0; S < 2; ++S)
                bfk[cf][S] = packW[PK_KV + ((w*2 + cf)*2 + S)*64 + lane];

        float b0v = bqkv[64 + w*32 + c15];
        float b1v = bqkv[64 + w*32 + 16 + c15];
        f32x4 acc[4][2];
        #pragma unroll
        for (int R = 0; R < 4; ++R){
            acc[R][0] = (f32x4){b0v, b0v, b0v, b0v};
            acc[R][1] = (f32x4){b1v, b1v, b1v, b1v};
        }
        #pragma unroll
        for (int S = 0; S < 2; ++S){
            int koff = S*64 + half*16;
            #pragma unroll
            for (int R = 0; R < 4; ++R){
                uint4 a = *(const uint4*)(Lb + A1B + (R*16 + c15)*128 + (koff ^ swzc));
                acc[R][0] = MFMA(a, bfk[0][S], acc[R][0]);
                acc[R][1] = MFMA(a, bfk[1][S], acc[R][1]);
            }
        }
        #pragma unroll
        for (int R = 0; R < 4; ++R){
            #pragma unroll
            for (int cf = 0; cf < 2; ++cf){
                int lcol = w*32 + cf*16 + c15;
                int off = lcol * 2;
                #pragma unroll
                for (int r = 0; r < 4; ++r){
                    int row = R*16 + half*4 + r;
                    *(bf16*)(Lb + A0B + row*256 + (off ^ ((row & 7) << 4))) = __float2bfloat16(acc[R][cf][r]);
                }
            }
        }
    }
    __syncthreads();

    {
        int row = t >> 2;
        int q = t & 3;
        #pragma unroll
        for (int c = 0; c < 4; ++c){
            int chunk = q*4 + c;
            uint4 d = *(const uint4*)(Lb + A0B + row*256 + ((chunk*16) ^ ((row & 7) << 4)));
            *((uint4*)(kv + (size_t)(blk0 + row) * 128 + chunk * 8)) = d;
        }
    }
}

// ---------------- Kernel 2: MFMA head (16 batches/block, 128 blocks) ----------------
#define T0B 0
#define T1B 4096
#define TQB 8192
#define XRB 12288
#define XFB 16384
#define TFB 20480
#define DTS 28672

#define TBA(base, row, col) (Lb + (base) + (row)*256 + ((((col)*2)) ^ (((row)&7)<<4)))
#define TFA(row, col)       (Lb + TFB   + (row)*512 + ((((col)*2)) ^ (((row)&7)<<4)))
#define XFA(row, col)       (Lb + XFB   + (row)*256 + ((((col)*4)) ^ (((row)&7)<<4)))

#define UNPK(u, arr) { arr[0]=blo(u.x); arr[1]=bhi(u.x); arr[2]=blo(u.y); arr[3]=bhi(u.y); \
                       arr[4]=blo(u.z); arr[5]=bhi(u.z); arr[6]=blo(u.w); arr[7]=bhi(u.w); }

__global__ __launch_bounds__(256) void k_head2(
    const bf16* __restrict__ kv, const float* __restrict__ src_last,
    const uint4* __restrict__ packH,
    const float* __restrict__ bqkv,  const float* __restrict__ bo,
    const float* __restrict__ ln1_g, const float* __restrict__ ln1_b,
    const float* __restrict__ b1,    const float* __restrict__ b2,
    const float* __restrict__ ln2_g, const float* __restrict__ ln2_b,
    const float* __restrict__ relu_b, const float* __restrict__ nd_b,
    const float* __restrict__ ldt_W, const float* __restrict__ ldt_b,
    const float* __restrict__ nz_b,  const float* __restrict__ lz_b,
    const float* __restrict__ na0_b, const float* __restrict__ na1_b,
    const float* __restrict__ la_b,
    float* __restrict__ out)
{
    __shared__ uint4 Lsh[1796];   // 28736 B
    char* Lb = (char*)Lsh;
    float* dTs = (float*)(Lb + DTS);

    const int t    = threadIdx.x;
    const int w    = t >> 6;
    const int lane = t & 63;
    const int half = lane >> 4;
    const int c15  = lane & 15;
    const int B0   = blockIdx.x * 16;
    const int bb   = t >> 4;
    const int g    = t & 15;
    const int gb   = B0 + bb;

    {
        float4 v = *(const float4*)(src_last + (size_t)gb * 64 + g * 4);
        *(float4*)XFA(bb, g*4) = v;
        uint2 u;
        u.x = pk2(v.x, v.y); u.y = pk2(v.z, v.w);
        *(uint2*)TBA(T0B, bb, g*4) = u;
    }
    __syncthreads();

    {
        int col = w*16 + c15;
        float bias = bqkv[col];
        f32x4 ac0 = {bias,bias,bias,bias};
        #pragma unroll
        for (int S = 0; S < 2; ++S){
            uint4 bfv = packH[H_WQ + (w*2 + S)*64 + lane];
            uint4 a0 = *(const uint4*)TBA(T0B, c15, S*32 + half*8);
            ac0 = MFMA(a0, bfv, ac0);
        }
        #pragma unroll
        for (int r = 0; r < 4; ++r)
            *(bf16*)TBA(TQB, half*4 + r, col) = __float2bfloat16(ac0[r] * 0.35355339059327373f);
    }
    __syncthreads();

    if (t < 128){
        int pb = t >> 3, h = t & 7;
        int gpb = B0 + pb;
        uint4 qu = *(const uint4*)TBA(TQB, pb, h*8);
        float qh[8]; UNPK(qu, qh);
        const uint4* kp = (const uint4*)(kv + (size_t)gpb * 40 * 128 + h*8);
        const uint4* vp = (const uint4*)(kv + (size_t)gpb * 40 * 128 + 64 + h*8);
        float sc[40];
        float m = -1e30f;
        #pragma unroll 4
        for (int j = 0; j < 40; ++j){
            uint4 ku = kp[j*16];
            float kf[8]; UNPK(ku, kf);
            float a = qh[0]*kf[0] + qh[1]*kf[1] + qh[2]*kf[2] + qh[3]*kf[3]
                    + qh[4]*kf[4] + qh[5]*kf[5] + qh[6]*kf[6] + qh[7]*kf[7];
            sc[j] = a; m = fmaxf(m, a);
        }
        float Z = 0.f;
        float o[8] = {0.f,0.f,0.f,0.f,0.f,0.f,0.f,0.f};
        #pragma unroll 4
        for (int j = 0; j < 40; ++j){
            float wj = __expf(sc[j] - m);
            Z += wj;
            uint4 vu = vp[j*16];
            float vf[8]; UNPK(vu, vf);
            #pragma unroll
            for (int d = 0; d < 8; ++d) o[d] = fmaf(wj, vf[d], o[d]);
        }
        float rz = 1.f / Z;
        uint4 u;
        u.x = pk2(o[0]*rz, o[1]*rz); u.y = pk2(o[2]*rz, o[3]*rz);
        u.z = pk2(o[4]*rz, o[5]*rz); u.w = pk2(o[6]*rz, o[7]*rz);
        *(uint4*)TBA(T1B, pb, h*8) = u;
    }
    __syncthreads();

    {
        int col = w*16 + c15;
        float bias = bo[col];
        f32x4 ac0 = {bias,bias,bias,bias};
        #pragma unroll
        for (int S = 0; S < 2; ++S){
            uint4 bfv = packH[H_WO + (w*2 + S)*64 + lane];
            uint4 a0 = *(const uint4*)TBA(T1B, c15, S*32 + half*8);
            ac0 = MFMA(a0, bfv, ac0);
        }
        #pragma unroll
        for (int r = 0; r < 4; ++r)
            *(float*)XFA(half*4 + r, col) += ac0[r];
    }
    __syncthreads();

    {
        float4 v = *(const float4*)XFA(bb, g*4);
        float vv[4] = {v.x, v.y, v.z, v.w};
        float s = 0.f, s2 = 0.f;
        #pragma unroll
        for (int j = 0; j < 4; ++j){ s += vv[j]; s2 += vv[j]*vv[j]; }
        #pragma unroll
        for (int msk = 1; msk < 16; msk <<= 1){ s += __shfl_xor(s, msk, 16); s2 += __shfl_xor(s2, msk, 16); }
        float mean = s * (1.f/64.f);
        float var  = s2 * (1.f/64.f) - mean*mean;
        float rstd = rsqrtf(var + 1e-5f);
        float xf[4];
        #pragma unroll
        for (int j = 0; j < 4; ++j){
            int c = g*4 + j;
            xf[j] = (vv[j] - mean) * rstd * ln1_g[c] + ln1_b[c];
        }
        uint2 u;
        u.x = pk2(xf[0], xf[1]); u.y = pk2(xf[2], xf[3]);
        *(uint2*)TBA(T0B, bb, g*4) = u;
        *(float4*)XFA(bb, g*4) = (float4){xf[0], xf[1], xf[2], xf[3]};
    }
    __syncthreads();

    {
        uint4 aS[2];
        #pragma unroll
        for (int S = 0; S < 2; ++S)
            aS[S] = *(const uint4*)TBA(T0B, c15, S*32 + half*8);
        #pragma unroll
        for (int k = 0; k < 4; ++k){
            int nb = k*4 + w;
            int col = nb*16 + c15;
            float bias = b1[col];
            f32x4 ac0 = {bias,bias,bias,bias};
            #pragma unroll
            for (int S = 0; S < 2; ++S){
                uint4 bfv = packH[H_W1 + (nb*2 + S)*64 + lane];
                ac0 = MFMA(aS[S], bfv, ac0);
            }
            #pragma unroll
            for (int r = 0; r < 4; ++r)
                *(bf16*)TFA(half*4 + r, col) = __float2bfloat16(fmaxf(ac0[r], 0.f));
        }
    }
    __syncthreads();

    {
        int col = w*16 + c15;
        float bias = b2[col];
        f32x4 ac0 = {bias,bias,bias,bias};
        #pragma unroll
        for (int S = 0; S < 8; ++S){
            uint4 bfv = packH[H_W2 + (w*8 + S)*64 + lane];
            uint4 a0 = *(const uint4*)TFA(c15, S*32 + half*8);
            ac0 = MFMA(a0, bfv, ac0);
        }
        #pragma unroll
        for (int r = 0; r < 4; ++r)
            *(float*)XFA(half*4 + r, col) += ac0[r];
    }
    __syncthreads();

    {
        float4 v = *(const float4*)XFA(bb, g*4);
        float vv[4] = {v.x, v.y, v.z, v.w};
        float s = 0.f, s2 = 0.f;
        #pragma unroll
        for (int j = 0; j < 4; ++j){ s += vv[j]; s2 += vv[j]*vv[j]; }
        #pragma unroll
        for (int msk = 1; msk < 16; msk <<= 1){ s += __shfl_xor(s, msk, 16); s2 += __shfl_xor(s2, msk, 16); }
        float mean = s * (1.f/64.f);
        float var  = s2 * (1.f/64.f) - mean*mean;
        float rstd = rsqrtf(var + 1e-5f);
        float xf[4];
        #pragma unroll
        for (int j = 0; j < 4; ++j){
            int c = g*4 + j;
            xf[j] = (vv[j] - mean) * rstd * ln2_g[c] + ln2_b[c];
        }
        uint2 u;
        u.x = pk2(xf[0], xf[1]); u.y = pk2(xf[2], xf[3]);
        *(uint2*)TBA(T0B, bb, g*4) = u;
    }
    __syncthreads();

    {
        int col = w*16 + c15;
        float bias = relu_b[col];
        f32x4 ac0 = {bias,bias,bias,bias};
        #pragma unroll
        for (int S = 0; S < 2; ++S){
            uint4 bfv = packH[H_RELU + (w*2 + S)*64 + lane];
            uint4 a0 = *(const uint4*)TBA(T0B, c15, S*32 + half*8);
            ac0 = MFMA(a0, bfv, ac0);
        }
        #pragma unroll
        for (int r = 0; r < 4; ++r)
            *(bf16*)TBA(XRB, half*4 + r, col) = __float2bfloat16(ac0[r]);
    }
    __syncthreads();

    {
        int col = w*16 + c15;
        float bias = nd_b[col];
        f32x4 ac0 = {bias,bias,bias,bias};
        #pragma unroll
        for (int S = 0; S < 2; ++S){
            uint4 bfv = packH[H_ND + (w*2 + S)*64 + lane];
            uint4 a0 = *(const uint4*)TBA(XRB, c15, S*32 + half*8);
            ac0 = MFMA(a0, bfv, ac0);
        }
        #pragma unroll
        for (int r = 0; r < 4; ++r)
            *(bf16*)TBA(T1B, half*4 + r, col) = __float2bfloat16(ac0[r]);
    }
    __syncthreads();

    {
        uint2 u = *(const uint2*)TBA(T1B, bb, g*4);
        float nf[4] = {blo(u.x), bhi(u.x), blo(u.y), bhi(u.y)};
        float p = 0.f;
        #pragma unroll
        for (int j = 0; j < 4; ++j) p = fmaf(nf[j], ldt_W[g*4 + j], p);
        #pragma unroll
        for (int msk = 1; msk < 16; msk <<= 1) p += __shfl_xor(p, msk, 16);
        if (g == 0){
            float dT = p + ldt_b[0];
            dTs[bb] = dT;
            out[(size_t)gb * 26] = dT;
        }
    }
    __syncthreads();

    if (g < 12){
        float dT = dTs[bb];
        int cb = g * 8;
        unsigned pr[4];
        #pragma unroll
        for (int pj = 0; pj < 4; ++pj){
            int c0 = cb + 2*pj, c1 = c0 + 1;
            float v0 = (c0 == 0) ? dT :
                       (c0 <= 64 ? __bfloat162float(*(const bf16*)TBA(XRB, bb, c0-1)) : 0.f);
            float v1 = (c1 <= 64 ? __bfloat162float(*(const bf16*)TBA(XRB, bb, c1-1)) : 0.f);
            pr[pj] = pk2(v0, v1);
        }
        *(uint4*)TBA(T0B, bb, cb) = (uint4){pr[0], pr[1], pr[2], pr[3]};
    }
    __syncthreads();

    {
        uint4 aS[3];
        #pragma unroll
        for (int S = 0; S < 3; ++S)
            aS[S] = *(const uint4*)TBA(T0B, c15, S*32 + half*8);
        int nbl[2]; int nnb = 1; nbl[0] = w;
        if (w == 0){ nbl[1] = 4; nnb = 2; }
        for (int q = 0; q < nnb; ++q){
            int nb = nbl[q];
            int col = nb*16 + c15;
            float bias = (col < 65) ? nz_b[col] : 0.f;
            f32x4 ac0 = {bias,bias,bias,bias};
            #pragma unroll
            for (int S = 0; S < 3; ++S){
                uint4 bfv = packH[H_NZ + (nb*3 + S)*64 + lane];
                ac0 = MFMA(aS[S], bfv, ac0);
            }
            #pragma unroll
            for (int r = 0; r < 4; ++r)
                *(bf16*)TBA(T1B, half*4 + r, col) = __float2bfloat16(ac0[r]);
        }
        if (t < 32){
            int row = t >> 1, seg = t & 1;
            *(uint4*)TBA(T1B, row, 80 + seg*8) = (uint4){0u,0u,0u,0u};
        }
    }
    __syncthreads();

    if (w < 2){
        uint4 aS[3];
        #pragma unroll
        for (int S = 0; S < 3; ++S)
            aS[S] = *(const uint4*)TBA(T1B, c15, S*32 + half*8);
        int nb = w;
        int col = nb*16 + c15;
        float bias = (col < 20) ? lz_b[col] : 0.f;
        f32x4 ac0 = {bias,bias,bias,bias};
        #pragma unroll
        for (int S = 0; S < 3; ++S){
            uint4 bfv = packH[H_LZ + (nb*3 + S)*64 + lane];
            ac0 = MFMA(aS[S], bfv, ac0);
        }
        #pragma unroll
        for (int r = 0; r < 4; ++r){
            int r0 = half*4 + r;
            *(bf16*)TBA(TQB, r0, col) = __float2bfloat16(ac0[r]);
            if (col < 20)
                out[(size_t)(B0 + r0) * 26 + 1 + col] = ac0[r];
        }
    }
    __syncthreads();

    if (g < 12){
        float dT = dTs[bb];
        int cb = g * 8;
        unsigned pr[4];
        #pragma unroll
        for (int pj = 0; pj < 4; ++pj){
            float vv[2];
            #pragma unroll
            for (int hh = 0; hh < 2; ++hh){
                int c = cb + 2*pj + hh;
                float v;
                if (c < 20)       v = __bfloat162float(*(const bf16*)TBA(TQB, bb, c));
                else if (c == 20) v = dT;
                else if (c < 85)  v = __bfloat162float(*(const bf16*)TBA(XRB, bb, c - 21));
                else              v = 0.f;
                vv[hh] = v;
            }
            pr[pj] = pk2(vv[0], vv[1]);
        }
        *(uint4*)TBA(T0B, bb, cb) = (uint4){pr[0], pr[1], pr[2], pr[3]};
    }
    __syncthreads();

    {
        uint4 aS[3];
        #pragma unroll
        for (int S = 0; S < 3; ++S)
            aS[S] = *(const uint4*)TBA(T0B, c15, S*32 + half*8);
        int nbl[2]; int nnb = 1; nbl[0] = w;
        if (w < 2){ nbl[1] = 4 + w; nnb = 2; }
        for (int q = 0; q < nnb; ++q){
            int nb = nbl[q];
            int col = nb*16 + c15;
            float bias = (col < 85) ? na0_b[col] : 0.f;
            f32x4 ac0 = {bias,bias,bias,bias};
            #pragma unroll
            for (int S = 0; S < 3; ++S){
                uint4 bfv = packH[H_NA0 + (nb*3 + S)*64 + lane];
                ac0 = MFMA(aS[S], bfv, ac0);
            }
            #pragma unroll
            for (int r = 0; r < 4; ++r)
                *(bf16*)TBA(T1B, half*4 + r, col) = __float2bfloat16(ac0[r]);
        }
    }
    __syncthreads();

    {
        uint4 aS[3];
        #pragma unroll
        for (int S = 0; S < 3; ++S)
            aS[S] = *(const uint4*)TBA(T1B, c15, S*32 + half*8);
        int nbl[2]; int nnb = 1; nbl[0] = w;
        if (w < 2){ nbl[1] = 4 + w; nnb = 2; }
        for (int q = 0; q < nnb; ++q){
            int nb = nbl[q];
            int col = nb*16 + c15;
            float bias = (col < 85) ? na1_b[col] : 0.f;
            f32x4 ac0 = {bias,bias,bias,bias};
            #pragma unroll
            for (int S = 0; S < 3; ++S){
                uint4 bfv = packH[H_NA1 + (nb*3 + S)*64 + lane];
                ac0 = MFMA(aS[S], bfv, ac0);
            }
            #pragma unroll
            for (int r = 0; r < 4; ++r)
                *(bf16*)TBA(T0B, half*4 + r, col) = __float2bfloat16(ac0[r]);
        }
    }
    __syncthreads();

    if (w == 0){
        int col = c15;
        float bias = (col < 5) ? la_b[col] : 0.f;
        f32x4 ac0 = {bias,bias,bias,bias};
        #pragma unroll
        for (int S = 0; S < 3; ++S){
            uint4 bfv = packH[H_LA + S*64 + lane];
            uint4 a0 = *(const uint4*)TBA(T0B, c15, S*32 + half*8);
            ac0 = MFMA(a0, bfv, ac0);
        }
        if (col < 5){
            #pragma unroll
            for (int r = 0; r < 4; ++r)
                out[(size_t)(B0 + half*4 + r) * 26 + 21 + col] = ac0[r];
        }
    }
}

extern "C" void kernel_launch(void* const* d_in, const int* in_sizes, int n_in,
                              void* d_out, int out_size, void* d_ws, size_t ws_size,
                              hipStream_t stream)
{
    const float* X        = (const float*)d_in[0];
    const float* emb_act  = (const float*)d_in[1];
    const float* emb_zone = (const float*)d_in[2];
    const float* lin0_W   = (const float*)d_in[3];
    const float* lin0_b   = (const float*)d_in[4];
    const float* gat_W    = (const float*)d_in[5];
    const float* gat_b    = (const float*)d_in[6];
    const float* gat_a    = (const float*)d_in[7];
    const float* gl0_W    = (const float*)d_in[8];
    const float* gl0_b    = (const float*)d_in[9];
    const float* gl1_W    = (const float*)d_in[10];
    const float* gl1_b    = (const float*)d_in[11];
    const float* gl2_W    = (const float*)d_in[12];
    const float* gl2_b    = (const float*)d_in[13];
    const float* Wqkv     = (const float*)d_in[14];
    const float* bqkv     = (const float*)d_in[15];
    const float* Wo       = (const float*)d_in[16];
    const float* bo       = (const float*)d_in[17];
    const float* ln1_g    = (const float*)d_in[18];
    const float* ln1_b    = (const float*)d_in[19];
    const float* W1       = (const float*)d_in[20];
    const float* b1       = (const float*)d_in[21];
    const float* W2       = (const float*)d_in[22];
    const float* b2       = (const float*)d_in[23];
    const float* ln2_g    = (const float*)d_in[24];
    const float* ln2_b    = (const float*)d_in[25];
    const float* relu_W   = (const float*)d_in[26];
    const float* relu_b   = (const float*)d_in[27];
    const float* nd_W     = (const float*)d_in[28];
    const float* nd_b     = (const float*)d_in[29];
    const float* ldt_W    = (const float*)d_in[30];
    const float* ldt_b    = (const float*)d_in[31];
    const float* nz_W     = (const float*)d_in[32];
    const float* nz_b     = (const float*)d_in[33];
    const float* lz_W     = (const float*)d_in[34];
    const float* lz_b     = (const float*)d_in[35];
    const float* na0_W    = (const float*)d_in[36];
    const float* na0_b    = (const float*)d_in[37];
    const float* na1_W    = (const float*)d_in[38];
    const float* na1_b    = (const float*)d_in[39];
    const float* la_W     = (const float*)d_in[40];
    const float* la_b     = (const float*)d_in[41];

    char* wsb = (char*)d_ws;
    bf16*  kv       = (bf16*)wsb;
    float* src_last = (float*)(wsb + (size_t)NTOK * 128 * sizeof(bf16));
    uint4* packW    = (uint4*)(wsb + (size_t)NTOK * 128 * sizeof(bf16) + (size_t)B_ * 64 * sizeof(float));
    uint4* packH    = packW + PK_TOT;

    k_pack_all<<<(PK_TOT + H_TOT + 255)/256, 256, 0, stream>>>(
        gl0_W, gl1_W, gl2_W, Wqkv, Wo, W1, W2, relu_W, nd_W, nz_W, lz_W,
        na0_W, na1_W, la_W, packW, packH);

    k_token<<<NTOK/TOKB, TPB, 0, stream>>>(X, emb_act, emb_zone, lin0_W, lin0_b,
        gat_W, gat_b, gat_a, gl0_b, gl1_b, gl2_b, bqkv, packW, kv, src_last);

    k_head2<<<B_/16, 256, 0, stream>>>(kv, src_last, packH, bqkv, bo,
        ln1_g, ln1_b, b1, b2, ln2_g, ln2_b, relu_b, nd_b, ldt_W, ldt_b,
        nz_b, lz_b, na0_b, na1_b, la_b, (float*)d_out);
}